// Round 3
// baseline (8976.993 us; speedup 1.0000x reference)
//
#include <hip/hip_runtime.h>
#include <math.h>

// PhysicsLSGStep: bitwise-faithful f32 replication of the numpy reference.
// R14 (on top of R13's precomputed pairwise-tree schedule):
//  - k_d1w / k_d1tz: thread = node, full float8 (two float4). Lanes 2i/2i+1
//    previously walked the SAME edge list (traffic shared, instructions
//    doubled). Per-feature op chains unchanged => bit-identical.
//  - k_dot_leaf / k_xr_dot: 8 independent accumulator chains of each base
//    block split across 8 lanes (exact chains + exact combine tree + exact
//    tail). Base phase parallelism 32 -> 256 lanes.
//  - fusions: k_init folded into setup k_d1tz (doInit); k_xr folded into the
//    r.r dot leaf kernel (update x,r for the leaf range, then dot fresh r).
// Scatter sums stay in sorted-edge-id (CSR) order; elementwise f32 __f*_rn.

#define F 8
#define CG_ITERS 30
#define LEAF_T 4096
#define LEAF_PAD (LEAF_T + LEAF_T / 128 + 8)
#define DOT_NB 800     // >= max leaves
#define ENC_ADD 1024   // operand encoding: <1024 = base slot, else add t+1024
#define BW_D 24        // max stack depth

#define S_RS    0
#define S_ALPHA 1
#define S_BETA  2
#define S_DONE  3
#define S_DONE2 4

// padded-LDS accessor (bank-spread: +1 word every 128)
#define LV(A_, i_) A_[(i_) + ((i_) >> 7)]

__device__ __forceinline__ float dt_eff_of(const float* dtp) {
    return fminf(fmaxf(dtp[0], 0.02f), 2.0f);
}

__device__ __forceinline__ int slotOf(int e, int NB) {
    return (e < ENC_ADD) ? e : (NB + (e - ENC_ADD));
}

// leaf decomposition of virtual [0, n) (n = NF-1; physical offset +1).
__global__ void k_build_leaves(int n, int* leafOff, int* leafN, int* nLeaf) {
    __shared__ int spOff[40], spN[40];
    if (threadIdx.x != 0 || blockIdx.x != 0) return;
    int sp = 0;
    spOff[0] = 0; spN[0] = n;
    int cnt = 0;
    while (sp >= 0) {
        int off = spOff[sp], nn = spN[sp]; sp--;
        if (nn <= LEAF_T) {
            if (cnt < 2048) { leafOff[cnt] = off; leafN[cnt] = nn; }
            cnt++;
        } else {
            int n2 = nn / 2; n2 -= (n2 & 7);
            spOff[++sp] = off + n2; spN[sp] = nn - n2;  // right (popped second)
            spOff[++sp] = off;      spN[sp] = n2;       // left  (popped first)
        }
    }
    *nLeaf = cnt;
}

// Symbolic replay of the pairwise recursion. Emits base blocks (left-to-right)
// and add triples (post-order) with depths. LDS stacks, stride 64.
__device__ void build_tree(int n, int T, int tid,
                           int* so, int* sn_, int* st, int* sid, int* sdp,
                           int* bOffOut, int* bNOut,
                           int* AOut, int* BOut, int* depOut,
                           int* pNB, int* pNT, int* pMaxD) {
    int sp = 0, coff = 0, cn = n, c2 = 0, t = 0;
    int rootd = 0;
    for (;;) {
        if (cn <= T) {
            if (bOffOut) { bOffOut[c2] = coff; bNOut[c2] = cn; }
            int id = c2, dep = 0; c2++;
            bool fin = false;
            for (;;) {
                if (sp == 0) { rootd = dep; fin = true; break; }
                int q = (sp - 1) * 64 + tid;
                if (st[q] == 0) {
                    st[q] = 1; sid[q] = id; sdp[q] = dep;
                    int n2 = sn_[q] / 2; n2 -= (n2 & 7);
                    coff = so[q] + n2; cn = sn_[q] - n2;
                    break;
                } else {
                    AOut[t] = sid[q]; BOut[t] = id;   // add = stored(left)+cur(right)
                    int dA = sdp[q];
                    dep = ((dA > dep) ? dA : dep) + 1;
                    depOut[t] = dep;
                    id = ENC_ADD + t; t++;
                    sp--;
                }
            }
            if (fin) break;
        } else {
            int q = sp * 64 + tid;
            so[q] = coff; sn_[q] = cn; st[q] = 0; sp++;
            int n2 = cn / 2; n2 -= (n2 & 7);
            cn = n2;
        }
    }
    *pNB = c2; *pNT = t; *pMaxD = rootd;
}

// depth-bucket the adds into evaluation order (level-parallel schedule)
__device__ void bucketize(const int* depArr, int NT, int maxD, int tid,
                          int* cnt, int* orderOut, int* levOffOut) {
    for (int d = 0; d <= maxD; ++d) cnt[d * 64 + tid] = 0;
    for (int t = 0; t < NT; ++t) cnt[depArr[t] * 64 + tid]++;
    int run = 0;
    levOffOut[0] = 0;
    for (int d = 1; d <= maxD; ++d) { run += cnt[d * 64 + tid]; levOffOut[d] = run; }
    for (int d = 1; d <= maxD; ++d) cnt[d * 64 + tid] = levOffOut[d - 1];
    for (int t = 0; t < NT; ++t) { int d = depArr[t]; orderOut[cnt[d * 64 + tid]++] = t; }
}

// one-shot schedule build: one thread per leaf; thread 0 also builds upper tree
__global__ void k_build_sched(const int* __restrict__ leafN, const int* __restrict__ nLeaf,
                              int* lNB, int* lBOff, int* lBN, int* lA, int* lB,
                              int* lDep, int* lOrder, int* lLevOff, int* lMaxD,
                              int* uHdr, int* uA, int* uB, int* uDep, int* uOrder,
                              int* uLevOff, int n) {
    __shared__ int sSo[BW_D * 64], sSn[BW_D * 64], sSt[BW_D * 64];
    __shared__ int sSid[BW_D * 64], sSdp[BW_D * 64];
    __shared__ int sCnt[32 * 64];
    int tid = threadIdx.x;
    int g = blockIdx.x * 64 + tid;
    int NL = *nLeaf; if (NL > 1024) NL = 1024;
    if (g < NL) {
        int NB, NT, maxD;
        build_tree(leafN[g], 128, tid, sSo, sSn, sSt, sSid, sSdp,
                   lBOff + g * 64, lBN + g * 64,
                   lA + g * 64, lB + g * 64, lDep + g * 64, &NB, &NT, &maxD);
        lNB[g] = NB; lMaxD[g] = maxD;
        bucketize(lDep + g * 64, NT, maxD, tid, sCnt, lOrder + g * 64,
                  lLevOff + g * 32);
    }
    if (g == 0) {
        int NB, NT, maxD;
        build_tree(n, LEAF_T, tid, sSo, sSn, sSt, sSid, sSdp,
                   (int*)0, (int*)0, uA, uB, uDep, &NB, &NT, &maxD);
        uHdr[0] = NT; uHdr[1] = maxD;
        bucketize(uDep, NT, maxD, tid, sCnt, uOrder, uLevOff);
    }
}

// shared tail of the leaf-dot: 8-way base chains + exact combine + tree eval.
// sA/sB may alias (r.r dot). blockDim = 256.
__device__ __forceinline__ void dot_eval(const float* sA, const float* sB,
                                         float* sChain, float* sVal,
                                         int j, int lane, int NB,
                                         const int* __restrict__ lBOff,
                                         const int* __restrict__ lBN,
                                         const int* __restrict__ lA,
                                         const int* __restrict__ lB,
                                         const int* __restrict__ lOrder,
                                         const int* __restrict__ lLevOff,
                                         const int* __restrict__ lMaxD,
                                         float* __restrict__ partial) {
    // phase A: chain r_j of base block bb on lane bb*8+j (independent chains)
    int bb = lane >> 3, jj = lane & 7;
    if (bb < NB) {
        int off = lBOff[j * 64 + bb], n = lBN[j * 64 + bb];
        if (n >= 8) {
            int lim = n - (n & 7);
            float rr = __fmul_rn(LV(sA, off + jj), LV(sB, off + jj));
            for (int e = jj + 8; e < lim; e += 8)
                rr = __fadd_rn(rr, __fmul_rn(LV(sA, off + e), LV(sB, off + e)));
            sChain[bb * 8 + jj] = rr;
        }
    }
    __syncthreads();
    // phase B: exact combine tree + exact tail per base block
    if (lane < NB) {
        int off = lBOff[j * 64 + lane], n = lBN[j * 64 + lane];
        float res;
        if (n < 8) {
            res = 0.f;
            for (int e = 0; e < n; ++e)
                res = __fadd_rn(res, __fmul_rn(LV(sA, off + e), LV(sB, off + e)));
        } else {
            int lim = n - (n & 7);
            const float* c = sChain + lane * 8;
            res = __fadd_rn(__fadd_rn(__fadd_rn(c[0], c[1]), __fadd_rn(c[2], c[3])),
                            __fadd_rn(__fadd_rn(c[4], c[5]), __fadd_rn(c[6], c[7])));
            for (int e = lim; e < n; ++e)
                res = __fadd_rn(res, __fmul_rn(LV(sA, off + e), LV(sB, off + e)));
        }
        sVal[lane] = res;
    }
    __syncthreads();
    // phase C: level-parallel replay of the leaf combine tree
    int maxD = lMaxD[j];
    const int* LO = lLevOff + j * 32;
    for (int d = 1; d <= maxD; ++d) {
        int s0 = LO[d - 1], s1 = LO[d];
        for (int s = s0 + lane; s < s1; s += 256) {
            int tt = lOrder[j * 64 + s];
            sVal[NB + tt] = __fadd_rn(sVal[slotOf(lA[j * 64 + tt], NB)],
                                      sVal[slotOf(lB[j * 64 + tt], NB)]);
        }
        __syncthreads();
    }
    if (lane == 0) partial[j] = (NB > 1) ? sVal[NB + NB - 2] : sVal[0];
}

// per-leaf dot partial (a.b): stage -> chains -> tree
__global__ void k_dot_leaf(const float* __restrict__ a, const float* __restrict__ b,
                           const int* __restrict__ leafOff, const int* __restrict__ leafN,
                           const int* __restrict__ nLeaf,
                           const int* __restrict__ lNB, const int* __restrict__ lBOff,
                           const int* __restrict__ lBN, const int* __restrict__ lA,
                           const int* __restrict__ lB, const int* __restrict__ lOrder,
                           const int* __restrict__ lLevOff, const int* __restrict__ lMaxD,
                           float* __restrict__ partial) {
    __shared__ float sA[LEAF_PAD], sB[LEAF_PAD];
    __shared__ float sChain[512];
    __shared__ float sVal[160];
    int j = blockIdx.x, lane = threadIdx.x;
    if (j >= *nLeaf) return;
    int P = leafOff[j] + 1, nn = leafN[j];
    for (int g = lane; g < nn; g += 256) {
        float av = a[P + g], bv = b[P + g];
        int m = g + (g >> 7);
        sA[m] = av; sB[m] = bv;
    }
    __syncthreads();
    dot_eval(sA, sB, sChain, sVal, j, lane, lNB[j], lBOff, lBN, lA, lB,
             lOrder, lLevOff, lMaxD, partial);
}

// fused: x += a*p ; r -= a*z (guarded by done_old) over this leaf's range,
// then leaf dot of the fresh r. Element 0 (not in any leaf) handled by block 0.
__global__ void k_xr_dot(float* __restrict__ x, float* __restrict__ r,
                         const float* __restrict__ p, const float* __restrict__ z,
                         const float* __restrict__ scal,
                         const int* __restrict__ leafOff, const int* __restrict__ leafN,
                         const int* __restrict__ nLeaf,
                         const int* __restrict__ lNB, const int* __restrict__ lBOff,
                         const int* __restrict__ lBN, const int* __restrict__ lA,
                         const int* __restrict__ lB, const int* __restrict__ lOrder,
                         const int* __restrict__ lLevOff, const int* __restrict__ lMaxD,
                         float* __restrict__ partial) {
    __shared__ float sA[LEAF_PAD];
    __shared__ float sChain[512];
    __shared__ float sVal[160];
    int j = blockIdx.x, lane = threadIdx.x;
    if (j >= *nLeaf) return;
    int P = leafOff[j] + 1, nn = leafN[j];
    int active = (scal[S_DONE] == 0.f);
    float al = scal[S_ALPHA];
    if (j == 0 && lane == 0 && active) {
        x[0] = __fadd_rn(x[0], __fmul_rn(al, p[0]));
        r[0] = __fsub_rn(r[0], __fmul_rn(al, z[0]));
    }
    for (int g = lane; g < nn; g += 256) {
        int q = P + g;
        float rv = r[q];
        if (active) {
            float xv = x[q], pv = p[q], zv = z[q];
            x[q] = __fadd_rn(xv, __fmul_rn(al, pv));
            rv = __fsub_rn(rv, __fmul_rn(al, zv));
            r[q] = rv;
        }
        sA[g + (g >> 7)] = rv;
    }
    __syncthreads();
    dot_eval(sA, sA, sChain, sVal, j, lane, lNB[j], lBOff, lBN, lA, lB,
             lOrder, lLevOff, lMaxD, partial);
}

// upper combine (level-parallel) + scalar update. 1 block, 256 threads.
__global__ void k_dot_fin(const float* __restrict__ a, const float* __restrict__ b,
                          const float* __restrict__ partial, const int* __restrict__ nLeaf,
                          const int* __restrict__ uHdr, const int* __restrict__ uA,
                          const int* __restrict__ uB, const int* __restrict__ uOrder,
                          const int* __restrict__ uLevOff, float* __restrict__ scal,
                          int mode) {
    __shared__ float sVal[2048];
    int lane = threadIdx.x;
    int NL = *nLeaf;
    int NT = uHdr[0], maxD = uHdr[1];
    for (int k = lane; k < NL; k += 256) sVal[k] = partial[k];
    __syncthreads();
    for (int d = 1; d <= maxD; ++d) {
        int s0 = uLevOff[d - 1], s1 = uLevOff[d];
        for (int s = s0 + lane; s < s1; s += 256) {
            int tt = uOrder[s];
            sVal[NL + tt] = __fadd_rn(sVal[slotOf(uA[tt], NL)],
                                      sVal[slotOf(uB[tt], NL)]);
        }
        __syncthreads();
    }
    if (lane != 0) return;
    float res = (NT > 0) ? sVal[NL + NT - 1] : sVal[0];
    res = __fadd_rn(__fmul_rn(a[0], b[0]), res);   // first-element init
    if (mode == 0) {
        scal[S_RS] = res; scal[S_DONE] = 0.f; scal[S_DONE2] = 0.f;
    } else if (mode == 1) {
        scal[S_DONE] = scal[S_DONE2];  // done_old for this iteration
        scal[S_ALPHA] = __fdiv_rn(scal[S_RS], __fadd_rn(res, (float)1e-12));
    } else {
        float rs1 = res;
        scal[S_BETA] = __fdiv_rn(rs1, __fadd_rn(scal[S_RS], (float)1e-12));
        float dn = scal[S_DONE];
        if (dn == 0.f) scal[S_RS] = rs1;
        scal[S_DONE2] = (dn != 0.f || __fsqrt_rn(rs1) <= (float)1e-4) ? 1.f : 0.f;
    }
}

// ---------- CSR build (stable in edge order) ----------

__global__ void k_edge_pre(const int* __restrict__ dst, const int* __restrict__ src,
                           int* __restrict__ dstCnt, int* __restrict__ srcCnt, int E) {
    int e = blockIdx.x * blockDim.x + threadIdx.x;
    if (e >= E) return;
    atomicAdd(&dstCnt[dst[e]], 1);
    atomicAdd(&srcCnt[src[e]], 1);
}

__global__ void k_scan1(const int* __restrict__ cnt, int* __restrict__ incl,
                        int* __restrict__ bsums, int N) {
    __shared__ int sm[512];
    int i = blockIdx.x * 512 + threadIdx.x;
    sm[threadIdx.x] = (i < N) ? cnt[i] : 0;
    __syncthreads();
    for (int off = 1; off < 512; off <<= 1) {
        int t = (threadIdx.x >= off) ? sm[threadIdx.x - off] : 0;
        __syncthreads();
        sm[threadIdx.x] += t;
        __syncthreads();
    }
    if (i < N) incl[i] = sm[threadIdx.x];
    if (threadIdx.x == 511) bsums[blockIdx.x] = sm[511];
}

__global__ void k_scan2(int* __restrict__ bsums, int nb) {
    __shared__ int sm[512];
    sm[threadIdx.x] = (threadIdx.x < nb) ? bsums[threadIdx.x] : 0;
    __syncthreads();
    for (int off = 1; off < 512; off <<= 1) {
        int t = (threadIdx.x >= off) ? sm[threadIdx.x - off] : 0;
        __syncthreads();
        sm[threadIdx.x] += t;
        __syncthreads();
    }
    if (threadIdx.x < nb) bsums[threadIdx.x] = sm[threadIdx.x];
}

__global__ void k_scan3(int* __restrict__ off, const int* __restrict__ bsums,
                        const int* __restrict__ cnt, int N, int E) {
    int i = blockIdx.x * 512 + threadIdx.x;
    if (i < N) {
        int add = (blockIdx.x > 0) ? bsums[blockIdx.x - 1] : 0;
        off[i] = off[i] + add - cnt[i];  // exclusive
    }
    if (i == 0) off[N] = E;
}

__global__ void k_fill(const int* __restrict__ dst, const int* __restrict__ src,
                       const int* __restrict__ dstOff, const int* __restrict__ srcOff,
                       int* __restrict__ cursD, int* __restrict__ cursS,
                       int* __restrict__ dstList, int* __restrict__ srcList, int E) {
    int e = blockIdx.x * blockDim.x + threadIdx.x;
    if (e >= E) return;
    int d = dst[e];
    dstList[dstOff[d] + atomicAdd(&cursD[d], 1)] = e;
    int s0 = src[e];
    srcList[srcOff[s0] + atomicAdd(&cursS[s0], 1)] = e;
}

__device__ __forceinline__ void insort(int* L, int lo, int hi) {
    for (int a = lo + 1; a < hi; ++a) {
        int key = L[a]; int b = a - 1;
        while (b >= lo && L[b] > key) { L[b + 1] = L[b]; b--; }
        L[b + 1] = key;
    }
}

__global__ void k_sort(const int* __restrict__ dstOff, const int* __restrict__ srcOff,
                       int* __restrict__ dstList, int* __restrict__ srcList, int N) {
    int i = blockIdx.x * blockDim.x + threadIdx.x;
    if (i >= N) return;
    insort(dstList, dstOff[i], dstOff[i + 1]);
    insort(srcList, srcOff[i], srcOff[i + 1]);
}

// Permute per-edge operands into CSR order, IN PLACE over the lists.
__global__ void k_perm(int* dstList, int* srcList,
                       const int* __restrict__ srcp, const int* __restrict__ dstp,
                       const float* __restrict__ ea,
                       float* __restrict__ invD, float* __restrict__ slopeD,
                       float* __restrict__ invS, int E) {
    int k = blockIdx.x * blockDim.x + threadIdx.x;
    if (k >= E) return;
    int e  = dstList[k];
    int e2 = srcList[k];
    float dx  = fmaxf(ea[2 * e], 1e-6f);
    float dx2 = fmaxf(ea[2 * e2], 1e-6f);
    int sA_ = srcp[e];
    int dB_ = dstp[e2];
    float iD = __fdiv_rn(1.f, dx);
    float sD = __fdiv_rn(ea[2 * e + 1], dx);
    float iS = __fdiv_rn(1.f, dx2);
    dstList[k] = sA_;    // srcA
    srcList[k] = dB_;    // dstB
    invD[k] = iD; slopeD[k] = sD; invS[k] = iS;
}

// ---------- physics kernels (exact np op order, f32 sequential) ----------

__global__ void k_slope_b(const float* __restrict__ u, const float* __restrict__ slopeD,
                          const int* __restrict__ dstOff,
                          float* __restrict__ r, float* __restrict__ y,
                          const float* __restrict__ dtp, const float* __restrict__ gp,
                          int N) {
    int i = blockIdx.x * blockDim.x + threadIdx.x;
    if (i >= N) return;
    float dtg = __fmul_rn(dt_eff_of(dtp), gp[0]);
    float sn = 0.f;
    int k0 = dstOff[i], k1 = dstOff[i + 1];
    for (int k = k0; k < k1; ++k) sn = __fadd_rn(sn, slopeD[k]);
    float ms = __fmul_rn(dtg, sn);
    const float4* u4 = (const float4*)u;
    float4* r4 = (float4*)r;
    float4* y4 = (float4*)y;
    #pragma unroll
    for (int hh = 0; hh < 2; ++hh) {
        float4 uv = u4[i * 2 + hh];
        float4 bv;
        bv.x = __fsub_rn(uv.x, ms);
        bv.y = __fsub_rn(uv.y, ms);
        bv.z = __fsub_rn(uv.z, ms);
        bv.w = __fsub_rn(uv.w, ms);
        r4[i * 2 + hh] = bv;
        float4 yv;
        yv.x = __fmul_rn(uv.x, bv.x);
        yv.y = __fmul_rn(uv.y, bv.y);
        yv.z = __fmul_rn(uv.z, bv.z);
        yv.w = __fmul_rn(uv.w, bv.w);
        y4[i * 2 + hh] = yv;
    }
}

// D1_T via y; out = base + dt*acc. thread = node (float8).
// doInit: also r := out, x := 0 (replaces k_init).
__global__ void k_d1tz(const int* __restrict__ dstB, const int* __restrict__ dstOff,
                       const float* __restrict__ invD, const int* __restrict__ srcOff,
                       const float* __restrict__ invS, const float* __restrict__ y,
                       const float* __restrict__ base, float* __restrict__ out,
                       const float* __restrict__ dtp,
                       float* __restrict__ rInit, float* __restrict__ xInit,
                       int doInit, int N) {
    int i = blockIdx.x * blockDim.x + threadIdx.x;
    if (i >= N) return;
    const float4* y4 = (const float4*)y;
    float4 uyL = y4[i * 2], uyH = y4[i * 2 + 1];
    float4 aL = make_float4(0.f, 0.f, 0.f, 0.f);
    float4 aH = make_float4(0.f, 0.f, 0.f, 0.f);
    int k0 = dstOff[i], k1 = dstOff[i + 1];
    for (int k = k0; k < k1; ++k) {
        float iv = invD[k];
        aL.x = __fadd_rn(aL.x, __fmul_rn(uyL.x, iv));
        aL.y = __fadd_rn(aL.y, __fmul_rn(uyL.y, iv));
        aL.z = __fadd_rn(aL.z, __fmul_rn(uyL.z, iv));
        aL.w = __fadd_rn(aL.w, __fmul_rn(uyL.w, iv));
        aH.x = __fadd_rn(aH.x, __fmul_rn(uyH.x, iv));
        aH.y = __fadd_rn(aH.y, __fmul_rn(uyH.y, iv));
        aH.z = __fadd_rn(aH.z, __fmul_rn(uyH.z, iv));
        aH.w = __fadd_rn(aH.w, __fmul_rn(uyH.w, iv));
    }
    k0 = srcOff[i]; k1 = srcOff[i + 1];
    for (int k = k0; k < k1; ++k) {
        int d = dstB[k];
        float iv = invS[k];
        float4 ydL = y4[d * 2], ydH = y4[d * 2 + 1];
        float t0 = __fmul_rn(ydL.x, iv); aL.x = __fadd_rn(aL.x, -t0);
        float t1 = __fmul_rn(ydL.y, iv); aL.y = __fadd_rn(aL.y, -t1);
        float t2 = __fmul_rn(ydL.z, iv); aL.z = __fadd_rn(aL.z, -t2);
        float t3 = __fmul_rn(ydL.w, iv); aL.w = __fadd_rn(aL.w, -t3);
        float t4 = __fmul_rn(ydH.x, iv); aH.x = __fadd_rn(aH.x, -t4);
        float t5 = __fmul_rn(ydH.y, iv); aH.y = __fadd_rn(aH.y, -t5);
        float t6 = __fmul_rn(ydH.z, iv); aH.z = __fadd_rn(aH.z, -t6);
        float t7 = __fmul_rn(ydH.w, iv); aH.w = __fadd_rn(aH.w, -t7);
    }
    float dt = dt_eff_of(dtp);
    const float4* b4 = (const float4*)base;
    float4 bsL = b4[i * 2], bsH = b4[i * 2 + 1];
    float4 oL, oH;
    oL.x = __fadd_rn(bsL.x, __fmul_rn(dt, aL.x));
    oL.y = __fadd_rn(bsL.y, __fmul_rn(dt, aL.y));
    oL.z = __fadd_rn(bsL.z, __fmul_rn(dt, aL.z));
    oL.w = __fadd_rn(bsL.w, __fmul_rn(dt, aL.w));
    oH.x = __fadd_rn(bsH.x, __fmul_rn(dt, aH.x));
    oH.y = __fadd_rn(bsH.y, __fmul_rn(dt, aH.y));
    oH.z = __fadd_rn(bsH.z, __fmul_rn(dt, aH.z));
    oH.w = __fadd_rn(bsH.w, __fmul_rn(dt, aH.w));
    float4* o4 = (float4*)out;
    o4[i * 2] = oL; o4[i * 2 + 1] = oH;
    if (doInit) {
        ((float4*)rInit)[i * 2] = oL;
        ((float4*)rInit)[i * 2 + 1] = oH;
        float4 zz = make_float4(0.f, 0.f, 0.f, 0.f);
        ((float4*)xInit)[i * 2] = zz;
        ((float4*)xInit)[i * 2 + 1] = zz;
    }
}

// D1(p) fused with w = p + dt*(u*t) and y = u*w. thread = node (float8).
__global__ void k_d1w(const int* __restrict__ srcA, const int* __restrict__ dstOff,
                      const float* __restrict__ invD, const float* __restrict__ pv,
                      const float* __restrict__ u,
                      float* __restrict__ w, float* __restrict__ y,
                      const float* __restrict__ dtp, int N) {
    int i = blockIdx.x * blockDim.x + threadIdx.x;
    if (i >= N) return;
    const float4* pv4 = (const float4*)pv;
    float4 piL = pv4[i * 2], piH = pv4[i * 2 + 1];
    float4 aL = make_float4(0.f, 0.f, 0.f, 0.f);
    float4 aH = make_float4(0.f, 0.f, 0.f, 0.f);
    int k0 = dstOff[i], k1 = dstOff[i + 1];
    for (int k = k0; k < k1; ++k) {
        int s = srcA[k];
        float iv = invD[k];
        float4 psL = pv4[s * 2], psH = pv4[s * 2 + 1];
        aL.x = __fadd_rn(aL.x, __fmul_rn(__fsub_rn(piL.x, psL.x), iv));
        aL.y = __fadd_rn(aL.y, __fmul_rn(__fsub_rn(piL.y, psL.y), iv));
        aL.z = __fadd_rn(aL.z, __fmul_rn(__fsub_rn(piL.z, psL.z), iv));
        aL.w = __fadd_rn(aL.w, __fmul_rn(__fsub_rn(piL.w, psL.w), iv));
        aH.x = __fadd_rn(aH.x, __fmul_rn(__fsub_rn(piH.x, psH.x), iv));
        aH.y = __fadd_rn(aH.y, __fmul_rn(__fsub_rn(piH.y, psH.y), iv));
        aH.z = __fadd_rn(aH.z, __fmul_rn(__fsub_rn(piH.z, psH.z), iv));
        aH.w = __fadd_rn(aH.w, __fmul_rn(__fsub_rn(piH.w, psH.w), iv));
    }
    float dt = dt_eff_of(dtp);
    const float4* u4 = (const float4*)u;
    float4 uvL = u4[i * 2], uvH = u4[i * 2 + 1];
    float4 wL, wH;
    wL.x = __fadd_rn(piL.x, __fmul_rn(dt, __fmul_rn(uvL.x, aL.x)));
    wL.y = __fadd_rn(piL.y, __fmul_rn(dt, __fmul_rn(uvL.y, aL.y)));
    wL.z = __fadd_rn(piL.z, __fmul_rn(dt, __fmul_rn(uvL.z, aL.z)));
    wL.w = __fadd_rn(piL.w, __fmul_rn(dt, __fmul_rn(uvL.w, aL.w)));
    wH.x = __fadd_rn(piH.x, __fmul_rn(dt, __fmul_rn(uvH.x, aH.x)));
    wH.y = __fadd_rn(piH.y, __fmul_rn(dt, __fmul_rn(uvH.y, aH.y)));
    wH.z = __fadd_rn(piH.z, __fmul_rn(dt, __fmul_rn(uvH.z, aH.z)));
    wH.w = __fadd_rn(piH.w, __fmul_rn(dt, __fmul_rn(uvH.w, aH.w)));
    ((float4*)w)[i * 2] = wL; ((float4*)w)[i * 2 + 1] = wH;
    float4 yL, yH;
    yL.x = __fmul_rn(uvL.x, wL.x);
    yL.y = __fmul_rn(uvL.y, wL.y);
    yL.z = __fmul_rn(uvL.z, wL.z);
    yL.w = __fmul_rn(uvL.w, wL.w);
    yH.x = __fmul_rn(uvH.x, wH.x);
    yH.y = __fmul_rn(uvH.y, wH.y);
    yH.z = __fmul_rn(uvH.z, wH.z);
    yH.w = __fmul_rn(uvH.w, wH.w);
    ((float4*)y)[i * 2] = yL; ((float4*)y)[i * 2 + 1] = yH;
}

// p = r + beta*p   (guarded by done_old)  float4
__global__ void k_p(float4* __restrict__ p4, const float4* __restrict__ r4,
                    const float* __restrict__ scal, int n4) {
    int i = blockIdx.x * blockDim.x + threadIdx.x;
    if (i >= n4) return;
    if (scal[S_DONE] != 0.f) return;
    float be = scal[S_BETA];
    float4 pv = p4[i], rv = r4[i];
    pv.x = __fadd_rn(rv.x, __fmul_rn(be, pv.x));
    pv.y = __fadd_rn(rv.y, __fmul_rn(be, pv.y));
    pv.z = __fadd_rn(rv.z, __fmul_rn(be, pv.z));
    pv.w = __fadd_rn(rv.w, __fmul_rn(be, pv.w));
    p4[i] = pv;
}

extern "C" void kernel_launch(void* const* d_in, const int* in_sizes, int n_in,
                              void* d_out, int out_size, void* d_ws, size_t ws_size,
                              hipStream_t stream) {
    const float* u   = (const float*)d_in[0];
    const int*   ei  = (const int*)d_in[1];
    const float* ea  = (const float*)d_in[2];
    const float* dtp = (const float*)d_in[3];
    const float* gp  = (const float*)d_in[4];

    const int NF = in_sizes[0];        // 1,600,000
    const int N  = NF / F;             // 200,000
    const int E  = in_sizes[2] / 2;    // 3,200,000
    const int* srcp = ei;
    const int* dstp = ei + E;

    char* wp = (char*)d_ws;
    float* scal    = (float*)wp; wp += 64 * 4;
    float* r       = (float*)wp; wp += (size_t)NF * 4;
    float* p       = (float*)wp; wp += (size_t)NF * 4;
    float* t       = (float*)wp; wp += (size_t)NF * 4;   // z
    float* w       = (float*)wp; wp += (size_t)NF * 4;
    float* y       = (float*)wp; wp += (size_t)NF * 4;   // u*w / u*b
    int*   dstList = (int*)wp;   wp += (size_t)E * 4;    // becomes srcA after k_perm
    int*   srcList = (int*)wp;   wp += (size_t)E * 4;    // becomes dstB after k_perm
    float* invD    = (float*)wp; wp += (size_t)E * 4;
    float* invS    = (float*)wp; wp += (size_t)E * 4;
    float* slopeD  = (float*)wp; wp += (size_t)E * 4;
    int*   dstOff  = (int*)wp;   wp += (size_t)(N + 1) * 4;
    int*   srcOff  = (int*)wp;   wp += (size_t)(N + 1) * 4;
    int*   dstCnt  = (int*)wp;   wp += (size_t)N * 4;
    int*   srcCnt  = (int*)wp;   wp += (size_t)N * 4;
    int*   cursD   = (int*)wp;   wp += (size_t)N * 4;
    int*   cursS   = (int*)wp;   wp += (size_t)N * 4;
    int*   bsD     = (int*)wp;   wp += 512 * 4;
    int*   bsS     = (int*)wp;   wp += 512 * 4;
    int*   leafOff = (int*)wp;   wp += 2048 * 4;
    int*   leafN   = (int*)wp;   wp += 2048 * 4;
    int*   nLeaf   = (int*)wp;   wp += 64;
    float* partial = (float*)wp; wp += 2048 * 4;
    // dot schedules (built once)
    int*   lNB     = (int*)wp;   wp += 1024 * 4;
    int*   lMaxD   = (int*)wp;   wp += 1024 * 4;
    int*   lBOff   = (int*)wp;   wp += (size_t)1024 * 64 * 4;
    int*   lBN     = (int*)wp;   wp += (size_t)1024 * 64 * 4;
    int*   lA      = (int*)wp;   wp += (size_t)1024 * 64 * 4;
    int*   lB      = (int*)wp;   wp += (size_t)1024 * 64 * 4;
    int*   lDep    = (int*)wp;   wp += (size_t)1024 * 64 * 4;
    int*   lOrder  = (int*)wp;   wp += (size_t)1024 * 64 * 4;
    int*   lLevOff = (int*)wp;   wp += (size_t)1024 * 32 * 4;
    int*   uHdr    = (int*)wp;   wp += 64;
    int*   uA      = (int*)wp;   wp += 1024 * 4;
    int*   uB      = (int*)wp;   wp += 1024 * 4;
    int*   uDep    = (int*)wp;   wp += 1024 * 4;
    int*   uOrder  = (int*)wp;   wp += 1024 * 4;
    int*   uLevOff = (int*)wp;   wp += 64 * 4;
    float* x = (float*)d_out;

    hipMemsetAsync(scal, 0, 64 * 4, stream);
    hipMemsetAsync(dstCnt, 0, (size_t)N * 4, stream);
    hipMemsetAsync(srcCnt, 0, (size_t)N * 4, stream);
    hipMemsetAsync(cursD, 0, (size_t)N * 4, stream);
    hipMemsetAsync(cursS, 0, (size_t)N * 4, stream);

    const int bn = 256;
    const int gN  = (N + bn - 1) / bn;
    const int gE  = (E + bn - 1) / bn;
    const int nb  = (N + 511) / 512;
    const int n4  = NF / 4;
    const int g4  = (n4 + bn - 1) / bn;

    // ---- CSR build (stable by edge id) ----
    k_edge_pre<<<gE, bn, 0, stream>>>(dstp, srcp, dstCnt, srcCnt, E);
    k_scan1<<<nb, 512, 0, stream>>>(dstCnt, dstOff, bsD, N);
    k_scan2<<<1, 512, 0, stream>>>(bsD, nb);
    k_scan3<<<nb, 512, 0, stream>>>(dstOff, bsD, dstCnt, N, E);
    k_scan1<<<nb, 512, 0, stream>>>(srcCnt, srcOff, bsS, N);
    k_scan2<<<1, 512, 0, stream>>>(bsS, nb);
    k_scan3<<<nb, 512, 0, stream>>>(srcOff, bsS, srcCnt, N, E);
    k_fill<<<gE, bn, 0, stream>>>(dstp, srcp, dstOff, srcOff, cursD, cursS,
                                  dstList, srcList, E);
    k_sort<<<gN, bn, 0, stream>>>(dstOff, srcOff, dstList, srcList, N);
    k_perm<<<gE, bn, 0, stream>>>(dstList, srcList, srcp, dstp, ea,
                                  invD, slopeD, invS, E);
    k_build_leaves<<<1, 64, 0, stream>>>(NF - 1, leafOff, leafN, nLeaf);
    k_build_sched<<<16, 64, 0, stream>>>(leafN, nLeaf, lNB, lBOff, lBN, lA, lB,
                                         lDep, lOrder, lLevOff, lMaxD,
                                         uHdr, uA, uB, uDep, uOrder, uLevOff,
                                         NF - 1);
    const int* srcA = dstList;   // after k_perm
    const int* dstB = srcList;   // after k_perm

    // ---- setup: b->r, y=u*b ; p = b + dt*D1T(y) ; r=p, x=0 ; rs0 = p.p ----
    k_slope_b<<<gN, bn, 0, stream>>>(u, slopeD, dstOff, r, y, dtp, gp, N);
    k_d1tz<<<gN, bn, 0, stream>>>(dstB, dstOff, invD, srcOff, invS,
                                  y, r, p, dtp, r, x, 1, N);
    k_dot_leaf<<<DOT_NB, 256, 0, stream>>>(p, p, leafOff, leafN, nLeaf, lNB,
                                           lBOff, lBN, lA, lB, lOrder, lLevOff,
                                           lMaxD, partial);
    k_dot_fin<<<1, 256, 0, stream>>>(p, p, partial, nLeaf, uHdr, uA, uB,
                                     uOrder, uLevOff, scal, 0);

    // ---- CG loop ----
    for (int it = 0; it < CG_ITERS; ++it) {
        k_d1w<<<gN, bn, 0, stream>>>(srcA, dstOff, invD, p, u, w, y, dtp, N);
        k_d1tz<<<gN, bn, 0, stream>>>(dstB, dstOff, invD, srcOff, invS,
                                      y, w, t, dtp, (float*)0, (float*)0, 0, N);
        k_dot_leaf<<<DOT_NB, 256, 0, stream>>>(p, t, leafOff, leafN, nLeaf, lNB,
                                               lBOff, lBN, lA, lB, lOrder,
                                               lLevOff, lMaxD, partial);
        k_dot_fin<<<1, 256, 0, stream>>>(p, t, partial, nLeaf, uHdr, uA, uB,
                                         uOrder, uLevOff, scal, 1);
        k_xr_dot<<<DOT_NB, 256, 0, stream>>>(x, r, p, t, scal, leafOff, leafN,
                                             nLeaf, lNB, lBOff, lBN, lA, lB,
                                             lOrder, lLevOff, lMaxD, partial);
        k_dot_fin<<<1, 256, 0, stream>>>(r, r, partial, nLeaf, uHdr, uA, uB,
                                         uOrder, uLevOff, scal, 2);
        k_p<<<g4, bn, 0, stream>>>((float4*)p, (const float4*)r, scal, n4);
    }
}

// Round 4
// 8096.861 us; speedup vs baseline: 1.1087x; 1.1087x over previous
//
#include <hip/hip_runtime.h>
#include <math.h>
#include <stdint.h>
#include <string.h>

// PhysicsLSGStep: bitwise-faithful f32 replication of the numpy reference.
// R15:
//  - REVERT R14's float8 thread-per-node in k_d1w/k_d1tz back to R13's
//    thread-per-(node,half): the gather kernels are latency-bound; 400K
//    threads (24 waves/CU) hide latency, 200K (12/CU) did not => R14 regressed.
//  - Pairwise-tree schedule now built ON HOST (deterministic function of NF)
//    into a static Sched blob, one hipMemcpyAsync per replay (~70KB).
//    Kills k_build_leaves + k_build_sched (405us serial dispatch, occ 0.02%).
//    Leaf sizes dedupe to ~3 classes; dot kernels launch exactly NL blocks.
//  - Keep R14's 8-way base-chain dot split + k_xr_dot fusion + d1tz doInit.
// Scatter sums stay in sorted-edge-id (CSR) order; dots replay the exact
// numpy pairwise tree (level-parallel, pairings unchanged). f32 __f*_rn only.

#define F 8
#define CG_ITERS 30
#define LEAF_T 4096
#define LEAF_PAD (LEAF_T + LEAF_T / 128 + 8)
#define ENC_ADD 1024   // operand encoding: <1024 = base/leaf slot, else add t+1024
#define MAX_LEAF 1024
#define MAX_CLS 32

#define S_RS    0
#define S_ALPHA 1
#define S_BETA  2
#define S_DONE  3
#define S_DONE2 4

// padded-LDS accessor (bank-spread: +1 word every 128)
#define LV(A_, i_) A_[(i_) + ((i_) >> 7)]

struct Sched {
    int NL, uNT, uMaxD, nCls;
    int leafOff[MAX_LEAF], leafN[MAX_LEAF], cls[MAX_LEAF];
    int cNB[MAX_CLS], cMaxD[MAX_CLS];
    int cBOff[MAX_CLS][64], cBN[MAX_CLS][64];
    int cA[MAX_CLS][64], cB[MAX_CLS][64], cOrder[MAX_CLS][64];
    int cLevOff[MAX_CLS][32];
    int uA[MAX_LEAF], uB[MAX_LEAF], uOrder[MAX_LEAF], uLevOff[64];
};

// ---------------- host-side schedule build (exact replica of the device
// recursion that was in k_build_leaves / k_build_sched; integer-only) -------

static void host_build_tree(int n, int T, int* bOff, int* bN,
                            int* A, int* B, int* dep,
                            int* pNB, int* pNT, int* pMaxD) {
    int so[64], sn[64], st[64], sid[64], sdp[64];
    int sp = 0, coff = 0, cn = n, c2 = 0, t = 0, rootd = 0;
    for (;;) {
        if (cn <= T) {
            if (bOff) { bOff[c2] = coff; bN[c2] = cn; }
            int id = c2, dp = 0; c2++;
            bool fin = false;
            for (;;) {
                if (sp == 0) { rootd = dp; fin = true; break; }
                if (st[sp - 1] == 0) {
                    st[sp - 1] = 1; sid[sp - 1] = id; sdp[sp - 1] = dp;
                    int n2 = sn[sp - 1] / 2; n2 -= (n2 & 7);
                    coff = so[sp - 1] + n2; cn = sn[sp - 1] - n2;
                    break;
                } else {
                    A[t] = sid[sp - 1]; B[t] = id;  // add = stored(left)+cur(right)
                    int dA = sdp[sp - 1];
                    dp = ((dA > dp) ? dA : dp) + 1;
                    dep[t] = dp;
                    id = ENC_ADD + t; t++;
                    sp--;
                }
            }
            if (fin) break;
        } else {
            so[sp] = coff; sn[sp] = cn; st[sp] = 0; sp++;
            int n2 = cn / 2; n2 -= (n2 & 7);
            cn = n2;
        }
    }
    *pNB = c2; *pNT = t; *pMaxD = rootd;
}

static void host_bucketize(const int* dep, int NT, int maxD,
                           int* order, int* levOff) {
    int cnt[64];
    for (int d = 0; d <= maxD; ++d) cnt[d] = 0;
    for (int t = 0; t < NT; ++t) cnt[dep[t]]++;
    int run = 0;
    levOff[0] = 0;
    for (int d = 1; d <= maxD; ++d) { run += cnt[d]; levOff[d] = run; }
    int cur[64];
    for (int d = 1; d <= maxD; ++d) cur[d] = levOff[d - 1];
    for (int t = 0; t < NT; ++t) { int d = dep[t]; order[cur[d]++] = t; }
}

static void build_sched_host(int n, Sched* s) {   // n = NF-1
    static int uDep[MAX_LEAF];
    host_build_tree(n, LEAF_T, s->leafOff, s->leafN, s->uA, s->uB, uDep,
                    &s->NL, &s->uNT, &s->uMaxD);
    host_bucketize(uDep, s->uNT, s->uMaxD, s->uOrder, s->uLevOff);
    s->nCls = 0;
    int clsN[MAX_CLS];
    int dep[64];
    for (int j = 0; j < s->NL; ++j) {
        int c = -1;
        for (int k = 0; k < s->nCls; ++k)
            if (clsN[k] == s->leafN[j]) { c = k; break; }
        if (c < 0 && s->nCls < MAX_CLS) {
            c = s->nCls++;
            clsN[c] = s->leafN[j];
            int NB, NT, maxD;
            host_build_tree(s->leafN[j], 128, s->cBOff[c], s->cBN[c],
                            s->cA[c], s->cB[c], dep, &NB, &NT, &maxD);
            s->cNB[c] = NB; s->cMaxD[c] = maxD;
            host_bucketize(dep, NT, maxD, s->cOrder[c], s->cLevOff[c]);
        }
        s->cls[j] = c;
    }
}

// ---------------- device ----------------

__device__ __forceinline__ float dt_eff_of(const float* dtp) {
    return fminf(fmaxf(dtp[0], 0.02f), 2.0f);
}

__device__ __forceinline__ int slotOf(int e, int NB) {
    return (e < ENC_ADD) ? e : (NB + (e - ENC_ADD));
}

// shared tail of the leaf-dot: 8-way base chains + exact combine + tree eval.
// sA/sB may alias (r.r dot). blockDim = 256.
__device__ __forceinline__ void dot_eval(const float* sA, const float* sB,
                                         float* sChain, float* sVal,
                                         int lane, int NB,
                                         const int* __restrict__ bOff,
                                         const int* __restrict__ bN,
                                         const int* __restrict__ A,
                                         const int* __restrict__ Bb,
                                         const int* __restrict__ order,
                                         const int* __restrict__ levOff,
                                         int maxD,
                                         float* __restrict__ partial, int j) {
    // phase A: chain r_j of base block bb on lane bb*8+j (independent chains)
    int bb = lane >> 3, jj = lane & 7;
    if (bb < NB) {
        int off = bOff[bb], n = bN[bb];
        if (n >= 8) {
            int lim = n - (n & 7);
            float rr = __fmul_rn(LV(sA, off + jj), LV(sB, off + jj));
            for (int e = jj + 8; e < lim; e += 8)
                rr = __fadd_rn(rr, __fmul_rn(LV(sA, off + e), LV(sB, off + e)));
            sChain[bb * 8 + jj] = rr;
        }
    }
    __syncthreads();
    // phase B: exact combine tree + exact tail per base block
    if (lane < NB) {
        int off = bOff[lane], n = bN[lane];
        float res;
        if (n < 8) {
            res = 0.f;
            for (int e = 0; e < n; ++e)
                res = __fadd_rn(res, __fmul_rn(LV(sA, off + e), LV(sB, off + e)));
        } else {
            int lim = n - (n & 7);
            const float* c = sChain + lane * 8;
            res = __fadd_rn(__fadd_rn(__fadd_rn(c[0], c[1]), __fadd_rn(c[2], c[3])),
                            __fadd_rn(__fadd_rn(c[4], c[5]), __fadd_rn(c[6], c[7])));
            for (int e = lim; e < n; ++e)
                res = __fadd_rn(res, __fmul_rn(LV(sA, off + e), LV(sB, off + e)));
        }
        sVal[lane] = res;
    }
    __syncthreads();
    // phase C: level-parallel replay of the leaf combine tree
    for (int d = 1; d <= maxD; ++d) {
        int s0 = levOff[d - 1], s1 = levOff[d];
        for (int s = s0 + lane; s < s1; s += 256) {
            int tt = order[s];
            sVal[NB + tt] = __fadd_rn(sVal[slotOf(A[tt], NB)],
                                      sVal[slotOf(Bb[tt], NB)]);
        }
        __syncthreads();
    }
    if (lane == 0) partial[j] = (NB > 1) ? sVal[NB + NB - 2] : sVal[0];
}

// per-leaf dot partial (a.b). grid = NL blocks, 256 threads.
__global__ void k_dot_leaf(const float* __restrict__ a, const float* __restrict__ b,
                           const Sched* __restrict__ sc, float* __restrict__ partial) {
    __shared__ float sA[LEAF_PAD], sB[LEAF_PAD];
    __shared__ float sChain[512];
    __shared__ float sVal[160];
    int j = blockIdx.x, lane = threadIdx.x;
    int P = sc->leafOff[j] + 1, nn = sc->leafN[j];
    for (int g = lane; g < nn; g += 256) {
        float av = a[P + g], bv = b[P + g];
        int m = g + (g >> 7);
        sA[m] = av; sB[m] = bv;
    }
    __syncthreads();
    int c = sc->cls[j];
    dot_eval(sA, sB, sChain, sVal, lane, sc->cNB[c], sc->cBOff[c], sc->cBN[c],
             sc->cA[c], sc->cB[c], sc->cOrder[c], sc->cLevOff[c], sc->cMaxD[c],
             partial, j);
}

// fused: x += a*p ; r -= a*z (guarded by done_old) over this leaf's range,
// then leaf dot of the fresh r. Element 0 handled by block 0.
__global__ void k_xr_dot(float* __restrict__ x, float* __restrict__ r,
                         const float* __restrict__ p, const float* __restrict__ z,
                         const float* __restrict__ scal,
                         const Sched* __restrict__ sc, float* __restrict__ partial) {
    __shared__ float sA[LEAF_PAD];
    __shared__ float sChain[512];
    __shared__ float sVal[160];
    int j = blockIdx.x, lane = threadIdx.x;
    int P = sc->leafOff[j] + 1, nn = sc->leafN[j];
    int active = (scal[S_DONE] == 0.f);
    float al = scal[S_ALPHA];
    if (j == 0 && lane == 0 && active) {
        x[0] = __fadd_rn(x[0], __fmul_rn(al, p[0]));
        r[0] = __fsub_rn(r[0], __fmul_rn(al, z[0]));
    }
    for (int g = lane; g < nn; g += 256) {
        int q = P + g;
        float rv = r[q];
        if (active) {
            float xv = x[q], pv = p[q], zv = z[q];
            x[q] = __fadd_rn(xv, __fmul_rn(al, pv));
            rv = __fsub_rn(rv, __fmul_rn(al, zv));
            r[q] = rv;
        }
        sA[g + (g >> 7)] = rv;
    }
    __syncthreads();
    int c = sc->cls[j];
    dot_eval(sA, sA, sChain, sVal, lane, sc->cNB[c], sc->cBOff[c], sc->cBN[c],
             sc->cA[c], sc->cB[c], sc->cOrder[c], sc->cLevOff[c], sc->cMaxD[c],
             partial, j);
}

// upper combine (level-parallel) + scalar update. 1 block, 256 threads.
__global__ void k_dot_fin(const float* __restrict__ a, const float* __restrict__ b,
                          const float* __restrict__ partial,
                          const Sched* __restrict__ sc, float* __restrict__ scal,
                          int mode, int NL) {
    __shared__ float sVal[2048];
    int lane = threadIdx.x;
    int NT = sc->uNT, maxD = sc->uMaxD;
    for (int k = lane; k < NL; k += 256) sVal[k] = partial[k];
    __syncthreads();
    for (int d = 1; d <= maxD; ++d) {
        int s0 = sc->uLevOff[d - 1], s1 = sc->uLevOff[d];
        for (int s = s0 + lane; s < s1; s += 256) {
            int tt = sc->uOrder[s];
            sVal[NL + tt] = __fadd_rn(sVal[slotOf(sc->uA[tt], NL)],
                                      sVal[slotOf(sc->uB[tt], NL)]);
        }
        __syncthreads();
    }
    if (lane != 0) return;
    float res = (NT > 0) ? sVal[NL + NT - 1] : sVal[0];
    res = __fadd_rn(__fmul_rn(a[0], b[0]), res);   // first-element init
    if (mode == 0) {
        scal[S_RS] = res; scal[S_DONE] = 0.f; scal[S_DONE2] = 0.f;
    } else if (mode == 1) {
        scal[S_DONE] = scal[S_DONE2];  // done_old for this iteration
        scal[S_ALPHA] = __fdiv_rn(scal[S_RS], __fadd_rn(res, (float)1e-12));
    } else {
        float rs1 = res;
        scal[S_BETA] = __fdiv_rn(rs1, __fadd_rn(scal[S_RS], (float)1e-12));
        float dn = scal[S_DONE];
        if (dn == 0.f) scal[S_RS] = rs1;
        scal[S_DONE2] = (dn != 0.f || __fsqrt_rn(rs1) <= (float)1e-4) ? 1.f : 0.f;
    }
}

// ---------- CSR build (stable in edge order) ----------

__global__ void k_edge_pre(const int* __restrict__ dst, const int* __restrict__ src,
                           int* __restrict__ dstCnt, int* __restrict__ srcCnt, int E) {
    int e = blockIdx.x * blockDim.x + threadIdx.x;
    if (e >= E) return;
    atomicAdd(&dstCnt[dst[e]], 1);
    atomicAdd(&srcCnt[src[e]], 1);
}

__global__ void k_scan1(const int* __restrict__ cnt, int* __restrict__ incl,
                        int* __restrict__ bsums, int N) {
    __shared__ int sm[512];
    int i = blockIdx.x * 512 + threadIdx.x;
    sm[threadIdx.x] = (i < N) ? cnt[i] : 0;
    __syncthreads();
    for (int off = 1; off < 512; off <<= 1) {
        int t = (threadIdx.x >= off) ? sm[threadIdx.x - off] : 0;
        __syncthreads();
        sm[threadIdx.x] += t;
        __syncthreads();
    }
    if (i < N) incl[i] = sm[threadIdx.x];
    if (threadIdx.x == 511) bsums[blockIdx.x] = sm[511];
}

__global__ void k_scan2(int* __restrict__ bsums, int nb) {
    __shared__ int sm[512];
    sm[threadIdx.x] = (threadIdx.x < nb) ? bsums[threadIdx.x] : 0;
    __syncthreads();
    for (int off = 1; off < 512; off <<= 1) {
        int t = (threadIdx.x >= off) ? sm[threadIdx.x - off] : 0;
        __syncthreads();
        sm[threadIdx.x] += t;
        __syncthreads();
    }
    if (threadIdx.x < nb) bsums[threadIdx.x] = sm[threadIdx.x];
}

__global__ void k_scan3(int* __restrict__ off, const int* __restrict__ bsums,
                        const int* __restrict__ cnt, int N, int E) {
    int i = blockIdx.x * 512 + threadIdx.x;
    if (i < N) {
        int add = (blockIdx.x > 0) ? bsums[blockIdx.x - 1] : 0;
        off[i] = off[i] + add - cnt[i];  // exclusive
    }
    if (i == 0) off[N] = E;
}

__global__ void k_fill(const int* __restrict__ dst, const int* __restrict__ src,
                       const int* __restrict__ dstOff, const int* __restrict__ srcOff,
                       int* __restrict__ cursD, int* __restrict__ cursS,
                       int* __restrict__ dstList, int* __restrict__ srcList, int E) {
    int e = blockIdx.x * blockDim.x + threadIdx.x;
    if (e >= E) return;
    int d = dst[e];
    dstList[dstOff[d] + atomicAdd(&cursD[d], 1)] = e;
    int s0 = src[e];
    srcList[srcOff[s0] + atomicAdd(&cursS[s0], 1)] = e;
}

__device__ __forceinline__ void insort(int* L, int lo, int hi) {
    for (int a = lo + 1; a < hi; ++a) {
        int key = L[a]; int b = a - 1;
        while (b >= lo && L[b] > key) { L[b + 1] = L[b]; b--; }
        L[b + 1] = key;
    }
}

__global__ void k_sort(const int* __restrict__ dstOff, const int* __restrict__ srcOff,
                       int* __restrict__ dstList, int* __restrict__ srcList, int N) {
    int i = blockIdx.x * blockDim.x + threadIdx.x;
    if (i >= N) return;
    insort(dstList, dstOff[i], dstOff[i + 1]);
    insort(srcList, srcOff[i], srcOff[i + 1]);
}

// Permute per-edge operands into CSR order, IN PLACE over the lists.
__global__ void k_perm(int* dstList, int* srcList,
                       const int* __restrict__ srcp, const int* __restrict__ dstp,
                       const float* __restrict__ ea,
                       float* __restrict__ invD, float* __restrict__ slopeD,
                       float* __restrict__ invS, int E) {
    int k = blockIdx.x * blockDim.x + threadIdx.x;
    if (k >= E) return;
    int e  = dstList[k];
    int e2 = srcList[k];
    float dx  = fmaxf(ea[2 * e], 1e-6f);
    float dx2 = fmaxf(ea[2 * e2], 1e-6f);
    int sA_ = srcp[e];
    int dB_ = dstp[e2];
    float iD = __fdiv_rn(1.f, dx);
    float sD = __fdiv_rn(ea[2 * e + 1], dx);
    float iS = __fdiv_rn(1.f, dx2);
    dstList[k] = sA_;    // srcA
    srcList[k] = dB_;    // dstB
    invD[k] = iD; slopeD[k] = sD; invS[k] = iS;
}

// ---------- physics kernels (exact np op order, f32 sequential) ----------

__global__ void k_slope_b(const float* __restrict__ u, const float* __restrict__ slopeD,
                          const int* __restrict__ dstOff,
                          float* __restrict__ r, float* __restrict__ y,
                          const float* __restrict__ dtp, const float* __restrict__ gp,
                          int N) {
    int i = blockIdx.x * blockDim.x + threadIdx.x;
    if (i >= N) return;
    float dtg = __fmul_rn(dt_eff_of(dtp), gp[0]);
    float sn = 0.f;
    int k0 = dstOff[i], k1 = dstOff[i + 1];
    for (int k = k0; k < k1; ++k) sn = __fadd_rn(sn, slopeD[k]);
    float ms = __fmul_rn(dtg, sn);
    const float4* u4 = (const float4*)u;
    float4* r4 = (float4*)r;
    float4* y4 = (float4*)y;
    #pragma unroll
    for (int hh = 0; hh < 2; ++hh) {
        float4 uv = u4[i * 2 + hh];
        float4 bv;
        bv.x = __fsub_rn(uv.x, ms);
        bv.y = __fsub_rn(uv.y, ms);
        bv.z = __fsub_rn(uv.z, ms);
        bv.w = __fsub_rn(uv.w, ms);
        r4[i * 2 + hh] = bv;
        float4 yv;
        yv.x = __fmul_rn(uv.x, bv.x);
        yv.y = __fmul_rn(uv.y, bv.y);
        yv.z = __fmul_rn(uv.z, bv.z);
        yv.w = __fmul_rn(uv.w, bv.w);
        y4[i * 2 + hh] = yv;
    }
}

// D1_T via y (= u*input); out = base + dt*acc. thread = (node, f-half).
// doInit: also rInit := out, xInit := 0 (replaces k_init). Setup only.
__global__ void k_d1tz(const int* __restrict__ dstB, const int* __restrict__ dstOff,
                       const float* __restrict__ invD, const int* __restrict__ srcOff,
                       const float* __restrict__ invS, const float* __restrict__ y,
                       const float* __restrict__ base, float* __restrict__ out,
                       const float* __restrict__ dtp,
                       float* __restrict__ rInit, float* __restrict__ xInit,
                       int doInit, int N2) {
    int idx2 = blockIdx.x * blockDim.x + threadIdx.x;
    if (idx2 >= N2) return;
    int i = idx2 >> 1, h = idx2 & 1;
    const float4* y4 = (const float4*)y;
    float4 uy = y4[idx2];
    float4 acc = make_float4(0.f, 0.f, 0.f, 0.f);
    int k0 = dstOff[i], k1 = dstOff[i + 1];
    for (int k = k0; k < k1; ++k) {
        float iv = invD[k];
        acc.x = __fadd_rn(acc.x, __fmul_rn(uy.x, iv));
        acc.y = __fadd_rn(acc.y, __fmul_rn(uy.y, iv));
        acc.z = __fadd_rn(acc.z, __fmul_rn(uy.z, iv));
        acc.w = __fadd_rn(acc.w, __fmul_rn(uy.w, iv));
    }
    k0 = srcOff[i]; k1 = srcOff[i + 1];
    for (int k = k0; k < k1; ++k) {
        int d = dstB[k];
        float iv = invS[k];
        float4 yd = y4[d * 2 + h];
        float t0 = __fmul_rn(yd.x, iv); acc.x = __fadd_rn(acc.x, -t0);
        float t1 = __fmul_rn(yd.y, iv); acc.y = __fadd_rn(acc.y, -t1);
        float t2 = __fmul_rn(yd.z, iv); acc.z = __fadd_rn(acc.z, -t2);
        float t3 = __fmul_rn(yd.w, iv); acc.w = __fadd_rn(acc.w, -t3);
    }
    float dt = dt_eff_of(dtp);
    float4 bs = ((const float4*)base)[idx2];
    float4 ov;
    ov.x = __fadd_rn(bs.x, __fmul_rn(dt, acc.x));
    ov.y = __fadd_rn(bs.y, __fmul_rn(dt, acc.y));
    ov.z = __fadd_rn(bs.z, __fmul_rn(dt, acc.z));
    ov.w = __fadd_rn(bs.w, __fmul_rn(dt, acc.w));
    ((float4*)out)[idx2] = ov;
    if (doInit) {
        ((float4*)rInit)[idx2] = ov;
        ((float4*)xInit)[idx2] = make_float4(0.f, 0.f, 0.f, 0.f);
    }
}

// D1(p) fused with w = p + dt*(u*t) and y = u*w. thread = (node, f-half).
__global__ void k_d1w(const int* __restrict__ srcA, const int* __restrict__ dstOff,
                      const float* __restrict__ invD, const float* __restrict__ pv,
                      const float* __restrict__ u,
                      float* __restrict__ w, float* __restrict__ y,
                      const float* __restrict__ dtp, int N2) {
    int idx2 = blockIdx.x * blockDim.x + threadIdx.x;
    if (idx2 >= N2) return;
    int i = idx2 >> 1, h = idx2 & 1;
    const float4* pv4 = (const float4*)pv;
    float4 pi = pv4[idx2];
    float4 acc = make_float4(0.f, 0.f, 0.f, 0.f);
    int k0 = dstOff[i], k1 = dstOff[i + 1];
    for (int k = k0; k < k1; ++k) {
        int s = srcA[k];
        float iv = invD[k];
        float4 ps = pv4[s * 2 + h];
        acc.x = __fadd_rn(acc.x, __fmul_rn(__fsub_rn(pi.x, ps.x), iv));
        acc.y = __fadd_rn(acc.y, __fmul_rn(__fsub_rn(pi.y, ps.y), iv));
        acc.z = __fadd_rn(acc.z, __fmul_rn(__fsub_rn(pi.z, ps.z), iv));
        acc.w = __fadd_rn(acc.w, __fmul_rn(__fsub_rn(pi.w, ps.w), iv));
    }
    float dt = dt_eff_of(dtp);
    float4 uv = ((const float4*)u)[idx2];
    float4 wv;
    wv.x = __fadd_rn(pi.x, __fmul_rn(dt, __fmul_rn(uv.x, acc.x)));
    wv.y = __fadd_rn(pi.y, __fmul_rn(dt, __fmul_rn(uv.y, acc.y)));
    wv.z = __fadd_rn(pi.z, __fmul_rn(dt, __fmul_rn(uv.z, acc.z)));
    wv.w = __fadd_rn(pi.w, __fmul_rn(dt, __fmul_rn(uv.w, acc.w)));
    ((float4*)w)[idx2] = wv;
    float4 yv;
    yv.x = __fmul_rn(uv.x, wv.x);
    yv.y = __fmul_rn(uv.y, wv.y);
    yv.z = __fmul_rn(uv.z, wv.z);
    yv.w = __fmul_rn(uv.w, wv.w);
    ((float4*)y)[idx2] = yv;
}

// p = r + beta*p   (guarded by done_old)  float4
__global__ void k_p(float4* __restrict__ p4, const float4* __restrict__ r4,
                    const float* __restrict__ scal, int n4) {
    int i = blockIdx.x * blockDim.x + threadIdx.x;
    if (i >= n4) return;
    if (scal[S_DONE] != 0.f) return;
    float be = scal[S_BETA];
    float4 pv = p4[i], rv = r4[i];
    pv.x = __fadd_rn(rv.x, __fmul_rn(be, pv.x));
    pv.y = __fadd_rn(rv.y, __fmul_rn(be, pv.y));
    pv.z = __fadd_rn(rv.z, __fmul_rn(be, pv.z));
    pv.w = __fadd_rn(rv.w, __fmul_rn(be, pv.w));
    p4[i] = pv;
}

extern "C" void kernel_launch(void* const* d_in, const int* in_sizes, int n_in,
                              void* d_out, int out_size, void* d_ws, size_t ws_size,
                              hipStream_t stream) {
    const float* u   = (const float*)d_in[0];
    const int*   ei  = (const int*)d_in[1];
    const float* ea  = (const float*)d_in[2];
    const float* dtp = (const float*)d_in[3];
    const float* gp  = (const float*)d_in[4];

    const int NF = in_sizes[0];        // 1,600,000
    const int N  = NF / F;             // 200,000
    const int E  = in_sizes[2] / 2;    // 3,200,000
    const int* srcp = ei;
    const int* dstp = ei + E;

    // host-side pairwise-tree schedule (deterministic fn of NF; static so the
    // graph-replayed hipMemcpyAsync source stays valid)
    static Sched h_sched;
    build_sched_host(NF - 1, &h_sched);
    const int NL = h_sched.NL;

    char* wp = (char*)d_ws;
    float* scal    = (float*)wp; wp += 64 * 4;
    float* r       = (float*)wp; wp += (size_t)NF * 4;
    float* p       = (float*)wp; wp += (size_t)NF * 4;
    float* t       = (float*)wp; wp += (size_t)NF * 4;   // z
    float* w       = (float*)wp; wp += (size_t)NF * 4;
    float* y       = (float*)wp; wp += (size_t)NF * 4;   // u*w / u*b
    int*   dstList = (int*)wp;   wp += (size_t)E * 4;    // becomes srcA after k_perm
    int*   srcList = (int*)wp;   wp += (size_t)E * 4;    // becomes dstB after k_perm
    float* invD    = (float*)wp; wp += (size_t)E * 4;
    float* invS    = (float*)wp; wp += (size_t)E * 4;
    float* slopeD  = (float*)wp; wp += (size_t)E * 4;
    int*   dstOff  = (int*)wp;   wp += (size_t)(N + 1) * 4;
    int*   srcOff  = (int*)wp;   wp += (size_t)(N + 1) * 4;
    int*   dstCnt  = (int*)wp;   wp += (size_t)N * 4;
    int*   srcCnt  = (int*)wp;   wp += (size_t)N * 4;
    int*   cursD   = (int*)wp;   wp += (size_t)N * 4;
    int*   cursS   = (int*)wp;   wp += (size_t)N * 4;
    int*   bsD     = (int*)wp;   wp += 512 * 4;
    int*   bsS     = (int*)wp;   wp += 512 * 4;
    float* partial = (float*)wp; wp += 2048 * 4;
    wp = (char*)(((uintptr_t)wp + 255) & ~(uintptr_t)255);
    Sched* d_sched = (Sched*)wp; wp += (sizeof(Sched) + 255) & ~(size_t)255;
    float* x = (float*)d_out;

    hipMemcpyAsync(d_sched, &h_sched, sizeof(Sched), hipMemcpyHostToDevice,
                   stream);
    hipMemsetAsync(scal, 0, 64 * 4, stream);
    hipMemsetAsync(dstCnt, 0, (size_t)N * 4, stream);
    hipMemsetAsync(srcCnt, 0, (size_t)N * 4, stream);
    hipMemsetAsync(cursD, 0, (size_t)N * 4, stream);
    hipMemsetAsync(cursS, 0, (size_t)N * 4, stream);

    const int bn = 256;
    const int gN  = (N + bn - 1) / bn;
    const int gE  = (E + bn - 1) / bn;
    const int nb  = (N + 511) / 512;
    const int n4  = NF / 4;
    const int g4  = (n4 + bn - 1) / bn;
    const int N2  = NF / 4;            // (node, feature-half) threads
    const int g2  = (N2 + bn - 1) / bn;

    // ---- CSR build (stable by edge id) ----
    k_edge_pre<<<gE, bn, 0, stream>>>(dstp, srcp, dstCnt, srcCnt, E);
    k_scan1<<<nb, 512, 0, stream>>>(dstCnt, dstOff, bsD, N);
    k_scan2<<<1, 512, 0, stream>>>(bsD, nb);
    k_scan3<<<nb, 512, 0, stream>>>(dstOff, bsD, dstCnt, N, E);
    k_scan1<<<nb, 512, 0, stream>>>(srcCnt, srcOff, bsS, N);
    k_scan2<<<1, 512, 0, stream>>>(bsS, nb);
    k_scan3<<<nb, 512, 0, stream>>>(srcOff, bsS, srcCnt, N, E);
    k_fill<<<gE, bn, 0, stream>>>(dstp, srcp, dstOff, srcOff, cursD, cursS,
                                  dstList, srcList, E);
    k_sort<<<gN, bn, 0, stream>>>(dstOff, srcOff, dstList, srcList, N);
    k_perm<<<gE, bn, 0, stream>>>(dstList, srcList, srcp, dstp, ea,
                                  invD, slopeD, invS, E);
    const int* srcA = dstList;   // after k_perm
    const int* dstB = srcList;   // after k_perm

    // ---- setup: b->r, y=u*b ; p = b + dt*D1T(y) ; r=p, x=0 ; rs0 = p.p ----
    k_slope_b<<<gN, bn, 0, stream>>>(u, slopeD, dstOff, r, y, dtp, gp, N);
    k_d1tz<<<g2, bn, 0, stream>>>(dstB, dstOff, invD, srcOff, invS,
                                  y, r, p, dtp, r, x, 1, N2);
    k_dot_leaf<<<NL, 256, 0, stream>>>(p, p, d_sched, partial);
    k_dot_fin<<<1, 256, 0, stream>>>(p, p, partial, d_sched, scal, 0, NL);

    // ---- CG loop ----
    for (int it = 0; it < CG_ITERS; ++it) {
        k_d1w<<<g2, bn, 0, stream>>>(srcA, dstOff, invD, p, u, w, y, dtp, N2);
        k_d1tz<<<g2, bn, 0, stream>>>(dstB, dstOff, invD, srcOff, invS,
                                      y, w, t, dtp, (float*)0, (float*)0, 0, N2);
        k_dot_leaf<<<NL, 256, 0, stream>>>(p, t, d_sched, partial);
        k_dot_fin<<<1, 256, 0, stream>>>(p, t, partial, d_sched, scal, 1, NL);
        k_xr_dot<<<NL, 256, 0, stream>>>(x, r, p, t, scal, d_sched, partial);
        k_dot_fin<<<1, 256, 0, stream>>>(r, r, partial, d_sched, scal, 2, NL);
        k_p<<<g4, bn, 0, stream>>>((float4*)p, (const float4*)r, scal, n4);
    }
}

// Round 5
// 8057.504 us; speedup vs baseline: 1.1141x; 1.0049x over previous
//
#include <hip/hip_runtime.h>
#include <math.h>
#include <stdint.h>
#include <string.h>

// PhysicsLSGStep: bitwise-faithful f32 replication of the numpy reference.
// R16 (on top of R15's host-built pairwise-tree schedule):
//  - The two 1-block k_dot_fin dispatches per CG iteration (full-GPU
//    serialization bubbles) are FUSED into their consumers: every block of
//    k_xr_dot redundantly upper-combines partial1 -> alpha; every block of
//    k_p_fin upper-combines partial2 -> beta and block 0 writes the next
//    iteration's scalars. Identical float ops => bit-identical.
//  - Scalar state uses per-iteration slots (RS[it] @ scal[8+it], DONE[it] @
//    scal[64+it]) so no kernel reads a cell another block of the same
//    dispatch writes. Loop: 7 -> 5 dispatches/iter.
// Scatter sums stay in sorted-edge-id (CSR) order; dots replay the exact
// numpy pairwise tree (level-parallel, pairings unchanged). f32 __f*_rn only.

#define F 8
#define CG_ITERS 30
#define LEAF_T 4096
#define LEAF_PAD (LEAF_T + LEAF_T / 128 + 8)
#define ENC_ADD 1024   // operand encoding: <1024 = base/leaf slot, else add t+1024
#define MAX_LEAF 1024
#define MAX_CLS 32

// scal slots: RS[it] = scal[8+it], DONE[it] = scal[64+it]  (it = 0..CG_ITERS)

// padded-LDS accessor (bank-spread: +1 word every 128)
#define LV(A_, i_) A_[(i_) + ((i_) >> 7)]

struct Sched {
    int NL, uNT, uMaxD, nCls;
    int leafOff[MAX_LEAF], leafN[MAX_LEAF], cls[MAX_LEAF];
    int cNB[MAX_CLS], cMaxD[MAX_CLS];
    int cBOff[MAX_CLS][64], cBN[MAX_CLS][64];
    int cA[MAX_CLS][64], cB[MAX_CLS][64], cOrder[MAX_CLS][64];
    int cLevOff[MAX_CLS][32];
    int uA[MAX_LEAF], uB[MAX_LEAF], uOrder[MAX_LEAF], uLevOff[64];
};

// ---------------- host-side schedule build (exact integer replica) --------

static void host_build_tree(int n, int T, int* bOff, int* bN,
                            int* A, int* B, int* dep,
                            int* pNB, int* pNT, int* pMaxD) {
    int so[64], sn[64], st[64], sid[64], sdp[64];
    int sp = 0, coff = 0, cn = n, c2 = 0, t = 0, rootd = 0;
    for (;;) {
        if (cn <= T) {
            if (bOff) { bOff[c2] = coff; bN[c2] = cn; }
            int id = c2, dp = 0; c2++;
            bool fin = false;
            for (;;) {
                if (sp == 0) { rootd = dp; fin = true; break; }
                if (st[sp - 1] == 0) {
                    st[sp - 1] = 1; sid[sp - 1] = id; sdp[sp - 1] = dp;
                    int n2 = sn[sp - 1] / 2; n2 -= (n2 & 7);
                    coff = so[sp - 1] + n2; cn = sn[sp - 1] - n2;
                    break;
                } else {
                    A[t] = sid[sp - 1]; B[t] = id;  // add = stored(left)+cur(right)
                    int dA = sdp[sp - 1];
                    dp = ((dA > dp) ? dA : dp) + 1;
                    dep[t] = dp;
                    id = ENC_ADD + t; t++;
                    sp--;
                }
            }
            if (fin) break;
        } else {
            so[sp] = coff; sn[sp] = cn; st[sp] = 0; sp++;
            int n2 = cn / 2; n2 -= (n2 & 7);
            cn = n2;
        }
    }
    *pNB = c2; *pNT = t; *pMaxD = rootd;
}

static void host_bucketize(const int* dep, int NT, int maxD,
                           int* order, int* levOff) {
    int cnt[64];
    for (int d = 0; d <= maxD; ++d) cnt[d] = 0;
    for (int t = 0; t < NT; ++t) cnt[dep[t]]++;
    int run = 0;
    levOff[0] = 0;
    for (int d = 1; d <= maxD; ++d) { run += cnt[d]; levOff[d] = run; }
    int cur[64];
    for (int d = 1; d <= maxD; ++d) cur[d] = levOff[d - 1];
    for (int t = 0; t < NT; ++t) { int d = dep[t]; order[cur[d]++] = t; }
}

static void build_sched_host(int n, Sched* s) {   // n = NF-1
    static int uDep[MAX_LEAF];
    host_build_tree(n, LEAF_T, s->leafOff, s->leafN, s->uA, s->uB, uDep,
                    &s->NL, &s->uNT, &s->uMaxD);
    host_bucketize(uDep, s->uNT, s->uMaxD, s->uOrder, s->uLevOff);
    s->nCls = 0;
    int clsN[MAX_CLS];
    int dep[64];
    for (int j = 0; j < s->NL; ++j) {
        int c = -1;
        for (int k = 0; k < s->nCls; ++k)
            if (clsN[k] == s->leafN[j]) { c = k; break; }
        if (c < 0 && s->nCls < MAX_CLS) {
            c = s->nCls++;
            clsN[c] = s->leafN[j];
            int NB, NT, maxD;
            host_build_tree(s->leafN[j], 128, s->cBOff[c], s->cBN[c],
                            s->cA[c], s->cB[c], dep, &NB, &NT, &maxD);
            s->cNB[c] = NB; s->cMaxD[c] = maxD;
            host_bucketize(dep, NT, maxD, s->cOrder[c], s->cLevOff[c]);
        }
        s->cls[j] = c;
    }
}

// ---------------- device ----------------

__device__ __forceinline__ float dt_eff_of(const float* dtp) {
    return fminf(fmaxf(dtp[0], 0.02f), 2.0f);
}

__device__ __forceinline__ int slotOf(int e, int NB) {
    return (e < ENC_ADD) ? e : (NB + (e - ENC_ADD));
}

// level-parallel upper-tree combine of partial[0..NL) into sU; returns root
// on all lanes (after final barrier). blockDim = 256.
__device__ __forceinline__ float combine_upper(const float* __restrict__ partial,
                                               const Sched* __restrict__ sc,
                                               float* sU, int lane) {
    int NL = sc->NL, NT = sc->uNT, maxD = sc->uMaxD;
    for (int k = lane; k < NL; k += 256) sU[k] = partial[k];
    __syncthreads();
    for (int d = 1; d <= maxD; ++d) {
        int s0 = sc->uLevOff[d - 1], s1 = sc->uLevOff[d];
        for (int s = s0 + lane; s < s1; s += 256) {
            int tt = sc->uOrder[s];
            sU[NL + tt] = __fadd_rn(sU[slotOf(sc->uA[tt], NL)],
                                    sU[slotOf(sc->uB[tt], NL)]);
        }
        __syncthreads();
    }
    return (NT > 0) ? sU[NL + NT - 1] : sU[0];
}

// shared tail of the leaf-dot: 8-way base chains + exact combine + tree eval.
// sA/sB may alias (r.r dot). blockDim = 256.
__device__ __forceinline__ void dot_eval(const float* sA, const float* sB,
                                         float* sChain, float* sVal,
                                         int lane, int NB,
                                         const int* __restrict__ bOff,
                                         const int* __restrict__ bN,
                                         const int* __restrict__ A,
                                         const int* __restrict__ Bb,
                                         const int* __restrict__ order,
                                         const int* __restrict__ levOff,
                                         int maxD,
                                         float* __restrict__ partial, int j) {
    // phase A: chain r_j of base block bb on lane bb*8+j (independent chains)
    int bb = lane >> 3, jj = lane & 7;
    if (bb < NB) {
        int off = bOff[bb], n = bN[bb];
        if (n >= 8) {
            int lim = n - (n & 7);
            float rr = __fmul_rn(LV(sA, off + jj), LV(sB, off + jj));
            for (int e = jj + 8; e < lim; e += 8)
                rr = __fadd_rn(rr, __fmul_rn(LV(sA, off + e), LV(sB, off + e)));
            sChain[bb * 8 + jj] = rr;
        }
    }
    __syncthreads();
    // phase B: exact combine tree + exact tail per base block
    if (lane < NB) {
        int off = bOff[lane], n = bN[lane];
        float res;
        if (n < 8) {
            res = 0.f;
            for (int e = 0; e < n; ++e)
                res = __fadd_rn(res, __fmul_rn(LV(sA, off + e), LV(sB, off + e)));
        } else {
            int lim = n - (n & 7);
            const float* c = sChain + lane * 8;
            res = __fadd_rn(__fadd_rn(__fadd_rn(c[0], c[1]), __fadd_rn(c[2], c[3])),
                            __fadd_rn(__fadd_rn(c[4], c[5]), __fadd_rn(c[6], c[7])));
            for (int e = lim; e < n; ++e)
                res = __fadd_rn(res, __fmul_rn(LV(sA, off + e), LV(sB, off + e)));
        }
        sVal[lane] = res;
    }
    __syncthreads();
    // phase C: level-parallel replay of the leaf combine tree
    for (int d = 1; d <= maxD; ++d) {
        int s0 = levOff[d - 1], s1 = levOff[d];
        for (int s = s0 + lane; s < s1; s += 256) {
            int tt = order[s];
            sVal[NB + tt] = __fadd_rn(sVal[slotOf(A[tt], NB)],
                                      sVal[slotOf(Bb[tt], NB)]);
        }
        __syncthreads();
    }
    if (lane == 0) partial[j] = (NB > 1) ? sVal[NB + NB - 2] : sVal[0];
}

// per-leaf dot partial (a.b). grid = NL blocks, 256 threads.
__global__ void k_dot_leaf(const float* __restrict__ a, const float* __restrict__ b,
                           const Sched* __restrict__ sc, float* __restrict__ partial) {
    __shared__ float sA[LEAF_PAD], sB[LEAF_PAD];
    __shared__ float sChain[512];
    __shared__ float sVal[160];
    int j = blockIdx.x, lane = threadIdx.x;
    int P = sc->leafOff[j] + 1, nn = sc->leafN[j];
    for (int g = lane; g < nn; g += 256) {
        float av = a[P + g], bv = b[P + g];
        int m = g + (g >> 7);
        sA[m] = av; sB[m] = bv;
    }
    __syncthreads();
    int c = sc->cls[j];
    dot_eval(sA, sB, sChain, sVal, lane, sc->cNB[c], sc->cBOff[c], sc->cBN[c],
             sc->cA[c], sc->cB[c], sc->cOrder[c], sc->cLevOff[c], sc->cMaxD[c],
             partial, j);
}

// setup-only: RS[0] = p.p from partial + first-element term. 1 block.
__global__ void k_dot_rs0(const float* __restrict__ a,
                          const float* __restrict__ partial,
                          const Sched* __restrict__ sc, float* __restrict__ scal) {
    __shared__ float sU[2048];
    int lane = threadIdx.x;
    float res = combine_upper(partial, sc, sU, lane);
    if (lane == 0)
        scal[8 + 0] = __fadd_rn(__fmul_rn(a[0], a[0]), res);
}

// fused: combine partial1 -> alpha (every block, redundantly);
// x += a*p ; r -= a*z (guarded by DONE[it]) over this leaf; dot fresh r.
__global__ void k_xr_dot(float* __restrict__ x, float* __restrict__ r,
                         const float* __restrict__ p, const float* __restrict__ z,
                         const float* __restrict__ scal,
                         const Sched* __restrict__ sc,
                         const float* __restrict__ partial1,
                         float* __restrict__ partial2, int it) {
    __shared__ float sA[LEAF_PAD];
    __shared__ float sU[2048];
    __shared__ float sChain[512];
    __shared__ float sVal[160];
    __shared__ float sAl;
    __shared__ int   sAct;
    int j = blockIdx.x, lane = threadIdx.x;
    float res = combine_upper(partial1, sc, sU, lane);
    if (lane == 0) {
        float pt = __fadd_rn(__fmul_rn(p[0], z[0]), res);
        sAl = __fdiv_rn(scal[8 + it], __fadd_rn(pt, (float)1e-12));
        sAct = (scal[64 + it] == 0.f) ? 1 : 0;
    }
    __syncthreads();
    int active = sAct;
    float al = sAl;
    int P = sc->leafOff[j] + 1, nn = sc->leafN[j];
    if (j == 0 && lane == 0 && active) {
        x[0] = __fadd_rn(x[0], __fmul_rn(al, p[0]));
        r[0] = __fsub_rn(r[0], __fmul_rn(al, z[0]));
    }
    for (int g = lane; g < nn; g += 256) {
        int q = P + g;
        float rv = r[q];
        if (active) {
            float xv = x[q], pv = p[q], zv = z[q];
            x[q] = __fadd_rn(xv, __fmul_rn(al, pv));
            rv = __fsub_rn(rv, __fmul_rn(al, zv));
            r[q] = rv;
        }
        sA[g + (g >> 7)] = rv;
    }
    __syncthreads();
    int c = sc->cls[j];
    dot_eval(sA, sA, sChain, sVal, lane, sc->cNB[c], sc->cBOff[c], sc->cBN[c],
             sc->cA[c], sc->cB[c], sc->cOrder[c], sc->cLevOff[c], sc->cMaxD[c],
             partial2, j);
}

// fused: combine partial2 -> rs1/beta (every block); p = r + beta*p (guarded);
// block 0 writes RS[it+1], DONE[it+1].
__global__ void k_p_fin(float4* __restrict__ p4, const float4* __restrict__ r4,
                        const float* __restrict__ rfull,
                        float* __restrict__ scal,
                        const Sched* __restrict__ sc,
                        const float* __restrict__ partial2, int it, int n4) {
    __shared__ float sU[2048];
    __shared__ float sBe;
    __shared__ int   sAct;
    int lane = threadIdx.x;
    float res = combine_upper(partial2, sc, sU, lane);
    if (lane == 0) {
        float rs1 = __fadd_rn(__fmul_rn(rfull[0], rfull[0]), res);
        float RS = scal[8 + it];
        float dn = scal[64 + it];
        sBe = __fdiv_rn(rs1, __fadd_rn(RS, (float)1e-12));
        sAct = (dn == 0.f) ? 1 : 0;
        if (blockIdx.x == 0) {
            scal[8 + it + 1]  = (dn == 0.f) ? rs1 : RS;
            scal[64 + it + 1] = (dn != 0.f || __fsqrt_rn(rs1) <= (float)1e-4)
                                ? 1.f : 0.f;
        }
    }
    __syncthreads();
    if (!sAct) return;
    float be = sBe;
    int i = blockIdx.x * blockDim.x + lane;
    if (i >= n4) return;
    float4 pv = p4[i], rv = r4[i];
    pv.x = __fadd_rn(rv.x, __fmul_rn(be, pv.x));
    pv.y = __fadd_rn(rv.y, __fmul_rn(be, pv.y));
    pv.z = __fadd_rn(rv.z, __fmul_rn(be, pv.z));
    pv.w = __fadd_rn(rv.w, __fmul_rn(be, pv.w));
    p4[i] = pv;
}

// ---------- CSR build (stable in edge order) ----------

__global__ void k_edge_pre(const int* __restrict__ dst, const int* __restrict__ src,
                           int* __restrict__ dstCnt, int* __restrict__ srcCnt, int E) {
    int e = blockIdx.x * blockDim.x + threadIdx.x;
    if (e >= E) return;
    atomicAdd(&dstCnt[dst[e]], 1);
    atomicAdd(&srcCnt[src[e]], 1);
}

__global__ void k_scan1(const int* __restrict__ cnt, int* __restrict__ incl,
                        int* __restrict__ bsums, int N) {
    __shared__ int sm[512];
    int i = blockIdx.x * 512 + threadIdx.x;
    sm[threadIdx.x] = (i < N) ? cnt[i] : 0;
    __syncthreads();
    for (int off = 1; off < 512; off <<= 1) {
        int t = (threadIdx.x >= off) ? sm[threadIdx.x - off] : 0;
        __syncthreads();
        sm[threadIdx.x] += t;
        __syncthreads();
    }
    if (i < N) incl[i] = sm[threadIdx.x];
    if (threadIdx.x == 511) bsums[blockIdx.x] = sm[511];
}

__global__ void k_scan2(int* __restrict__ bsums, int nb) {
    __shared__ int sm[512];
    sm[threadIdx.x] = (threadIdx.x < nb) ? bsums[threadIdx.x] : 0;
    __syncthreads();
    for (int off = 1; off < 512; off <<= 1) {
        int t = (threadIdx.x >= off) ? sm[threadIdx.x - off] : 0;
        __syncthreads();
        sm[threadIdx.x] += t;
        __syncthreads();
    }
    if (threadIdx.x < nb) bsums[threadIdx.x] = sm[threadIdx.x];
}

__global__ void k_scan3(int* __restrict__ off, const int* __restrict__ bsums,
                        const int* __restrict__ cnt, int N, int E) {
    int i = blockIdx.x * 512 + threadIdx.x;
    if (i < N) {
        int add = (blockIdx.x > 0) ? bsums[blockIdx.x - 1] : 0;
        off[i] = off[i] + add - cnt[i];  // exclusive
    }
    if (i == 0) off[N] = E;
}

__global__ void k_fill(const int* __restrict__ dst, const int* __restrict__ src,
                       const int* __restrict__ dstOff, const int* __restrict__ srcOff,
                       int* __restrict__ cursD, int* __restrict__ cursS,
                       int* __restrict__ dstList, int* __restrict__ srcList, int E) {
    int e = blockIdx.x * blockDim.x + threadIdx.x;
    if (e >= E) return;
    int d = dst[e];
    dstList[dstOff[d] + atomicAdd(&cursD[d], 1)] = e;
    int s0 = src[e];
    srcList[srcOff[s0] + atomicAdd(&cursS[s0], 1)] = e;
}

__device__ __forceinline__ void insort(int* L, int lo, int hi) {
    for (int a = lo + 1; a < hi; ++a) {
        int key = L[a]; int b = a - 1;
        while (b >= lo && L[b] > key) { L[b + 1] = L[b]; b--; }
        L[b + 1] = key;
    }
}

__global__ void k_sort(const int* __restrict__ dstOff, const int* __restrict__ srcOff,
                       int* __restrict__ dstList, int* __restrict__ srcList, int N) {
    int i = blockIdx.x * blockDim.x + threadIdx.x;
    if (i >= N) return;
    insort(dstList, dstOff[i], dstOff[i + 1]);
    insort(srcList, srcOff[i], srcOff[i + 1]);
}

// Permute per-edge operands into CSR order, IN PLACE over the lists.
__global__ void k_perm(int* dstList, int* srcList,
                       const int* __restrict__ srcp, const int* __restrict__ dstp,
                       const float* __restrict__ ea,
                       float* __restrict__ invD, float* __restrict__ slopeD,
                       float* __restrict__ invS, int E) {
    int k = blockIdx.x * blockDim.x + threadIdx.x;
    if (k >= E) return;
    int e  = dstList[k];
    int e2 = srcList[k];
    float dx  = fmaxf(ea[2 * e], 1e-6f);
    float dx2 = fmaxf(ea[2 * e2], 1e-6f);
    int sA_ = srcp[e];
    int dB_ = dstp[e2];
    float iD = __fdiv_rn(1.f, dx);
    float sD = __fdiv_rn(ea[2 * e + 1], dx);
    float iS = __fdiv_rn(1.f, dx2);
    dstList[k] = sA_;    // srcA
    srcList[k] = dB_;    // dstB
    invD[k] = iD; slopeD[k] = sD; invS[k] = iS;
}

// ---------- physics kernels (exact np op order, f32 sequential) ----------

__global__ void k_slope_b(const float* __restrict__ u, const float* __restrict__ slopeD,
                          const int* __restrict__ dstOff,
                          float* __restrict__ r, float* __restrict__ y,
                          const float* __restrict__ dtp, const float* __restrict__ gp,
                          int N) {
    int i = blockIdx.x * blockDim.x + threadIdx.x;
    if (i >= N) return;
    float dtg = __fmul_rn(dt_eff_of(dtp), gp[0]);
    float sn = 0.f;
    int k0 = dstOff[i], k1 = dstOff[i + 1];
    for (int k = k0; k < k1; ++k) sn = __fadd_rn(sn, slopeD[k]);
    float ms = __fmul_rn(dtg, sn);
    const float4* u4 = (const float4*)u;
    float4* r4 = (float4*)r;
    float4* y4 = (float4*)y;
    #pragma unroll
    for (int hh = 0; hh < 2; ++hh) {
        float4 uv = u4[i * 2 + hh];
        float4 bv;
        bv.x = __fsub_rn(uv.x, ms);
        bv.y = __fsub_rn(uv.y, ms);
        bv.z = __fsub_rn(uv.z, ms);
        bv.w = __fsub_rn(uv.w, ms);
        r4[i * 2 + hh] = bv;
        float4 yv;
        yv.x = __fmul_rn(uv.x, bv.x);
        yv.y = __fmul_rn(uv.y, bv.y);
        yv.z = __fmul_rn(uv.z, bv.z);
        yv.w = __fmul_rn(uv.w, bv.w);
        y4[i * 2 + hh] = yv;
    }
}

// D1_T via y (= u*input); out = base + dt*acc. thread = (node, f-half).
// doInit: also rInit := out, xInit := 0. Setup only.
__global__ void k_d1tz(const int* __restrict__ dstB, const int* __restrict__ dstOff,
                       const float* __restrict__ invD, const int* __restrict__ srcOff,
                       const float* __restrict__ invS, const float* __restrict__ y,
                       const float* __restrict__ base, float* __restrict__ out,
                       const float* __restrict__ dtp,
                       float* __restrict__ rInit, float* __restrict__ xInit,
                       int doInit, int N2) {
    int idx2 = blockIdx.x * blockDim.x + threadIdx.x;
    if (idx2 >= N2) return;
    int i = idx2 >> 1, h = idx2 & 1;
    const float4* y4 = (const float4*)y;
    float4 uy = y4[idx2];
    float4 acc = make_float4(0.f, 0.f, 0.f, 0.f);
    int k0 = dstOff[i], k1 = dstOff[i + 1];
    for (int k = k0; k < k1; ++k) {
        float iv = invD[k];
        acc.x = __fadd_rn(acc.x, __fmul_rn(uy.x, iv));
        acc.y = __fadd_rn(acc.y, __fmul_rn(uy.y, iv));
        acc.z = __fadd_rn(acc.z, __fmul_rn(uy.z, iv));
        acc.w = __fadd_rn(acc.w, __fmul_rn(uy.w, iv));
    }
    k0 = srcOff[i]; k1 = srcOff[i + 1];
    for (int k = k0; k < k1; ++k) {
        int d = dstB[k];
        float iv = invS[k];
        float4 yd = y4[d * 2 + h];
        float t0 = __fmul_rn(yd.x, iv); acc.x = __fadd_rn(acc.x, -t0);
        float t1 = __fmul_rn(yd.y, iv); acc.y = __fadd_rn(acc.y, -t1);
        float t2 = __fmul_rn(yd.z, iv); acc.z = __fadd_rn(acc.z, -t2);
        float t3 = __fmul_rn(yd.w, iv); acc.w = __fadd_rn(acc.w, -t3);
    }
    float dt = dt_eff_of(dtp);
    float4 bs = ((const float4*)base)[idx2];
    float4 ov;
    ov.x = __fadd_rn(bs.x, __fmul_rn(dt, acc.x));
    ov.y = __fadd_rn(bs.y, __fmul_rn(dt, acc.y));
    ov.z = __fadd_rn(bs.z, __fmul_rn(dt, acc.z));
    ov.w = __fadd_rn(bs.w, __fmul_rn(dt, acc.w));
    ((float4*)out)[idx2] = ov;
    if (doInit) {
        ((float4*)rInit)[idx2] = ov;
        ((float4*)xInit)[idx2] = make_float4(0.f, 0.f, 0.f, 0.f);
    }
}

// D1(p) fused with w = p + dt*(u*t) and y = u*w. thread = (node, f-half).
__global__ void k_d1w(const int* __restrict__ srcA, const int* __restrict__ dstOff,
                      const float* __restrict__ invD, const float* __restrict__ pv,
                      const float* __restrict__ u,
                      float* __restrict__ w, float* __restrict__ y,
                      const float* __restrict__ dtp, int N2) {
    int idx2 = blockIdx.x * blockDim.x + threadIdx.x;
    if (idx2 >= N2) return;
    int i = idx2 >> 1, h = idx2 & 1;
    const float4* pv4 = (const float4*)pv;
    float4 pi = pv4[idx2];
    float4 acc = make_float4(0.f, 0.f, 0.f, 0.f);
    int k0 = dstOff[i], k1 = dstOff[i + 1];
    for (int k = k0; k < k1; ++k) {
        int s = srcA[k];
        float iv = invD[k];
        float4 ps = pv4[s * 2 + h];
        acc.x = __fadd_rn(acc.x, __fmul_rn(__fsub_rn(pi.x, ps.x), iv));
        acc.y = __fadd_rn(acc.y, __fmul_rn(__fsub_rn(pi.y, ps.y), iv));
        acc.z = __fadd_rn(acc.z, __fmul_rn(__fsub_rn(pi.z, ps.z), iv));
        acc.w = __fadd_rn(acc.w, __fmul_rn(__fsub_rn(pi.w, ps.w), iv));
    }
    float dt = dt_eff_of(dtp);
    float4 uv = ((const float4*)u)[idx2];
    float4 wv;
    wv.x = __fadd_rn(pi.x, __fmul_rn(dt, __fmul_rn(uv.x, acc.x)));
    wv.y = __fadd_rn(pi.y, __fmul_rn(dt, __fmul_rn(uv.y, acc.y)));
    wv.z = __fadd_rn(pi.z, __fmul_rn(dt, __fmul_rn(uv.z, acc.z)));
    wv.w = __fadd_rn(pi.w, __fmul_rn(dt, __fmul_rn(uv.w, acc.w)));
    ((float4*)w)[idx2] = wv;
    float4 yv;
    yv.x = __fmul_rn(uv.x, wv.x);
    yv.y = __fmul_rn(uv.y, wv.y);
    yv.z = __fmul_rn(uv.z, wv.z);
    yv.w = __fmul_rn(uv.w, wv.w);
    ((float4*)y)[idx2] = yv;
}

extern "C" void kernel_launch(void* const* d_in, const int* in_sizes, int n_in,
                              void* d_out, int out_size, void* d_ws, size_t ws_size,
                              hipStream_t stream) {
    const float* u   = (const float*)d_in[0];
    const int*   ei  = (const int*)d_in[1];
    const float* ea  = (const float*)d_in[2];
    const float* dtp = (const float*)d_in[3];
    const float* gp  = (const float*)d_in[4];

    const int NF = in_sizes[0];        // 1,600,000
    const int N  = NF / F;             // 200,000
    const int E  = in_sizes[2] / 2;    // 3,200,000
    const int* srcp = ei;
    const int* dstp = ei + E;

    // host-side pairwise-tree schedule (deterministic fn of NF; static so the
    // graph-replayed hipMemcpyAsync source stays valid)
    static Sched h_sched;
    build_sched_host(NF - 1, &h_sched);
    const int NL = h_sched.NL;

    char* wp = (char*)d_ws;
    float* scal    = (float*)wp; wp += 128 * 4;   // RS[it]@8+it, DONE[it]@64+it
    float* r       = (float*)wp; wp += (size_t)NF * 4;
    float* p       = (float*)wp; wp += (size_t)NF * 4;
    float* t       = (float*)wp; wp += (size_t)NF * 4;   // z
    float* w       = (float*)wp; wp += (size_t)NF * 4;
    float* y       = (float*)wp; wp += (size_t)NF * 4;   // u*w / u*b
    int*   dstList = (int*)wp;   wp += (size_t)E * 4;    // becomes srcA after k_perm
    int*   srcList = (int*)wp;   wp += (size_t)E * 4;    // becomes dstB after k_perm
    float* invD    = (float*)wp; wp += (size_t)E * 4;
    float* invS    = (float*)wp; wp += (size_t)E * 4;
    float* slopeD  = (float*)wp; wp += (size_t)E * 4;
    int*   dstOff  = (int*)wp;   wp += (size_t)(N + 1) * 4;
    int*   srcOff  = (int*)wp;   wp += (size_t)(N + 1) * 4;
    int*   dstCnt  = (int*)wp;   wp += (size_t)N * 4;
    int*   srcCnt  = (int*)wp;   wp += (size_t)N * 4;
    int*   cursD   = (int*)wp;   wp += (size_t)N * 4;
    int*   cursS   = (int*)wp;   wp += (size_t)N * 4;
    int*   bsD     = (int*)wp;   wp += 512 * 4;
    int*   bsS     = (int*)wp;   wp += 512 * 4;
    float* partial1 = (float*)wp; wp += 2048 * 4;
    float* partial2 = (float*)wp; wp += 2048 * 4;
    wp = (char*)(((uintptr_t)wp + 255) & ~(uintptr_t)255);
    Sched* d_sched = (Sched*)wp; wp += (sizeof(Sched) + 255) & ~(size_t)255;
    float* x = (float*)d_out;

    hipMemcpyAsync(d_sched, &h_sched, sizeof(Sched), hipMemcpyHostToDevice,
                   stream);
    hipMemsetAsync(scal, 0, 128 * 4, stream);
    hipMemsetAsync(dstCnt, 0, (size_t)N * 4, stream);
    hipMemsetAsync(srcCnt, 0, (size_t)N * 4, stream);
    hipMemsetAsync(cursD, 0, (size_t)N * 4, stream);
    hipMemsetAsync(cursS, 0, (size_t)N * 4, stream);

    const int bn = 256;
    const int gN  = (N + bn - 1) / bn;
    const int gE  = (E + bn - 1) / bn;
    const int nb  = (N + 511) / 512;
    const int n4  = NF / 4;
    const int g4  = (n4 + bn - 1) / bn;
    const int N2  = NF / 4;            // (node, feature-half) threads
    const int g2  = (N2 + bn - 1) / bn;

    // ---- CSR build (stable by edge id) ----
    k_edge_pre<<<gE, bn, 0, stream>>>(dstp, srcp, dstCnt, srcCnt, E);
    k_scan1<<<nb, 512, 0, stream>>>(dstCnt, dstOff, bsD, N);
    k_scan2<<<1, 512, 0, stream>>>(bsD, nb);
    k_scan3<<<nb, 512, 0, stream>>>(dstOff, bsD, dstCnt, N, E);
    k_scan1<<<nb, 512, 0, stream>>>(srcCnt, srcOff, bsS, N);
    k_scan2<<<1, 512, 0, stream>>>(bsS, nb);
    k_scan3<<<nb, 512, 0, stream>>>(srcOff, bsS, srcCnt, N, E);
    k_fill<<<gE, bn, 0, stream>>>(dstp, srcp, dstOff, srcOff, cursD, cursS,
                                  dstList, srcList, E);
    k_sort<<<gN, bn, 0, stream>>>(dstOff, srcOff, dstList, srcList, N);
    k_perm<<<gE, bn, 0, stream>>>(dstList, srcList, srcp, dstp, ea,
                                  invD, slopeD, invS, E);
    const int* srcA = dstList;   // after k_perm
    const int* dstB = srcList;   // after k_perm

    // ---- setup: b->r, y=u*b ; p = b + dt*D1T(y) ; r=p, x=0 ; RS[0] = p.p ----
    k_slope_b<<<gN, bn, 0, stream>>>(u, slopeD, dstOff, r, y, dtp, gp, N);
    k_d1tz<<<g2, bn, 0, stream>>>(dstB, dstOff, invD, srcOff, invS,
                                  y, r, p, dtp, r, x, 1, N2);
    k_dot_leaf<<<NL, 256, 0, stream>>>(p, p, d_sched, partial1);
    k_dot_rs0<<<1, 256, 0, stream>>>(p, partial1, d_sched, scal);

    // ---- CG loop (5 dispatches/iter) ----
    for (int it = 0; it < CG_ITERS; ++it) {
        k_d1w<<<g2, bn, 0, stream>>>(srcA, dstOff, invD, p, u, w, y, dtp, N2);
        k_d1tz<<<g2, bn, 0, stream>>>(dstB, dstOff, invD, srcOff, invS,
                                      y, w, t, dtp, (float*)0, (float*)0, 0, N2);
        k_dot_leaf<<<NL, 256, 0, stream>>>(p, t, d_sched, partial1);
        k_xr_dot<<<NL, 256, 0, stream>>>(x, r, p, t, scal, d_sched,
                                         partial1, partial2, it);
        k_p_fin<<<g4, bn, 0, stream>>>((float4*)p, (const float4*)r, r, scal,
                                       d_sched, partial2, it, n4);
    }
}

// Round 6
// 5032.943 us; speedup vs baseline: 1.7836x; 1.6010x over previous
//
#include <hip/hip_runtime.h>
#include <math.h>
#include <stdint.h>
#include <string.h>

// PhysicsLSGStep: bitwise-faithful f32 replication of the numpy reference.
// R17 (on top of R16): gather kernels k_d1w / k_d1tz re-partitioned to
// thread-per-(node, feature-PAIR) (float2, 800K threads): at float4/400K the
// machine was grid-starved (~24 of 32 waves/CU) and the kernels are
// gather-latency-bound => more TLP = more outstanding loads. Gather line
// traffic unchanged (4 pair-threads of a node share its 32B row). Plus
// #pragma unroll 4 on the gather loops (4 loads in flight per wave; unroll
// preserves the __fadd_rn chain order => bit-exact). Everything else frozen.
// Scatter sums stay in sorted-edge-id (CSR) order; dots replay the exact
// numpy pairwise tree (level-parallel, pairings unchanged). f32 __f*_rn only.

#define F 8
#define CG_ITERS 30
#define LEAF_T 4096
#define LEAF_PAD (LEAF_T + LEAF_T / 128 + 8)
#define ENC_ADD 1024   // operand encoding: <1024 = base/leaf slot, else add t+1024
#define MAX_LEAF 1024
#define MAX_CLS 32

// scal slots: RS[it] = scal[8+it], DONE[it] = scal[64+it]  (it = 0..CG_ITERS)

// padded-LDS accessor (bank-spread: +1 word every 128)
#define LV(A_, i_) A_[(i_) + ((i_) >> 7)]

struct Sched {
    int NL, uNT, uMaxD, nCls;
    int leafOff[MAX_LEAF], leafN[MAX_LEAF], cls[MAX_LEAF];
    int cNB[MAX_CLS], cMaxD[MAX_CLS];
    int cBOff[MAX_CLS][64], cBN[MAX_CLS][64];
    int cA[MAX_CLS][64], cB[MAX_CLS][64], cOrder[MAX_CLS][64];
    int cLevOff[MAX_CLS][32];
    int uA[MAX_LEAF], uB[MAX_LEAF], uOrder[MAX_LEAF], uLevOff[64];
};

// ---------------- host-side schedule build (exact integer replica) --------

static void host_build_tree(int n, int T, int* bOff, int* bN,
                            int* A, int* B, int* dep,
                            int* pNB, int* pNT, int* pMaxD) {
    int so[64], sn[64], st[64], sid[64], sdp[64];
    int sp = 0, coff = 0, cn = n, c2 = 0, t = 0, rootd = 0;
    for (;;) {
        if (cn <= T) {
            if (bOff) { bOff[c2] = coff; bN[c2] = cn; }
            int id = c2, dp = 0; c2++;
            bool fin = false;
            for (;;) {
                if (sp == 0) { rootd = dp; fin = true; break; }
                if (st[sp - 1] == 0) {
                    st[sp - 1] = 1; sid[sp - 1] = id; sdp[sp - 1] = dp;
                    int n2 = sn[sp - 1] / 2; n2 -= (n2 & 7);
                    coff = so[sp - 1] + n2; cn = sn[sp - 1] - n2;
                    break;
                } else {
                    A[t] = sid[sp - 1]; B[t] = id;  // add = stored(left)+cur(right)
                    int dA = sdp[sp - 1];
                    dp = ((dA > dp) ? dA : dp) + 1;
                    dep[t] = dp;
                    id = ENC_ADD + t; t++;
                    sp--;
                }
            }
            if (fin) break;
        } else {
            so[sp] = coff; sn[sp] = cn; st[sp] = 0; sp++;
            int n2 = cn / 2; n2 -= (n2 & 7);
            cn = n2;
        }
    }
    *pNB = c2; *pNT = t; *pMaxD = rootd;
}

static void host_bucketize(const int* dep, int NT, int maxD,
                           int* order, int* levOff) {
    int cnt[64];
    for (int d = 0; d <= maxD; ++d) cnt[d] = 0;
    for (int t = 0; t < NT; ++t) cnt[dep[t]]++;
    int run = 0;
    levOff[0] = 0;
    for (int d = 1; d <= maxD; ++d) { run += cnt[d]; levOff[d] = run; }
    int cur[64];
    for (int d = 1; d <= maxD; ++d) cur[d] = levOff[d - 1];
    for (int t = 0; t < NT; ++t) { int d = dep[t]; order[cur[d]++] = t; }
}

static void build_sched_host(int n, Sched* s) {   // n = NF-1
    static int uDep[MAX_LEAF];
    host_build_tree(n, LEAF_T, s->leafOff, s->leafN, s->uA, s->uB, uDep,
                    &s->NL, &s->uNT, &s->uMaxD);
    host_bucketize(uDep, s->uNT, s->uMaxD, s->uOrder, s->uLevOff);
    s->nCls = 0;
    int clsN[MAX_CLS];
    int dep[64];
    for (int j = 0; j < s->NL; ++j) {
        int c = -1;
        for (int k = 0; k < s->nCls; ++k)
            if (clsN[k] == s->leafN[j]) { c = k; break; }
        if (c < 0 && s->nCls < MAX_CLS) {
            c = s->nCls++;
            clsN[c] = s->leafN[j];
            int NB, NT, maxD;
            host_build_tree(s->leafN[j], 128, s->cBOff[c], s->cBN[c],
                            s->cA[c], s->cB[c], dep, &NB, &NT, &maxD);
            s->cNB[c] = NB; s->cMaxD[c] = maxD;
            host_bucketize(dep, NT, maxD, s->cOrder[c], s->cLevOff[c]);
        }
        s->cls[j] = c;
    }
}

// ---------------- device ----------------

__device__ __forceinline__ float dt_eff_of(const float* dtp) {
    return fminf(fmaxf(dtp[0], 0.02f), 2.0f);
}

__device__ __forceinline__ int slotOf(int e, int NB) {
    return (e < ENC_ADD) ? e : (NB + (e - ENC_ADD));
}

// level-parallel upper-tree combine of partial[0..NL) into sU; returns root
// on all lanes (after final barrier). blockDim = 256.
__device__ __forceinline__ float combine_upper(const float* __restrict__ partial,
                                               const Sched* __restrict__ sc,
                                               float* sU, int lane) {
    int NL = sc->NL, NT = sc->uNT, maxD = sc->uMaxD;
    for (int k = lane; k < NL; k += 256) sU[k] = partial[k];
    __syncthreads();
    for (int d = 1; d <= maxD; ++d) {
        int s0 = sc->uLevOff[d - 1], s1 = sc->uLevOff[d];
        for (int s = s0 + lane; s < s1; s += 256) {
            int tt = sc->uOrder[s];
            sU[NL + tt] = __fadd_rn(sU[slotOf(sc->uA[tt], NL)],
                                    sU[slotOf(sc->uB[tt], NL)]);
        }
        __syncthreads();
    }
    return (NT > 0) ? sU[NL + NT - 1] : sU[0];
}

// shared tail of the leaf-dot: 8-way base chains + exact combine + tree eval.
// sA/sB may alias (r.r dot). blockDim = 256.
__device__ __forceinline__ void dot_eval(const float* sA, const float* sB,
                                         float* sChain, float* sVal,
                                         int lane, int NB,
                                         const int* __restrict__ bOff,
                                         const int* __restrict__ bN,
                                         const int* __restrict__ A,
                                         const int* __restrict__ Bb,
                                         const int* __restrict__ order,
                                         const int* __restrict__ levOff,
                                         int maxD,
                                         float* __restrict__ partial, int j) {
    // phase A: chain r_j of base block bb on lane bb*8+j (independent chains)
    int bb = lane >> 3, jj = lane & 7;
    if (bb < NB) {
        int off = bOff[bb], n = bN[bb];
        if (n >= 8) {
            int lim = n - (n & 7);
            float rr = __fmul_rn(LV(sA, off + jj), LV(sB, off + jj));
            for (int e = jj + 8; e < lim; e += 8)
                rr = __fadd_rn(rr, __fmul_rn(LV(sA, off + e), LV(sB, off + e)));
            sChain[bb * 8 + jj] = rr;
        }
    }
    __syncthreads();
    // phase B: exact combine tree + exact tail per base block
    if (lane < NB) {
        int off = bOff[lane], n = bN[lane];
        float res;
        if (n < 8) {
            res = 0.f;
            for (int e = 0; e < n; ++e)
                res = __fadd_rn(res, __fmul_rn(LV(sA, off + e), LV(sB, off + e)));
        } else {
            int lim = n - (n & 7);
            const float* c = sChain + lane * 8;
            res = __fadd_rn(__fadd_rn(__fadd_rn(c[0], c[1]), __fadd_rn(c[2], c[3])),
                            __fadd_rn(__fadd_rn(c[4], c[5]), __fadd_rn(c[6], c[7])));
            for (int e = lim; e < n; ++e)
                res = __fadd_rn(res, __fmul_rn(LV(sA, off + e), LV(sB, off + e)));
        }
        sVal[lane] = res;
    }
    __syncthreads();
    // phase C: level-parallel replay of the leaf combine tree
    for (int d = 1; d <= maxD; ++d) {
        int s0 = levOff[d - 1], s1 = levOff[d];
        for (int s = s0 + lane; s < s1; s += 256) {
            int tt = order[s];
            sVal[NB + tt] = __fadd_rn(sVal[slotOf(A[tt], NB)],
                                      sVal[slotOf(Bb[tt], NB)]);
        }
        __syncthreads();
    }
    if (lane == 0) partial[j] = (NB > 1) ? sVal[NB + NB - 2] : sVal[0];
}

// per-leaf dot partial (a.b). grid = NL blocks, 256 threads.
__global__ void k_dot_leaf(const float* __restrict__ a, const float* __restrict__ b,
                           const Sched* __restrict__ sc, float* __restrict__ partial) {
    __shared__ float sA[LEAF_PAD], sB[LEAF_PAD];
    __shared__ float sChain[512];
    __shared__ float sVal[160];
    int j = blockIdx.x, lane = threadIdx.x;
    int P = sc->leafOff[j] + 1, nn = sc->leafN[j];
    for (int g = lane; g < nn; g += 256) {
        float av = a[P + g], bv = b[P + g];
        int m = g + (g >> 7);
        sA[m] = av; sB[m] = bv;
    }
    __syncthreads();
    int c = sc->cls[j];
    dot_eval(sA, sB, sChain, sVal, lane, sc->cNB[c], sc->cBOff[c], sc->cBN[c],
             sc->cA[c], sc->cB[c], sc->cOrder[c], sc->cLevOff[c], sc->cMaxD[c],
             partial, j);
}

// setup-only: RS[0] = p.p from partial + first-element term. 1 block.
__global__ void k_dot_rs0(const float* __restrict__ a,
                          const float* __restrict__ partial,
                          const Sched* __restrict__ sc, float* __restrict__ scal) {
    __shared__ float sU[2048];
    int lane = threadIdx.x;
    float res = combine_upper(partial, sc, sU, lane);
    if (lane == 0)
        scal[8 + 0] = __fadd_rn(__fmul_rn(a[0], a[0]), res);
}

// fused: combine partial1 -> alpha (every block, redundantly);
// x += a*p ; r -= a*z (guarded by DONE[it]) over this leaf; dot fresh r.
__global__ void k_xr_dot(float* __restrict__ x, float* __restrict__ r,
                         const float* __restrict__ p, const float* __restrict__ z,
                         const float* __restrict__ scal,
                         const Sched* __restrict__ sc,
                         const float* __restrict__ partial1,
                         float* __restrict__ partial2, int it) {
    __shared__ float sA[LEAF_PAD];
    __shared__ float sU[2048];
    __shared__ float sChain[512];
    __shared__ float sVal[160];
    __shared__ float sAl;
    __shared__ int   sAct;
    int j = blockIdx.x, lane = threadIdx.x;
    float res = combine_upper(partial1, sc, sU, lane);
    if (lane == 0) {
        float pt = __fadd_rn(__fmul_rn(p[0], z[0]), res);
        sAl = __fdiv_rn(scal[8 + it], __fadd_rn(pt, (float)1e-12));
        sAct = (scal[64 + it] == 0.f) ? 1 : 0;
    }
    __syncthreads();
    int active = sAct;
    float al = sAl;
    int P = sc->leafOff[j] + 1, nn = sc->leafN[j];
    if (j == 0 && lane == 0 && active) {
        x[0] = __fadd_rn(x[0], __fmul_rn(al, p[0]));
        r[0] = __fsub_rn(r[0], __fmul_rn(al, z[0]));
    }
    for (int g = lane; g < nn; g += 256) {
        int q = P + g;
        float rv = r[q];
        if (active) {
            float xv = x[q], pv = p[q], zv = z[q];
            x[q] = __fadd_rn(xv, __fmul_rn(al, pv));
            rv = __fsub_rn(rv, __fmul_rn(al, zv));
            r[q] = rv;
        }
        sA[g + (g >> 7)] = rv;
    }
    __syncthreads();
    int c = sc->cls[j];
    dot_eval(sA, sA, sChain, sVal, lane, sc->cNB[c], sc->cBOff[c], sc->cBN[c],
             sc->cA[c], sc->cB[c], sc->cOrder[c], sc->cLevOff[c], sc->cMaxD[c],
             partial2, j);
}

// fused: combine partial2 -> rs1/beta (every block); p = r + beta*p (guarded);
// block 0 writes RS[it+1], DONE[it+1].
__global__ void k_p_fin(float4* __restrict__ p4, const float4* __restrict__ r4,
                        const float* __restrict__ rfull,
                        float* __restrict__ scal,
                        const Sched* __restrict__ sc,
                        const float* __restrict__ partial2, int it, int n4) {
    __shared__ float sU[2048];
    __shared__ float sBe;
    __shared__ int   sAct;
    int lane = threadIdx.x;
    float res = combine_upper(partial2, sc, sU, lane);
    if (lane == 0) {
        float rs1 = __fadd_rn(__fmul_rn(rfull[0], rfull[0]), res);
        float RS = scal[8 + it];
        float dn = scal[64 + it];
        sBe = __fdiv_rn(rs1, __fadd_rn(RS, (float)1e-12));
        sAct = (dn == 0.f) ? 1 : 0;
        if (blockIdx.x == 0) {
            scal[8 + it + 1]  = (dn == 0.f) ? rs1 : RS;
            scal[64 + it + 1] = (dn != 0.f || __fsqrt_rn(rs1) <= (float)1e-4)
                                ? 1.f : 0.f;
        }
    }
    __syncthreads();
    if (!sAct) return;
    float be = sBe;
    int i = blockIdx.x * blockDim.x + lane;
    if (i >= n4) return;
    float4 pv = p4[i], rv = r4[i];
    pv.x = __fadd_rn(rv.x, __fmul_rn(be, pv.x));
    pv.y = __fadd_rn(rv.y, __fmul_rn(be, pv.y));
    pv.z = __fadd_rn(rv.z, __fmul_rn(be, pv.z));
    pv.w = __fadd_rn(rv.w, __fmul_rn(be, pv.w));
    p4[i] = pv;
}

// ---------- CSR build (stable in edge order) ----------

__global__ void k_edge_pre(const int* __restrict__ dst, const int* __restrict__ src,
                           int* __restrict__ dstCnt, int* __restrict__ srcCnt, int E) {
    int e = blockIdx.x * blockDim.x + threadIdx.x;
    if (e >= E) return;
    atomicAdd(&dstCnt[dst[e]], 1);
    atomicAdd(&srcCnt[src[e]], 1);
}

__global__ void k_scan1(const int* __restrict__ cnt, int* __restrict__ incl,
                        int* __restrict__ bsums, int N) {
    __shared__ int sm[512];
    int i = blockIdx.x * 512 + threadIdx.x;
    sm[threadIdx.x] = (i < N) ? cnt[i] : 0;
    __syncthreads();
    for (int off = 1; off < 512; off <<= 1) {
        int t = (threadIdx.x >= off) ? sm[threadIdx.x - off] : 0;
        __syncthreads();
        sm[threadIdx.x] += t;
        __syncthreads();
    }
    if (i < N) incl[i] = sm[threadIdx.x];
    if (threadIdx.x == 511) bsums[blockIdx.x] = sm[511];
}

__global__ void k_scan2(int* __restrict__ bsums, int nb) {
    __shared__ int sm[512];
    sm[threadIdx.x] = (threadIdx.x < nb) ? bsums[threadIdx.x] : 0;
    __syncthreads();
    for (int off = 1; off < 512; off <<= 1) {
        int t = (threadIdx.x >= off) ? sm[threadIdx.x - off] : 0;
        __syncthreads();
        sm[threadIdx.x] += t;
        __syncthreads();
    }
    if (threadIdx.x < nb) bsums[threadIdx.x] = sm[threadIdx.x];
}

__global__ void k_scan3(int* __restrict__ off, const int* __restrict__ bsums,
                        const int* __restrict__ cnt, int N, int E) {
    int i = blockIdx.x * 512 + threadIdx.x;
    if (i < N) {
        int add = (blockIdx.x > 0) ? bsums[blockIdx.x - 1] : 0;
        off[i] = off[i] + add - cnt[i];  // exclusive
    }
    if (i == 0) off[N] = E;
}

__global__ void k_fill(const int* __restrict__ dst, const int* __restrict__ src,
                       const int* __restrict__ dstOff, const int* __restrict__ srcOff,
                       int* __restrict__ cursD, int* __restrict__ cursS,
                       int* __restrict__ dstList, int* __restrict__ srcList, int E) {
    int e = blockIdx.x * blockDim.x + threadIdx.x;
    if (e >= E) return;
    int d = dst[e];
    dstList[dstOff[d] + atomicAdd(&cursD[d], 1)] = e;
    int s0 = src[e];
    srcList[srcOff[s0] + atomicAdd(&cursS[s0], 1)] = e;
}

__device__ __forceinline__ void insort(int* L, int lo, int hi) {
    for (int a = lo + 1; a < hi; ++a) {
        int key = L[a]; int b = a - 1;
        while (b >= lo && L[b] > key) { L[b + 1] = L[b]; b--; }
        L[b + 1] = key;
    }
}

__global__ void k_sort(const int* __restrict__ dstOff, const int* __restrict__ srcOff,
                       int* __restrict__ dstList, int* __restrict__ srcList, int N) {
    int i = blockIdx.x * blockDim.x + threadIdx.x;
    if (i >= N) return;
    insort(dstList, dstOff[i], dstOff[i + 1]);
    insort(srcList, srcOff[i], srcOff[i + 1]);
}

// Permute per-edge operands into CSR order, IN PLACE over the lists.
__global__ void k_perm(int* dstList, int* srcList,
                       const int* __restrict__ srcp, const int* __restrict__ dstp,
                       const float* __restrict__ ea,
                       float* __restrict__ invD, float* __restrict__ slopeD,
                       float* __restrict__ invS, int E) {
    int k = blockIdx.x * blockDim.x + threadIdx.x;
    if (k >= E) return;
    int e  = dstList[k];
    int e2 = srcList[k];
    float dx  = fmaxf(ea[2 * e], 1e-6f);
    float dx2 = fmaxf(ea[2 * e2], 1e-6f);
    int sA_ = srcp[e];
    int dB_ = dstp[e2];
    float iD = __fdiv_rn(1.f, dx);
    float sD = __fdiv_rn(ea[2 * e + 1], dx);
    float iS = __fdiv_rn(1.f, dx2);
    dstList[k] = sA_;    // srcA
    srcList[k] = dB_;    // dstB
    invD[k] = iD; slopeD[k] = sD; invS[k] = iS;
}

// ---------- physics kernels (exact np op order, f32 sequential) ----------

__global__ void k_slope_b(const float* __restrict__ u, const float* __restrict__ slopeD,
                          const int* __restrict__ dstOff,
                          float* __restrict__ r, float* __restrict__ y,
                          const float* __restrict__ dtp, const float* __restrict__ gp,
                          int N) {
    int i = blockIdx.x * blockDim.x + threadIdx.x;
    if (i >= N) return;
    float dtg = __fmul_rn(dt_eff_of(dtp), gp[0]);
    float sn = 0.f;
    int k0 = dstOff[i], k1 = dstOff[i + 1];
    for (int k = k0; k < k1; ++k) sn = __fadd_rn(sn, slopeD[k]);
    float ms = __fmul_rn(dtg, sn);
    const float4* u4 = (const float4*)u;
    float4* r4 = (float4*)r;
    float4* y4 = (float4*)y;
    #pragma unroll
    for (int hh = 0; hh < 2; ++hh) {
        float4 uv = u4[i * 2 + hh];
        float4 bv;
        bv.x = __fsub_rn(uv.x, ms);
        bv.y = __fsub_rn(uv.y, ms);
        bv.z = __fsub_rn(uv.z, ms);
        bv.w = __fsub_rn(uv.w, ms);
        r4[i * 2 + hh] = bv;
        float4 yv;
        yv.x = __fmul_rn(uv.x, bv.x);
        yv.y = __fmul_rn(uv.y, bv.y);
        yv.z = __fmul_rn(uv.z, bv.z);
        yv.w = __fmul_rn(uv.w, bv.w);
        y4[i * 2 + hh] = yv;
    }
}

// D1_T via y (= u*input); out = base + dt*acc. thread = (node, feature-PAIR).
// doInit: also rInit := out, xInit := 0. Setup only.
__global__ void k_d1tz(const int* __restrict__ dstB, const int* __restrict__ dstOff,
                       const float* __restrict__ invD, const int* __restrict__ srcOff,
                       const float* __restrict__ invS, const float* __restrict__ y,
                       const float* __restrict__ base, float* __restrict__ out,
                       const float* __restrict__ dtp,
                       float* __restrict__ rInit, float* __restrict__ xInit,
                       int doInit, int NP) {
    int idx = blockIdx.x * blockDim.x + threadIdx.x;
    if (idx >= NP) return;
    int i = idx >> 2, c = idx & 3;
    const float2* y2 = (const float2*)y;
    float2 uy = y2[idx];
    float2 acc = make_float2(0.f, 0.f);
    int k0 = dstOff[i], k1 = dstOff[i + 1];
    #pragma unroll 4
    for (int k = k0; k < k1; ++k) {
        float iv = invD[k];
        acc.x = __fadd_rn(acc.x, __fmul_rn(uy.x, iv));
        acc.y = __fadd_rn(acc.y, __fmul_rn(uy.y, iv));
    }
    k0 = srcOff[i]; k1 = srcOff[i + 1];
    #pragma unroll 4
    for (int k = k0; k < k1; ++k) {
        int d = dstB[k];
        float iv = invS[k];
        float2 yd = y2[d * 4 + c];
        float t0 = __fmul_rn(yd.x, iv); acc.x = __fadd_rn(acc.x, -t0);
        float t1 = __fmul_rn(yd.y, iv); acc.y = __fadd_rn(acc.y, -t1);
    }
    float dt = dt_eff_of(dtp);
    float2 bs = ((const float2*)base)[idx];
    float2 ov;
    ov.x = __fadd_rn(bs.x, __fmul_rn(dt, acc.x));
    ov.y = __fadd_rn(bs.y, __fmul_rn(dt, acc.y));
    ((float2*)out)[idx] = ov;
    if (doInit) {
        ((float2*)rInit)[idx] = ov;
        ((float2*)xInit)[idx] = make_float2(0.f, 0.f);
    }
}

// D1(p) fused with w = p + dt*(u*t) and y = u*w. thread = (node, feature-PAIR).
__global__ void k_d1w(const int* __restrict__ srcA, const int* __restrict__ dstOff,
                      const float* __restrict__ invD, const float* __restrict__ pv,
                      const float* __restrict__ u,
                      float* __restrict__ w, float* __restrict__ y,
                      const float* __restrict__ dtp, int NP) {
    int idx = blockIdx.x * blockDim.x + threadIdx.x;
    if (idx >= NP) return;
    int i = idx >> 2, c = idx & 3;
    const float2* pv2 = (const float2*)pv;
    float2 pi = pv2[idx];
    float2 acc = make_float2(0.f, 0.f);
    int k0 = dstOff[i], k1 = dstOff[i + 1];
    #pragma unroll 4
    for (int k = k0; k < k1; ++k) {
        int s = srcA[k];
        float iv = invD[k];
        float2 ps = pv2[s * 4 + c];
        acc.x = __fadd_rn(acc.x, __fmul_rn(__fsub_rn(pi.x, ps.x), iv));
        acc.y = __fadd_rn(acc.y, __fmul_rn(__fsub_rn(pi.y, ps.y), iv));
    }
    float dt = dt_eff_of(dtp);
    float2 uv = ((const float2*)u)[idx];
    float2 wv;
    wv.x = __fadd_rn(pi.x, __fmul_rn(dt, __fmul_rn(uv.x, acc.x)));
    wv.y = __fadd_rn(pi.y, __fmul_rn(dt, __fmul_rn(uv.y, acc.y)));
    ((float2*)w)[idx] = wv;
    float2 yv;
    yv.x = __fmul_rn(uv.x, wv.x);
    yv.y = __fmul_rn(uv.y, wv.y);
    ((float2*)y)[idx] = yv;
}

extern "C" void kernel_launch(void* const* d_in, const int* in_sizes, int n_in,
                              void* d_out, int out_size, void* d_ws, size_t ws_size,
                              hipStream_t stream) {
    const float* u   = (const float*)d_in[0];
    const int*   ei  = (const int*)d_in[1];
    const float* ea  = (const float*)d_in[2];
    const float* dtp = (const float*)d_in[3];
    const float* gp  = (const float*)d_in[4];

    const int NF = in_sizes[0];        // 1,600,000
    const int N  = NF / F;             // 200,000
    const int E  = in_sizes[2] / 2;    // 3,200,000
    const int* srcp = ei;
    const int* dstp = ei + E;

    // host-side pairwise-tree schedule (deterministic fn of NF; static so the
    // graph-replayed hipMemcpyAsync source stays valid)
    static Sched h_sched;
    build_sched_host(NF - 1, &h_sched);
    const int NL = h_sched.NL;

    char* wp = (char*)d_ws;
    float* scal    = (float*)wp; wp += 128 * 4;   // RS[it]@8+it, DONE[it]@64+it
    float* r       = (float*)wp; wp += (size_t)NF * 4;
    float* p       = (float*)wp; wp += (size_t)NF * 4;
    float* t       = (float*)wp; wp += (size_t)NF * 4;   // z
    float* w       = (float*)wp; wp += (size_t)NF * 4;
    float* y       = (float*)wp; wp += (size_t)NF * 4;   // u*w / u*b
    int*   dstList = (int*)wp;   wp += (size_t)E * 4;    // becomes srcA after k_perm
    int*   srcList = (int*)wp;   wp += (size_t)E * 4;    // becomes dstB after k_perm
    float* invD    = (float*)wp; wp += (size_t)E * 4;
    float* invS    = (float*)wp; wp += (size_t)E * 4;
    float* slopeD  = (float*)wp; wp += (size_t)E * 4;
    int*   dstOff  = (int*)wp;   wp += (size_t)(N + 1) * 4;
    int*   srcOff  = (int*)wp;   wp += (size_t)(N + 1) * 4;
    int*   dstCnt  = (int*)wp;   wp += (size_t)N * 4;
    int*   srcCnt  = (int*)wp;   wp += (size_t)N * 4;
    int*   cursD   = (int*)wp;   wp += (size_t)N * 4;
    int*   cursS   = (int*)wp;   wp += (size_t)N * 4;
    int*   bsD     = (int*)wp;   wp += 512 * 4;
    int*   bsS     = (int*)wp;   wp += 512 * 4;
    float* partial1 = (float*)wp; wp += 2048 * 4;
    float* partial2 = (float*)wp; wp += 2048 * 4;
    wp = (char*)(((uintptr_t)wp + 255) & ~(uintptr_t)255);
    Sched* d_sched = (Sched*)wp; wp += (sizeof(Sched) + 255) & ~(size_t)255;
    float* x = (float*)d_out;

    hipMemcpyAsync(d_sched, &h_sched, sizeof(Sched), hipMemcpyHostToDevice,
                   stream);
    hipMemsetAsync(scal, 0, 128 * 4, stream);
    hipMemsetAsync(dstCnt, 0, (size_t)N * 4, stream);
    hipMemsetAsync(srcCnt, 0, (size_t)N * 4, stream);
    hipMemsetAsync(cursD, 0, (size_t)N * 4, stream);
    hipMemsetAsync(cursS, 0, (size_t)N * 4, stream);

    const int bn = 256;
    const int gN  = (N + bn - 1) / bn;
    const int gE  = (E + bn - 1) / bn;
    const int nb  = (N + 511) / 512;
    const int n4  = NF / 4;
    const int g4  = (n4 + bn - 1) / bn;
    const int NP  = NF / 2;            // (node, feature-pair) threads
    const int gP  = (NP + bn - 1) / bn;

    // ---- CSR build (stable by edge id) ----
    k_edge_pre<<<gE, bn, 0, stream>>>(dstp, srcp, dstCnt, srcCnt, E);
    k_scan1<<<nb, 512, 0, stream>>>(dstCnt, dstOff, bsD, N);
    k_scan2<<<1, 512, 0, stream>>>(bsD, nb);
    k_scan3<<<nb, 512, 0, stream>>>(dstOff, bsD, dstCnt, N, E);
    k_scan1<<<nb, 512, 0, stream>>>(srcCnt, srcOff, bsS, N);
    k_scan2<<<1, 512, 0, stream>>>(bsS, nb);
    k_scan3<<<nb, 512, 0, stream>>>(srcOff, bsS, srcCnt, N, E);
    k_fill<<<gE, bn, 0, stream>>>(dstp, srcp, dstOff, srcOff, cursD, cursS,
                                  dstList, srcList, E);
    k_sort<<<gN, bn, 0, stream>>>(dstOff, srcOff, dstList, srcList, N);
    k_perm<<<gE, bn, 0, stream>>>(dstList, srcList, srcp, dstp, ea,
                                  invD, slopeD, invS, E);
    const int* srcA = dstList;   // after k_perm
    const int* dstB = srcList;   // after k_perm

    // ---- setup: b->r, y=u*b ; p = b + dt*D1T(y) ; r=p, x=0 ; RS[0] = p.p ----
    k_slope_b<<<gN, bn, 0, stream>>>(u, slopeD, dstOff, r, y, dtp, gp, N);
    k_d1tz<<<gP, bn, 0, stream>>>(dstB, dstOff, invD, srcOff, invS,
                                  y, r, p, dtp, r, x, 1, NP);
    k_dot_leaf<<<NL, 256, 0, stream>>>(p, p, d_sched, partial1);
    k_dot_rs0<<<1, 256, 0, stream>>>(p, partial1, d_sched, scal);

    // ---- CG loop (5 dispatches/iter) ----
    for (int it = 0; it < CG_ITERS; ++it) {
        k_d1w<<<gP, bn, 0, stream>>>(srcA, dstOff, invD, p, u, w, y, dtp, NP);
        k_d1tz<<<gP, bn, 0, stream>>>(dstB, dstOff, invD, srcOff, invS,
                                      y, w, t, dtp, (float*)0, (float*)0, 0, NP);
        k_dot_leaf<<<NL, 256, 0, stream>>>(p, t, d_sched, partial1);
        k_xr_dot<<<NL, 256, 0, stream>>>(x, r, p, t, scal, d_sched,
                                         partial1, partial2, it);
        k_p_fin<<<g4, bn, 0, stream>>>((float4*)p, (const float4*)r, r, scal,
                                       d_sched, partial2, it, n4);
    }
}

// Round 7
// 4812.003 us; speedup vs baseline: 1.8655x; 1.0459x over previous
//
#include <hip/hip_runtime.h>
#include <math.h>
#include <stdint.h>
#include <string.h>

// PhysicsLSGStep: bitwise-faithful f32 replication of the numpy reference.
// R18 (on top of R17):
//  - k_d1tz's dst-side loop is FUSED into k_d1w (k_d1w_f): after w,y rows are
//    computed (in registers), a second pass over the L2-hot edge segment
//    accumulates dacc = sum(y[i]*inv) with the identical __fadd_rn chain.
//    k_d1tzs starts from acc = dacc[idx] and does only the src-side gather =>
//    the running value sees the exact same op sequence as before (bit-exact).
//    Saves per iter: 6.4MB y re-read + cold 12.8MB invD stream + kernel ramp.
//  - Edge operands packed: edD[k]={src,inv} (dst-CSR), edS[k]={dst,inv}
//    (src-CSR), 8B aligned => one dwordx2 per edge instead of two dwords.
// Scatter sums stay in sorted-edge-id (CSR) order; dots replay the exact
// numpy pairwise tree (level-parallel, pairings unchanged). f32 __f*_rn only.

#define F 8
#define CG_ITERS 30
#define LEAF_T 4096
#define LEAF_PAD (LEAF_T + LEAF_T / 128 + 8)
#define ENC_ADD 1024   // operand encoding: <1024 = base/leaf slot, else add t+1024
#define MAX_LEAF 1024
#define MAX_CLS 32

// scal slots: RS[it] = scal[8+it], DONE[it] = scal[64+it]  (it = 0..CG_ITERS)

// padded-LDS accessor (bank-spread: +1 word every 128)
#define LV(A_, i_) A_[(i_) + ((i_) >> 7)]

struct __align__(8) Ed { int n; float v; };   // packed edge operand

struct Sched {
    int NL, uNT, uMaxD, nCls;
    int leafOff[MAX_LEAF], leafN[MAX_LEAF], cls[MAX_LEAF];
    int cNB[MAX_CLS], cMaxD[MAX_CLS];
    int cBOff[MAX_CLS][64], cBN[MAX_CLS][64];
    int cA[MAX_CLS][64], cB[MAX_CLS][64], cOrder[MAX_CLS][64];
    int cLevOff[MAX_CLS][32];
    int uA[MAX_LEAF], uB[MAX_LEAF], uOrder[MAX_LEAF], uLevOff[64];
};

// ---------------- host-side schedule build (exact integer replica) --------

static void host_build_tree(int n, int T, int* bOff, int* bN,
                            int* A, int* B, int* dep,
                            int* pNB, int* pNT, int* pMaxD) {
    int so[64], sn[64], st[64], sid[64], sdp[64];
    int sp = 0, coff = 0, cn = n, c2 = 0, t = 0, rootd = 0;
    for (;;) {
        if (cn <= T) {
            if (bOff) { bOff[c2] = coff; bN[c2] = cn; }
            int id = c2, dp = 0; c2++;
            bool fin = false;
            for (;;) {
                if (sp == 0) { rootd = dp; fin = true; break; }
                if (st[sp - 1] == 0) {
                    st[sp - 1] = 1; sid[sp - 1] = id; sdp[sp - 1] = dp;
                    int n2 = sn[sp - 1] / 2; n2 -= (n2 & 7);
                    coff = so[sp - 1] + n2; cn = sn[sp - 1] - n2;
                    break;
                } else {
                    A[t] = sid[sp - 1]; B[t] = id;  // add = stored(left)+cur(right)
                    int dA = sdp[sp - 1];
                    dp = ((dA > dp) ? dA : dp) + 1;
                    dep[t] = dp;
                    id = ENC_ADD + t; t++;
                    sp--;
                }
            }
            if (fin) break;
        } else {
            so[sp] = coff; sn[sp] = cn; st[sp] = 0; sp++;
            int n2 = cn / 2; n2 -= (n2 & 7);
            cn = n2;
        }
    }
    *pNB = c2; *pNT = t; *pMaxD = rootd;
}

static void host_bucketize(const int* dep, int NT, int maxD,
                           int* order, int* levOff) {
    int cnt[64];
    for (int d = 0; d <= maxD; ++d) cnt[d] = 0;
    for (int t = 0; t < NT; ++t) cnt[dep[t]]++;
    int run = 0;
    levOff[0] = 0;
    for (int d = 1; d <= maxD; ++d) { run += cnt[d]; levOff[d] = run; }
    int cur[64];
    for (int d = 1; d <= maxD; ++d) cur[d] = levOff[d - 1];
    for (int t = 0; t < NT; ++t) { int d = dep[t]; order[cur[d]++] = t; }
}

static void build_sched_host(int n, Sched* s) {   // n = NF-1
    static int uDep[MAX_LEAF];
    host_build_tree(n, LEAF_T, s->leafOff, s->leafN, s->uA, s->uB, uDep,
                    &s->NL, &s->uNT, &s->uMaxD);
    host_bucketize(uDep, s->uNT, s->uMaxD, s->uOrder, s->uLevOff);
    s->nCls = 0;
    int clsN[MAX_CLS];
    int dep[64];
    for (int j = 0; j < s->NL; ++j) {
        int c = -1;
        for (int k = 0; k < s->nCls; ++k)
            if (clsN[k] == s->leafN[j]) { c = k; break; }
        if (c < 0 && s->nCls < MAX_CLS) {
            c = s->nCls++;
            clsN[c] = s->leafN[j];
            int NB, NT, maxD;
            host_build_tree(s->leafN[j], 128, s->cBOff[c], s->cBN[c],
                            s->cA[c], s->cB[c], dep, &NB, &NT, &maxD);
            s->cNB[c] = NB; s->cMaxD[c] = maxD;
            host_bucketize(dep, NT, maxD, s->cOrder[c], s->cLevOff[c]);
        }
        s->cls[j] = c;
    }
}

// ---------------- device ----------------

__device__ __forceinline__ float dt_eff_of(const float* dtp) {
    return fminf(fmaxf(dtp[0], 0.02f), 2.0f);
}

__device__ __forceinline__ int slotOf(int e, int NB) {
    return (e < ENC_ADD) ? e : (NB + (e - ENC_ADD));
}

// level-parallel upper-tree combine of partial[0..NL) into sU; returns root
// on all lanes (after final barrier). blockDim = 256.
__device__ __forceinline__ float combine_upper(const float* __restrict__ partial,
                                               const Sched* __restrict__ sc,
                                               float* sU, int lane) {
    int NL = sc->NL, NT = sc->uNT, maxD = sc->uMaxD;
    for (int k = lane; k < NL; k += 256) sU[k] = partial[k];
    __syncthreads();
    for (int d = 1; d <= maxD; ++d) {
        int s0 = sc->uLevOff[d - 1], s1 = sc->uLevOff[d];
        for (int s = s0 + lane; s < s1; s += 256) {
            int tt = sc->uOrder[s];
            sU[NL + tt] = __fadd_rn(sU[slotOf(sc->uA[tt], NL)],
                                    sU[slotOf(sc->uB[tt], NL)]);
        }
        __syncthreads();
    }
    return (NT > 0) ? sU[NL + NT - 1] : sU[0];
}

// shared tail of the leaf-dot: 8-way base chains + exact combine + tree eval.
// sA/sB may alias (r.r dot). blockDim = 256.
__device__ __forceinline__ void dot_eval(const float* sA, const float* sB,
                                         float* sChain, float* sVal,
                                         int lane, int NB,
                                         const int* __restrict__ bOff,
                                         const int* __restrict__ bN,
                                         const int* __restrict__ A,
                                         const int* __restrict__ Bb,
                                         const int* __restrict__ order,
                                         const int* __restrict__ levOff,
                                         int maxD,
                                         float* __restrict__ partial, int j) {
    // phase A: chain r_j of base block bb on lane bb*8+j (independent chains)
    int bb = lane >> 3, jj = lane & 7;
    if (bb < NB) {
        int off = bOff[bb], n = bN[bb];
        if (n >= 8) {
            int lim = n - (n & 7);
            float rr = __fmul_rn(LV(sA, off + jj), LV(sB, off + jj));
            for (int e = jj + 8; e < lim; e += 8)
                rr = __fadd_rn(rr, __fmul_rn(LV(sA, off + e), LV(sB, off + e)));
            sChain[bb * 8 + jj] = rr;
        }
    }
    __syncthreads();
    // phase B: exact combine tree + exact tail per base block
    if (lane < NB) {
        int off = bOff[lane], n = bN[lane];
        float res;
        if (n < 8) {
            res = 0.f;
            for (int e = 0; e < n; ++e)
                res = __fadd_rn(res, __fmul_rn(LV(sA, off + e), LV(sB, off + e)));
        } else {
            int lim = n - (n & 7);
            const float* c = sChain + lane * 8;
            res = __fadd_rn(__fadd_rn(__fadd_rn(c[0], c[1]), __fadd_rn(c[2], c[3])),
                            __fadd_rn(__fadd_rn(c[4], c[5]), __fadd_rn(c[6], c[7])));
            for (int e = lim; e < n; ++e)
                res = __fadd_rn(res, __fmul_rn(LV(sA, off + e), LV(sB, off + e)));
        }
        sVal[lane] = res;
    }
    __syncthreads();
    // phase C: level-parallel replay of the leaf combine tree
    for (int d = 1; d <= maxD; ++d) {
        int s0 = levOff[d - 1], s1 = levOff[d];
        for (int s = s0 + lane; s < s1; s += 256) {
            int tt = order[s];
            sVal[NB + tt] = __fadd_rn(sVal[slotOf(A[tt], NB)],
                                      sVal[slotOf(Bb[tt], NB)]);
        }
        __syncthreads();
    }
    if (lane == 0) partial[j] = (NB > 1) ? sVal[NB + NB - 2] : sVal[0];
}

// per-leaf dot partial (a.b). grid = NL blocks, 256 threads.
__global__ void k_dot_leaf(const float* __restrict__ a, const float* __restrict__ b,
                           const Sched* __restrict__ sc, float* __restrict__ partial) {
    __shared__ float sA[LEAF_PAD], sB[LEAF_PAD];
    __shared__ float sChain[512];
    __shared__ float sVal[160];
    int j = blockIdx.x, lane = threadIdx.x;
    int P = sc->leafOff[j] + 1, nn = sc->leafN[j];
    for (int g = lane; g < nn; g += 256) {
        float av = a[P + g], bv = b[P + g];
        int m = g + (g >> 7);
        sA[m] = av; sB[m] = bv;
    }
    __syncthreads();
    int c = sc->cls[j];
    dot_eval(sA, sB, sChain, sVal, lane, sc->cNB[c], sc->cBOff[c], sc->cBN[c],
             sc->cA[c], sc->cB[c], sc->cOrder[c], sc->cLevOff[c], sc->cMaxD[c],
             partial, j);
}

// setup-only: RS[0] = p.p from partial + first-element term. 1 block.
__global__ void k_dot_rs0(const float* __restrict__ a,
                          const float* __restrict__ partial,
                          const Sched* __restrict__ sc, float* __restrict__ scal) {
    __shared__ float sU[2048];
    int lane = threadIdx.x;
    float res = combine_upper(partial, sc, sU, lane);
    if (lane == 0)
        scal[8 + 0] = __fadd_rn(__fmul_rn(a[0], a[0]), res);
}

// fused: combine partial1 -> alpha (every block, redundantly);
// x += a*p ; r -= a*z (guarded by DONE[it]) over this leaf; dot fresh r.
__global__ void k_xr_dot(float* __restrict__ x, float* __restrict__ r,
                         const float* __restrict__ p, const float* __restrict__ z,
                         const float* __restrict__ scal,
                         const Sched* __restrict__ sc,
                         const float* __restrict__ partial1,
                         float* __restrict__ partial2, int it) {
    __shared__ float sA[LEAF_PAD];
    __shared__ float sU[2048];
    __shared__ float sChain[512];
    __shared__ float sVal[160];
    __shared__ float sAl;
    __shared__ int   sAct;
    int j = blockIdx.x, lane = threadIdx.x;
    float res = combine_upper(partial1, sc, sU, lane);
    if (lane == 0) {
        float pt = __fadd_rn(__fmul_rn(p[0], z[0]), res);
        sAl = __fdiv_rn(scal[8 + it], __fadd_rn(pt, (float)1e-12));
        sAct = (scal[64 + it] == 0.f) ? 1 : 0;
    }
    __syncthreads();
    int active = sAct;
    float al = sAl;
    int P = sc->leafOff[j] + 1, nn = sc->leafN[j];
    if (j == 0 && lane == 0 && active) {
        x[0] = __fadd_rn(x[0], __fmul_rn(al, p[0]));
        r[0] = __fsub_rn(r[0], __fmul_rn(al, z[0]));
    }
    for (int g = lane; g < nn; g += 256) {
        int q = P + g;
        float rv = r[q];
        if (active) {
            float xv = x[q], pv = p[q], zv = z[q];
            x[q] = __fadd_rn(xv, __fmul_rn(al, pv));
            rv = __fsub_rn(rv, __fmul_rn(al, zv));
            r[q] = rv;
        }
        sA[g + (g >> 7)] = rv;
    }
    __syncthreads();
    int c = sc->cls[j];
    dot_eval(sA, sA, sChain, sVal, lane, sc->cNB[c], sc->cBOff[c], sc->cBN[c],
             sc->cA[c], sc->cB[c], sc->cOrder[c], sc->cLevOff[c], sc->cMaxD[c],
             partial2, j);
}

// fused: combine partial2 -> rs1/beta (every block); p = r + beta*p (guarded);
// block 0 writes RS[it+1], DONE[it+1].
__global__ void k_p_fin(float4* __restrict__ p4, const float4* __restrict__ r4,
                        const float* __restrict__ rfull,
                        float* __restrict__ scal,
                        const Sched* __restrict__ sc,
                        const float* __restrict__ partial2, int it, int n4) {
    __shared__ float sU[2048];
    __shared__ float sBe;
    __shared__ int   sAct;
    int lane = threadIdx.x;
    float res = combine_upper(partial2, sc, sU, lane);
    if (lane == 0) {
        float rs1 = __fadd_rn(__fmul_rn(rfull[0], rfull[0]), res);
        float RS = scal[8 + it];
        float dn = scal[64 + it];
        sBe = __fdiv_rn(rs1, __fadd_rn(RS, (float)1e-12));
        sAct = (dn == 0.f) ? 1 : 0;
        if (blockIdx.x == 0) {
            scal[8 + it + 1]  = (dn == 0.f) ? rs1 : RS;
            scal[64 + it + 1] = (dn != 0.f || __fsqrt_rn(rs1) <= (float)1e-4)
                                ? 1.f : 0.f;
        }
    }
    __syncthreads();
    if (!sAct) return;
    float be = sBe;
    int i = blockIdx.x * blockDim.x + lane;
    if (i >= n4) return;
    float4 pv = p4[i], rv = r4[i];
    pv.x = __fadd_rn(rv.x, __fmul_rn(be, pv.x));
    pv.y = __fadd_rn(rv.y, __fmul_rn(be, pv.y));
    pv.z = __fadd_rn(rv.z, __fmul_rn(be, pv.z));
    pv.w = __fadd_rn(rv.w, __fmul_rn(be, pv.w));
    p4[i] = pv;
}

// ---------- CSR build (stable in edge order) ----------

__global__ void k_edge_pre(const int* __restrict__ dst, const int* __restrict__ src,
                           int* __restrict__ dstCnt, int* __restrict__ srcCnt, int E) {
    int e = blockIdx.x * blockDim.x + threadIdx.x;
    if (e >= E) return;
    atomicAdd(&dstCnt[dst[e]], 1);
    atomicAdd(&srcCnt[src[e]], 1);
}

__global__ void k_scan1(const int* __restrict__ cnt, int* __restrict__ incl,
                        int* __restrict__ bsums, int N) {
    __shared__ int sm[512];
    int i = blockIdx.x * 512 + threadIdx.x;
    sm[threadIdx.x] = (i < N) ? cnt[i] : 0;
    __syncthreads();
    for (int off = 1; off < 512; off <<= 1) {
        int t = (threadIdx.x >= off) ? sm[threadIdx.x - off] : 0;
        __syncthreads();
        sm[threadIdx.x] += t;
        __syncthreads();
    }
    if (i < N) incl[i] = sm[threadIdx.x];
    if (threadIdx.x == 511) bsums[blockIdx.x] = sm[511];
}

__global__ void k_scan2(int* __restrict__ bsums, int nb) {
    __shared__ int sm[512];
    sm[threadIdx.x] = (threadIdx.x < nb) ? bsums[threadIdx.x] : 0;
    __syncthreads();
    for (int off = 1; off < 512; off <<= 1) {
        int t = (threadIdx.x >= off) ? sm[threadIdx.x - off] : 0;
        __syncthreads();
        sm[threadIdx.x] += t;
        __syncthreads();
    }
    if (threadIdx.x < nb) bsums[threadIdx.x] = sm[threadIdx.x];
}

__global__ void k_scan3(int* __restrict__ off, const int* __restrict__ bsums,
                        const int* __restrict__ cnt, int N, int E) {
    int i = blockIdx.x * 512 + threadIdx.x;
    if (i < N) {
        int add = (blockIdx.x > 0) ? bsums[blockIdx.x - 1] : 0;
        off[i] = off[i] + add - cnt[i];  // exclusive
    }
    if (i == 0) off[N] = E;
}

__global__ void k_fill(const int* __restrict__ dst, const int* __restrict__ src,
                       const int* __restrict__ dstOff, const int* __restrict__ srcOff,
                       int* __restrict__ cursD, int* __restrict__ cursS,
                       int* __restrict__ dstList, int* __restrict__ srcList, int E) {
    int e = blockIdx.x * blockDim.x + threadIdx.x;
    if (e >= E) return;
    int d = dst[e];
    dstList[dstOff[d] + atomicAdd(&cursD[d], 1)] = e;
    int s0 = src[e];
    srcList[srcOff[s0] + atomicAdd(&cursS[s0], 1)] = e;
}

__device__ __forceinline__ void insort(int* L, int lo, int hi) {
    for (int a = lo + 1; a < hi; ++a) {
        int key = L[a]; int b = a - 1;
        while (b >= lo && L[b] > key) { L[b + 1] = L[b]; b--; }
        L[b + 1] = key;
    }
}

__global__ void k_sort(const int* __restrict__ dstOff, const int* __restrict__ srcOff,
                       int* __restrict__ dstList, int* __restrict__ srcList, int N) {
    int i = blockIdx.x * blockDim.x + threadIdx.x;
    if (i >= N) return;
    insort(dstList, dstOff[i], dstOff[i + 1]);
    insort(srcList, srcOff[i], srcOff[i + 1]);
}

// Permute per-edge operands into CSR order: packed {src,inv} / {dst,inv}.
__global__ void k_perm(const int* __restrict__ dstList, const int* __restrict__ srcList,
                       const int* __restrict__ srcp, const int* __restrict__ dstp,
                       const float* __restrict__ ea,
                       Ed* __restrict__ edD, float* __restrict__ slopeD,
                       Ed* __restrict__ edS, int E) {
    int k = blockIdx.x * blockDim.x + threadIdx.x;
    if (k >= E) return;
    int e  = dstList[k];
    int e2 = srcList[k];
    float dx  = fmaxf(ea[2 * e], 1e-6f);
    float dx2 = fmaxf(ea[2 * e2], 1e-6f);
    Ed d0; d0.n = srcp[e];  d0.v = __fdiv_rn(1.f, dx);
    Ed s0; s0.n = dstp[e2]; s0.v = __fdiv_rn(1.f, dx2);
    float sD = __fdiv_rn(ea[2 * e + 1], dx);
    edD[k] = d0;
    edS[k] = s0;
    slopeD[k] = sD;
}

// ---------- physics kernels (exact np op order, f32 sequential) ----------

__global__ void k_slope_b(const float* __restrict__ u, const float* __restrict__ slopeD,
                          const int* __restrict__ dstOff,
                          float* __restrict__ r, float* __restrict__ y,
                          const float* __restrict__ dtp, const float* __restrict__ gp,
                          int N) {
    int i = blockIdx.x * blockDim.x + threadIdx.x;
    if (i >= N) return;
    float dtg = __fmul_rn(dt_eff_of(dtp), gp[0]);
    float sn = 0.f;
    int k0 = dstOff[i], k1 = dstOff[i + 1];
    for (int k = k0; k < k1; ++k) sn = __fadd_rn(sn, slopeD[k]);
    float ms = __fmul_rn(dtg, sn);
    const float4* u4 = (const float4*)u;
    float4* r4 = (float4*)r;
    float4* y4 = (float4*)y;
    #pragma unroll
    for (int hh = 0; hh < 2; ++hh) {
        float4 uv = u4[i * 2 + hh];
        float4 bv;
        bv.x = __fsub_rn(uv.x, ms);
        bv.y = __fsub_rn(uv.y, ms);
        bv.z = __fsub_rn(uv.z, ms);
        bv.w = __fsub_rn(uv.w, ms);
        r4[i * 2 + hh] = bv;
        float4 yv;
        yv.x = __fmul_rn(uv.x, bv.x);
        yv.y = __fmul_rn(uv.y, bv.y);
        yv.z = __fmul_rn(uv.z, bv.z);
        yv.w = __fmul_rn(uv.w, bv.w);
        y4[i * 2 + hh] = yv;
    }
}

// Full D1_T (setup only): both loops; out = base + dt*acc; doInit r/x.
// thread = (node, feature-pair).
__global__ void k_d1tz_full(const Ed* __restrict__ edD, const int* __restrict__ dstOff,
                            const Ed* __restrict__ edS, const int* __restrict__ srcOff,
                            const float* __restrict__ y,
                            const float* __restrict__ base, float* __restrict__ out,
                            const float* __restrict__ dtp,
                            float* __restrict__ rInit, float* __restrict__ xInit,
                            int NP) {
    int idx = blockIdx.x * blockDim.x + threadIdx.x;
    if (idx >= NP) return;
    int i = idx >> 2, c = idx & 3;
    const float2* y2 = (const float2*)y;
    float2 uy = y2[idx];
    float2 acc = make_float2(0.f, 0.f);
    int k0 = dstOff[i], k1 = dstOff[i + 1];
    #pragma unroll 4
    for (int k = k0; k < k1; ++k) {
        float iv = edD[k].v;
        acc.x = __fadd_rn(acc.x, __fmul_rn(uy.x, iv));
        acc.y = __fadd_rn(acc.y, __fmul_rn(uy.y, iv));
    }
    k0 = srcOff[i]; k1 = srcOff[i + 1];
    #pragma unroll 4
    for (int k = k0; k < k1; ++k) {
        Ed e = edS[k];
        float2 yd = y2[e.n * 4 + c];
        float t0 = __fmul_rn(yd.x, e.v); acc.x = __fadd_rn(acc.x, -t0);
        float t1 = __fmul_rn(yd.y, e.v); acc.y = __fadd_rn(acc.y, -t1);
    }
    float dt = dt_eff_of(dtp);
    float2 bs = ((const float2*)base)[idx];
    float2 ov;
    ov.x = __fadd_rn(bs.x, __fmul_rn(dt, acc.x));
    ov.y = __fadd_rn(bs.y, __fmul_rn(dt, acc.y));
    ((float2*)out)[idx] = ov;
    ((float2*)rInit)[idx] = ov;
    ((float2*)xInit)[idx] = make_float2(0.f, 0.f);
}

// Loop kernel 1: D1(p) -> w = p + dt*(u*acc), y = u*w, AND the dst-side of
// next D1_T: dacc = sum_k y[i]*invD[k] (y row in registers; same add chain).
__global__ void k_d1w_f(const Ed* __restrict__ edD, const int* __restrict__ dstOff,
                        const float* __restrict__ pv, const float* __restrict__ u,
                        float* __restrict__ w, float* __restrict__ y,
                        float* __restrict__ dacc,
                        const float* __restrict__ dtp, int NP) {
    int idx = blockIdx.x * blockDim.x + threadIdx.x;
    if (idx >= NP) return;
    int i = idx >> 2, c = idx & 3;
    const float2* pv2 = (const float2*)pv;
    float2 pi = pv2[idx];
    float2 acc = make_float2(0.f, 0.f);
    int k0 = dstOff[i], k1 = dstOff[i + 1];
    #pragma unroll 4
    for (int k = k0; k < k1; ++k) {
        Ed e = edD[k];
        float2 ps = pv2[e.n * 4 + c];
        acc.x = __fadd_rn(acc.x, __fmul_rn(__fsub_rn(pi.x, ps.x), e.v));
        acc.y = __fadd_rn(acc.y, __fmul_rn(__fsub_rn(pi.y, ps.y), e.v));
    }
    float dt = dt_eff_of(dtp);
    float2 uv = ((const float2*)u)[idx];
    float2 wv;
    wv.x = __fadd_rn(pi.x, __fmul_rn(dt, __fmul_rn(uv.x, acc.x)));
    wv.y = __fadd_rn(pi.y, __fmul_rn(dt, __fmul_rn(uv.y, acc.y)));
    ((float2*)w)[idx] = wv;
    float2 yv;
    yv.x = __fmul_rn(uv.x, wv.x);
    yv.y = __fmul_rn(uv.y, wv.y);
    ((float2*)y)[idx] = yv;
    // dst-side accumulation of D1_T with yv in registers (L2-hot re-stream)
    float2 da = make_float2(0.f, 0.f);
    #pragma unroll 4
    for (int k = k0; k < k1; ++k) {
        float iv = edD[k].v;
        da.x = __fadd_rn(da.x, __fmul_rn(yv.x, iv));
        da.y = __fadd_rn(da.y, __fmul_rn(yv.y, iv));
    }
    ((float2*)dacc)[idx] = da;
}

// Loop kernel 2: src-side of D1_T continuing from dacc; t = w + dt*acc.
__global__ void k_d1tzs(const Ed* __restrict__ edS, const int* __restrict__ srcOff,
                        const float* __restrict__ y, const float* __restrict__ dacc,
                        const float* __restrict__ base, float* __restrict__ out,
                        const float* __restrict__ dtp, int NP) {
    int idx = blockIdx.x * blockDim.x + threadIdx.x;
    if (idx >= NP) return;
    int i = idx >> 2, c = idx & 3;
    const float2* y2 = (const float2*)y;
    float2 acc = ((const float2*)dacc)[idx];
    int k0 = srcOff[i], k1 = srcOff[i + 1];
    #pragma unroll 4
    for (int k = k0; k < k1; ++k) {
        Ed e = edS[k];
        float2 yd = y2[e.n * 4 + c];
        float t0 = __fmul_rn(yd.x, e.v); acc.x = __fadd_rn(acc.x, -t0);
        float t1 = __fmul_rn(yd.y, e.v); acc.y = __fadd_rn(acc.y, -t1);
    }
    float dt = dt_eff_of(dtp);
    float2 bs = ((const float2*)base)[idx];
    float2 ov;
    ov.x = __fadd_rn(bs.x, __fmul_rn(dt, acc.x));
    ov.y = __fadd_rn(bs.y, __fmul_rn(dt, acc.y));
    ((float2*)out)[idx] = ov;
}

extern "C" void kernel_launch(void* const* d_in, const int* in_sizes, int n_in,
                              void* d_out, int out_size, void* d_ws, size_t ws_size,
                              hipStream_t stream) {
    const float* u   = (const float*)d_in[0];
    const int*   ei  = (const int*)d_in[1];
    const float* ea  = (const float*)d_in[2];
    const float* dtp = (const float*)d_in[3];
    const float* gp  = (const float*)d_in[4];

    const int NF = in_sizes[0];        // 1,600,000
    const int N  = NF / F;             // 200,000
    const int E  = in_sizes[2] / 2;    // 3,200,000
    const int* srcp = ei;
    const int* dstp = ei + E;

    // host-side pairwise-tree schedule (deterministic fn of NF; static so the
    // graph-replayed hipMemcpyAsync source stays valid)
    static Sched h_sched;
    build_sched_host(NF - 1, &h_sched);
    const int NL = h_sched.NL;

    char* wp = (char*)d_ws;
    float* scal    = (float*)wp; wp += 128 * 4;   // RS[it]@8+it, DONE[it]@64+it
    float* r       = (float*)wp; wp += (size_t)NF * 4;
    float* p       = (float*)wp; wp += (size_t)NF * 4;
    float* t       = (float*)wp; wp += (size_t)NF * 4;   // z
    float* w       = (float*)wp; wp += (size_t)NF * 4;
    float* y       = (float*)wp; wp += (size_t)NF * 4;   // u*w / u*b
    float* dacc    = (float*)wp; wp += (size_t)NF * 4;   // dst-side D1_T partial
    int*   dstList = (int*)wp;   wp += (size_t)E * 4;
    int*   srcList = (int*)wp;   wp += (size_t)E * 4;
    Ed*    edD     = (Ed*)wp;    wp += (size_t)E * 8;    // {src,inv} dst-CSR
    Ed*    edS     = (Ed*)wp;    wp += (size_t)E * 8;    // {dst,inv} src-CSR
    float* slopeD  = (float*)wp; wp += (size_t)E * 4;
    int*   dstOff  = (int*)wp;   wp += (size_t)(N + 1) * 4;
    int*   srcOff  = (int*)wp;   wp += (size_t)(N + 1) * 4;
    int*   dstCnt  = (int*)wp;   wp += (size_t)N * 4;
    int*   srcCnt  = (int*)wp;   wp += (size_t)N * 4;
    int*   cursD   = (int*)wp;   wp += (size_t)N * 4;
    int*   cursS   = (int*)wp;   wp += (size_t)N * 4;
    int*   bsD     = (int*)wp;   wp += 512 * 4;
    int*   bsS     = (int*)wp;   wp += 512 * 4;
    float* partial1 = (float*)wp; wp += 2048 * 4;
    float* partial2 = (float*)wp; wp += 2048 * 4;
    wp = (char*)(((uintptr_t)wp + 255) & ~(uintptr_t)255);
    Sched* d_sched = (Sched*)wp; wp += (sizeof(Sched) + 255) & ~(size_t)255;
    float* x = (float*)d_out;

    hipMemcpyAsync(d_sched, &h_sched, sizeof(Sched), hipMemcpyHostToDevice,
                   stream);
    hipMemsetAsync(scal, 0, 128 * 4, stream);
    hipMemsetAsync(dstCnt, 0, (size_t)N * 4, stream);
    hipMemsetAsync(srcCnt, 0, (size_t)N * 4, stream);
    hipMemsetAsync(cursD, 0, (size_t)N * 4, stream);
    hipMemsetAsync(cursS, 0, (size_t)N * 4, stream);

    const int bn = 256;
    const int gN  = (N + bn - 1) / bn;
    const int gE  = (E + bn - 1) / bn;
    const int nb  = (N + 511) / 512;
    const int n4  = NF / 4;
    const int g4  = (n4 + bn - 1) / bn;
    const int NP  = NF / 2;            // (node, feature-pair) threads
    const int gP  = (NP + bn - 1) / bn;

    // ---- CSR build (stable by edge id) ----
    k_edge_pre<<<gE, bn, 0, stream>>>(dstp, srcp, dstCnt, srcCnt, E);
    k_scan1<<<nb, 512, 0, stream>>>(dstCnt, dstOff, bsD, N);
    k_scan2<<<1, 512, 0, stream>>>(bsD, nb);
    k_scan3<<<nb, 512, 0, stream>>>(dstOff, bsD, dstCnt, N, E);
    k_scan1<<<nb, 512, 0, stream>>>(srcCnt, srcOff, bsS, N);
    k_scan2<<<1, 512, 0, stream>>>(bsS, nb);
    k_scan3<<<nb, 512, 0, stream>>>(srcOff, bsS, srcCnt, N, E);
    k_fill<<<gE, bn, 0, stream>>>(dstp, srcp, dstOff, srcOff, cursD, cursS,
                                  dstList, srcList, E);
    k_sort<<<gN, bn, 0, stream>>>(dstOff, srcOff, dstList, srcList, N);
    k_perm<<<gE, bn, 0, stream>>>(dstList, srcList, srcp, dstp, ea,
                                  edD, slopeD, edS, E);

    // ---- setup: b->r, y=u*b ; p = b + dt*D1T(y) ; r=p, x=0 ; RS[0] = p.p ----
    k_slope_b<<<gN, bn, 0, stream>>>(u, slopeD, dstOff, r, y, dtp, gp, N);
    k_d1tz_full<<<gP, bn, 0, stream>>>(edD, dstOff, edS, srcOff,
                                       y, r, p, dtp, r, x, NP);
    k_dot_leaf<<<NL, 256, 0, stream>>>(p, p, d_sched, partial1);
    k_dot_rs0<<<1, 256, 0, stream>>>(p, partial1, d_sched, scal);

    // ---- CG loop (5 dispatches/iter) ----
    for (int it = 0; it < CG_ITERS; ++it) {
        k_d1w_f<<<gP, bn, 0, stream>>>(edD, dstOff, p, u, w, y, dacc, dtp, NP);
        k_d1tzs<<<gP, bn, 0, stream>>>(edS, srcOff, y, dacc, w, t, dtp, NP);
        k_dot_leaf<<<NL, 256, 0, stream>>>(p, t, d_sched, partial1);
        k_xr_dot<<<NL, 256, 0, stream>>>(x, r, p, t, scal, d_sched,
                                         partial1, partial2, it);
        k_p_fin<<<g4, bn, 0, stream>>>((float4*)p, (const float4*)r, r, scal,
                                       d_sched, partial2, it, n4);
    }
}

// Round 8
// 4662.332 us; speedup vs baseline: 1.9254x; 1.0321x over previous
//
#include <hip/hip_runtime.h>
#include <math.h>
#include <stdint.h>
#include <string.h>

// PhysicsLSGStep: bitwise-faithful f32 replication of the numpy reference.
// R19 (on top of R18): CSR build refactor — k_perm (3 random gather streams
// of ~205MB line traffic each) is DELETED. k_fill now scatters 16B records
// {e, other_node, inv, slope} built from COALESCED edge-order reads (dst[e],
// src[e], ea as float2); k_sort orders records by .e (same final order);
// k_compact splits into edD/edS/slopeD with fully-sequential IO. All float
// ops (fmaxf + __fdiv_rn) identical, just moved => bit-exact. Loop untouched.
// Scatter sums stay in sorted-edge-id (CSR) order; dots replay the exact
// numpy pairwise tree (level-parallel, pairings unchanged). f32 __f*_rn only.

#define F 8
#define CG_ITERS 30
#define LEAF_T 4096
#define LEAF_PAD (LEAF_T + LEAF_T / 128 + 8)
#define ENC_ADD 1024   // operand encoding: <1024 = base/leaf slot, else add t+1024
#define MAX_LEAF 1024
#define MAX_CLS 32

// scal slots: RS[it] = scal[8+it], DONE[it] = scal[64+it]  (it = 0..CG_ITERS)

// padded-LDS accessor (bank-spread: +1 word every 128)
#define LV(A_, i_) A_[(i_) + ((i_) >> 7)]

struct __align__(8) Ed { int n; float v; };          // packed edge operand
struct __align__(16) Rec { int e; int n; float v; float s; };  // fill record

struct Sched {
    int NL, uNT, uMaxD, nCls;
    int leafOff[MAX_LEAF], leafN[MAX_LEAF], cls[MAX_LEAF];
    int cNB[MAX_CLS], cMaxD[MAX_CLS];
    int cBOff[MAX_CLS][64], cBN[MAX_CLS][64];
    int cA[MAX_CLS][64], cB[MAX_CLS][64], cOrder[MAX_CLS][64];
    int cLevOff[MAX_CLS][32];
    int uA[MAX_LEAF], uB[MAX_LEAF], uOrder[MAX_LEAF], uLevOff[64];
};

// ---------------- host-side schedule build (exact integer replica) --------

static void host_build_tree(int n, int T, int* bOff, int* bN,
                            int* A, int* B, int* dep,
                            int* pNB, int* pNT, int* pMaxD) {
    int so[64], sn[64], st[64], sid[64], sdp[64];
    int sp = 0, coff = 0, cn = n, c2 = 0, t = 0, rootd = 0;
    for (;;) {
        if (cn <= T) {
            if (bOff) { bOff[c2] = coff; bN[c2] = cn; }
            int id = c2, dp = 0; c2++;
            bool fin = false;
            for (;;) {
                if (sp == 0) { rootd = dp; fin = true; break; }
                if (st[sp - 1] == 0) {
                    st[sp - 1] = 1; sid[sp - 1] = id; sdp[sp - 1] = dp;
                    int n2 = sn[sp - 1] / 2; n2 -= (n2 & 7);
                    coff = so[sp - 1] + n2; cn = sn[sp - 1] - n2;
                    break;
                } else {
                    A[t] = sid[sp - 1]; B[t] = id;  // add = stored(left)+cur(right)
                    int dA = sdp[sp - 1];
                    dp = ((dA > dp) ? dA : dp) + 1;
                    dep[t] = dp;
                    id = ENC_ADD + t; t++;
                    sp--;
                }
            }
            if (fin) break;
        } else {
            so[sp] = coff; sn[sp] = cn; st[sp] = 0; sp++;
            int n2 = cn / 2; n2 -= (n2 & 7);
            cn = n2;
        }
    }
    *pNB = c2; *pNT = t; *pMaxD = rootd;
}

static void host_bucketize(const int* dep, int NT, int maxD,
                           int* order, int* levOff) {
    int cnt[64];
    for (int d = 0; d <= maxD; ++d) cnt[d] = 0;
    for (int t = 0; t < NT; ++t) cnt[dep[t]]++;
    int run = 0;
    levOff[0] = 0;
    for (int d = 1; d <= maxD; ++d) { run += cnt[d]; levOff[d] = run; }
    int cur[64];
    for (int d = 1; d <= maxD; ++d) cur[d] = levOff[d - 1];
    for (int t = 0; t < NT; ++t) { int d = dep[t]; order[cur[d]++] = t; }
}

static void build_sched_host(int n, Sched* s) {   // n = NF-1
    static int uDep[MAX_LEAF];
    host_build_tree(n, LEAF_T, s->leafOff, s->leafN, s->uA, s->uB, uDep,
                    &s->NL, &s->uNT, &s->uMaxD);
    host_bucketize(uDep, s->uNT, s->uMaxD, s->uOrder, s->uLevOff);
    s->nCls = 0;
    int clsN[MAX_CLS];
    int dep[64];
    for (int j = 0; j < s->NL; ++j) {
        int c = -1;
        for (int k = 0; k < s->nCls; ++k)
            if (clsN[k] == s->leafN[j]) { c = k; break; }
        if (c < 0 && s->nCls < MAX_CLS) {
            c = s->nCls++;
            clsN[c] = s->leafN[j];
            int NB, NT, maxD;
            host_build_tree(s->leafN[j], 128, s->cBOff[c], s->cBN[c],
                            s->cA[c], s->cB[c], dep, &NB, &NT, &maxD);
            s->cNB[c] = NB; s->cMaxD[c] = maxD;
            host_bucketize(dep, NT, maxD, s->cOrder[c], s->cLevOff[c]);
        }
        s->cls[j] = c;
    }
}

// ---------------- device ----------------

__device__ __forceinline__ float dt_eff_of(const float* dtp) {
    return fminf(fmaxf(dtp[0], 0.02f), 2.0f);
}

__device__ __forceinline__ int slotOf(int e, int NB) {
    return (e < ENC_ADD) ? e : (NB + (e - ENC_ADD));
}

// level-parallel upper-tree combine of partial[0..NL) into sU; returns root
// on all lanes (after final barrier). blockDim = 256.
__device__ __forceinline__ float combine_upper(const float* __restrict__ partial,
                                               const Sched* __restrict__ sc,
                                               float* sU, int lane) {
    int NL = sc->NL, NT = sc->uNT, maxD = sc->uMaxD;
    for (int k = lane; k < NL; k += 256) sU[k] = partial[k];
    __syncthreads();
    for (int d = 1; d <= maxD; ++d) {
        int s0 = sc->uLevOff[d - 1], s1 = sc->uLevOff[d];
        for (int s = s0 + lane; s < s1; s += 256) {
            int tt = sc->uOrder[s];
            sU[NL + tt] = __fadd_rn(sU[slotOf(sc->uA[tt], NL)],
                                    sU[slotOf(sc->uB[tt], NL)]);
        }
        __syncthreads();
    }
    return (NT > 0) ? sU[NL + NT - 1] : sU[0];
}

// shared tail of the leaf-dot: 8-way base chains + exact combine + tree eval.
// sA/sB may alias (r.r dot). blockDim = 256.
__device__ __forceinline__ void dot_eval(const float* sA, const float* sB,
                                         float* sChain, float* sVal,
                                         int lane, int NB,
                                         const int* __restrict__ bOff,
                                         const int* __restrict__ bN,
                                         const int* __restrict__ A,
                                         const int* __restrict__ Bb,
                                         const int* __restrict__ order,
                                         const int* __restrict__ levOff,
                                         int maxD,
                                         float* __restrict__ partial, int j) {
    // phase A: chain r_j of base block bb on lane bb*8+j (independent chains)
    int bb = lane >> 3, jj = lane & 7;
    if (bb < NB) {
        int off = bOff[bb], n = bN[bb];
        if (n >= 8) {
            int lim = n - (n & 7);
            float rr = __fmul_rn(LV(sA, off + jj), LV(sB, off + jj));
            for (int e = jj + 8; e < lim; e += 8)
                rr = __fadd_rn(rr, __fmul_rn(LV(sA, off + e), LV(sB, off + e)));
            sChain[bb * 8 + jj] = rr;
        }
    }
    __syncthreads();
    // phase B: exact combine tree + exact tail per base block
    if (lane < NB) {
        int off = bOff[lane], n = bN[lane];
        float res;
        if (n < 8) {
            res = 0.f;
            for (int e = 0; e < n; ++e)
                res = __fadd_rn(res, __fmul_rn(LV(sA, off + e), LV(sB, off + e)));
        } else {
            int lim = n - (n & 7);
            const float* c = sChain + lane * 8;
            res = __fadd_rn(__fadd_rn(__fadd_rn(c[0], c[1]), __fadd_rn(c[2], c[3])),
                            __fadd_rn(__fadd_rn(c[4], c[5]), __fadd_rn(c[6], c[7])));
            for (int e = lim; e < n; ++e)
                res = __fadd_rn(res, __fmul_rn(LV(sA, off + e), LV(sB, off + e)));
        }
        sVal[lane] = res;
    }
    __syncthreads();
    // phase C: level-parallel replay of the leaf combine tree
    for (int d = 1; d <= maxD; ++d) {
        int s0 = levOff[d - 1], s1 = levOff[d];
        for (int s = s0 + lane; s < s1; s += 256) {
            int tt = order[s];
            sVal[NB + tt] = __fadd_rn(sVal[slotOf(A[tt], NB)],
                                      sVal[slotOf(Bb[tt], NB)]);
        }
        __syncthreads();
    }
    if (lane == 0) partial[j] = (NB > 1) ? sVal[NB + NB - 2] : sVal[0];
}

// per-leaf dot partial (a.b). grid = NL blocks, 256 threads.
__global__ void k_dot_leaf(const float* __restrict__ a, const float* __restrict__ b,
                           const Sched* __restrict__ sc, float* __restrict__ partial) {
    __shared__ float sA[LEAF_PAD], sB[LEAF_PAD];
    __shared__ float sChain[512];
    __shared__ float sVal[160];
    int j = blockIdx.x, lane = threadIdx.x;
    int P = sc->leafOff[j] + 1, nn = sc->leafN[j];
    for (int g = lane; g < nn; g += 256) {
        float av = a[P + g], bv = b[P + g];
        int m = g + (g >> 7);
        sA[m] = av; sB[m] = bv;
    }
    __syncthreads();
    int c = sc->cls[j];
    dot_eval(sA, sB, sChain, sVal, lane, sc->cNB[c], sc->cBOff[c], sc->cBN[c],
             sc->cA[c], sc->cB[c], sc->cOrder[c], sc->cLevOff[c], sc->cMaxD[c],
             partial, j);
}

// setup-only: RS[0] = p.p from partial + first-element term. 1 block.
__global__ void k_dot_rs0(const float* __restrict__ a,
                          const float* __restrict__ partial,
                          const Sched* __restrict__ sc, float* __restrict__ scal) {
    __shared__ float sU[2048];
    int lane = threadIdx.x;
    float res = combine_upper(partial, sc, sU, lane);
    if (lane == 0)
        scal[8 + 0] = __fadd_rn(__fmul_rn(a[0], a[0]), res);
}

// fused: combine partial1 -> alpha (every block, redundantly);
// x += a*p ; r -= a*z (guarded by DONE[it]) over this leaf; dot fresh r.
__global__ void k_xr_dot(float* __restrict__ x, float* __restrict__ r,
                         const float* __restrict__ p, const float* __restrict__ z,
                         const float* __restrict__ scal,
                         const Sched* __restrict__ sc,
                         const float* __restrict__ partial1,
                         float* __restrict__ partial2, int it) {
    __shared__ float sA[LEAF_PAD];
    __shared__ float sU[2048];
    __shared__ float sChain[512];
    __shared__ float sVal[160];
    __shared__ float sAl;
    __shared__ int   sAct;
    int j = blockIdx.x, lane = threadIdx.x;
    float res = combine_upper(partial1, sc, sU, lane);
    if (lane == 0) {
        float pt = __fadd_rn(__fmul_rn(p[0], z[0]), res);
        sAl = __fdiv_rn(scal[8 + it], __fadd_rn(pt, (float)1e-12));
        sAct = (scal[64 + it] == 0.f) ? 1 : 0;
    }
    __syncthreads();
    int active = sAct;
    float al = sAl;
    int P = sc->leafOff[j] + 1, nn = sc->leafN[j];
    if (j == 0 && lane == 0 && active) {
        x[0] = __fadd_rn(x[0], __fmul_rn(al, p[0]));
        r[0] = __fsub_rn(r[0], __fmul_rn(al, z[0]));
    }
    for (int g = lane; g < nn; g += 256) {
        int q = P + g;
        float rv = r[q];
        if (active) {
            float xv = x[q], pv = p[q], zv = z[q];
            x[q] = __fadd_rn(xv, __fmul_rn(al, pv));
            rv = __fsub_rn(rv, __fmul_rn(al, zv));
            r[q] = rv;
        }
        sA[g + (g >> 7)] = rv;
    }
    __syncthreads();
    int c = sc->cls[j];
    dot_eval(sA, sA, sChain, sVal, lane, sc->cNB[c], sc->cBOff[c], sc->cBN[c],
             sc->cA[c], sc->cB[c], sc->cOrder[c], sc->cLevOff[c], sc->cMaxD[c],
             partial2, j);
}

// fused: combine partial2 -> rs1/beta (every block); p = r + beta*p (guarded);
// block 0 writes RS[it+1], DONE[it+1].
__global__ void k_p_fin(float4* __restrict__ p4, const float4* __restrict__ r4,
                        const float* __restrict__ rfull,
                        float* __restrict__ scal,
                        const Sched* __restrict__ sc,
                        const float* __restrict__ partial2, int it, int n4) {
    __shared__ float sU[2048];
    __shared__ float sBe;
    __shared__ int   sAct;
    int lane = threadIdx.x;
    float res = combine_upper(partial2, sc, sU, lane);
    if (lane == 0) {
        float rs1 = __fadd_rn(__fmul_rn(rfull[0], rfull[0]), res);
        float RS = scal[8 + it];
        float dn = scal[64 + it];
        sBe = __fdiv_rn(rs1, __fadd_rn(RS, (float)1e-12));
        sAct = (dn == 0.f) ? 1 : 0;
        if (blockIdx.x == 0) {
            scal[8 + it + 1]  = (dn == 0.f) ? rs1 : RS;
            scal[64 + it + 1] = (dn != 0.f || __fsqrt_rn(rs1) <= (float)1e-4)
                                ? 1.f : 0.f;
        }
    }
    __syncthreads();
    if (!sAct) return;
    float be = sBe;
    int i = blockIdx.x * blockDim.x + lane;
    if (i >= n4) return;
    float4 pv = p4[i], rv = r4[i];
    pv.x = __fadd_rn(rv.x, __fmul_rn(be, pv.x));
    pv.y = __fadd_rn(rv.y, __fmul_rn(be, pv.y));
    pv.z = __fadd_rn(rv.z, __fmul_rn(be, pv.z));
    pv.w = __fadd_rn(rv.w, __fmul_rn(be, pv.w));
    p4[i] = pv;
}

// ---------- CSR build (stable in edge order) ----------

__global__ void k_edge_pre(const int* __restrict__ dst, const int* __restrict__ src,
                           int* __restrict__ dstCnt, int* __restrict__ srcCnt, int E) {
    int e = blockIdx.x * blockDim.x + threadIdx.x;
    if (e >= E) return;
    atomicAdd(&dstCnt[dst[e]], 1);
    atomicAdd(&srcCnt[src[e]], 1);
}

__global__ void k_scan1(const int* __restrict__ cnt, int* __restrict__ incl,
                        int* __restrict__ bsums, int N) {
    __shared__ int sm[512];
    int i = blockIdx.x * 512 + threadIdx.x;
    sm[threadIdx.x] = (i < N) ? cnt[i] : 0;
    __syncthreads();
    for (int off = 1; off < 512; off <<= 1) {
        int t = (threadIdx.x >= off) ? sm[threadIdx.x - off] : 0;
        __syncthreads();
        sm[threadIdx.x] += t;
        __syncthreads();
    }
    if (i < N) incl[i] = sm[threadIdx.x];
    if (threadIdx.x == 511) bsums[blockIdx.x] = sm[511];
}

__global__ void k_scan2(int* __restrict__ bsums, int nb) {
    __shared__ int sm[512];
    sm[threadIdx.x] = (threadIdx.x < nb) ? bsums[threadIdx.x] : 0;
    __syncthreads();
    for (int off = 1; off < 512; off <<= 1) {
        int t = (threadIdx.x >= off) ? sm[threadIdx.x - off] : 0;
        __syncthreads();
        sm[threadIdx.x] += t;
        __syncthreads();
    }
    if (threadIdx.x < nb) bsums[threadIdx.x] = sm[threadIdx.x];
}

__global__ void k_scan3(int* __restrict__ off, const int* __restrict__ bsums,
                        const int* __restrict__ cnt, int N, int E) {
    int i = blockIdx.x * 512 + threadIdx.x;
    if (i < N) {
        int add = (blockIdx.x > 0) ? bsums[blockIdx.x - 1] : 0;
        off[i] = off[i] + add - cnt[i];  // exclusive
    }
    if (i == 0) off[N] = E;
}

// fill: scatter 16B records built from COALESCED edge-order reads.
// dst record: {e, src[e], 1/dx, dz/dx} ; src record: {e, dst[e], 1/dx, 0}.
__global__ void k_fill(const int* __restrict__ dst, const int* __restrict__ src,
                       const float* __restrict__ ea,
                       const int* __restrict__ dstOff, const int* __restrict__ srcOff,
                       int* __restrict__ cursD, int* __restrict__ cursS,
                       Rec* __restrict__ recD, Rec* __restrict__ recS, int E) {
    int e = blockIdx.x * blockDim.x + threadIdx.x;
    if (e >= E) return;
    int d = dst[e];
    int s0 = src[e];
    float2 exy = ((const float2*)ea)[e];
    float dx = fmaxf(exy.x, 1e-6f);
    float iv = __fdiv_rn(1.f, dx);
    float sl = __fdiv_rn(exy.y, dx);
    Rec rd; rd.e = e; rd.n = s0; rd.v = iv; rd.s = sl;
    Rec rs; rs.e = e; rs.n = d;  rs.v = iv; rs.s = 0.f;
    recD[dstOff[d] + atomicAdd(&cursD[d], 1)] = rd;
    recS[srcOff[s0] + atomicAdd(&cursS[s0], 1)] = rs;
}

__device__ __forceinline__ void insortR(Rec* L, int lo, int hi) {
    for (int a = lo + 1; a < hi; ++a) {
        Rec key = L[a]; int b = a - 1;
        while (b >= lo && L[b].e > key.e) { L[b + 1] = L[b]; b--; }
        L[b + 1] = key;
    }
}

__global__ void k_sort(const int* __restrict__ dstOff, const int* __restrict__ srcOff,
                       Rec* __restrict__ recD, Rec* __restrict__ recS, int N) {
    int i = blockIdx.x * blockDim.x + threadIdx.x;
    if (i >= N) return;
    insortR(recD, dstOff[i], dstOff[i + 1]);
    insortR(recS, srcOff[i], srcOff[i + 1]);
}

// sequential split of sorted records into loop-kernel operand streams.
__global__ void k_compact(const Rec* __restrict__ recD, const Rec* __restrict__ recS,
                          Ed* __restrict__ edD, float* __restrict__ slopeD,
                          Ed* __restrict__ edS, int E) {
    int k = blockIdx.x * blockDim.x + threadIdx.x;
    if (k >= E) return;
    Rec rd = recD[k];
    Rec rs = recS[k];
    Ed d0; d0.n = rd.n; d0.v = rd.v;
    Ed s0; s0.n = rs.n; s0.v = rs.v;
    edD[k] = d0;
    edS[k] = s0;
    slopeD[k] = rd.s;
}

// ---------- physics kernels (exact np op order, f32 sequential) ----------

__global__ void k_slope_b(const float* __restrict__ u, const float* __restrict__ slopeD,
                          const int* __restrict__ dstOff,
                          float* __restrict__ r, float* __restrict__ y,
                          const float* __restrict__ dtp, const float* __restrict__ gp,
                          int N) {
    int i = blockIdx.x * blockDim.x + threadIdx.x;
    if (i >= N) return;
    float dtg = __fmul_rn(dt_eff_of(dtp), gp[0]);
    float sn = 0.f;
    int k0 = dstOff[i], k1 = dstOff[i + 1];
    for (int k = k0; k < k1; ++k) sn = __fadd_rn(sn, slopeD[k]);
    float ms = __fmul_rn(dtg, sn);
    const float4* u4 = (const float4*)u;
    float4* r4 = (float4*)r;
    float4* y4 = (float4*)y;
    #pragma unroll
    for (int hh = 0; hh < 2; ++hh) {
        float4 uv = u4[i * 2 + hh];
        float4 bv;
        bv.x = __fsub_rn(uv.x, ms);
        bv.y = __fsub_rn(uv.y, ms);
        bv.z = __fsub_rn(uv.z, ms);
        bv.w = __fsub_rn(uv.w, ms);
        r4[i * 2 + hh] = bv;
        float4 yv;
        yv.x = __fmul_rn(uv.x, bv.x);
        yv.y = __fmul_rn(uv.y, bv.y);
        yv.z = __fmul_rn(uv.z, bv.z);
        yv.w = __fmul_rn(uv.w, bv.w);
        y4[i * 2 + hh] = yv;
    }
}

// Full D1_T (setup only): both loops; out = base + dt*acc; doInit r/x.
// thread = (node, feature-pair).
__global__ void k_d1tz_full(const Ed* __restrict__ edD, const int* __restrict__ dstOff,
                            const Ed* __restrict__ edS, const int* __restrict__ srcOff,
                            const float* __restrict__ y,
                            const float* __restrict__ base, float* __restrict__ out,
                            const float* __restrict__ dtp,
                            float* __restrict__ rInit, float* __restrict__ xInit,
                            int NP) {
    int idx = blockIdx.x * blockDim.x + threadIdx.x;
    if (idx >= NP) return;
    int i = idx >> 2, c = idx & 3;
    const float2* y2 = (const float2*)y;
    float2 uy = y2[idx];
    float2 acc = make_float2(0.f, 0.f);
    int k0 = dstOff[i], k1 = dstOff[i + 1];
    #pragma unroll 4
    for (int k = k0; k < k1; ++k) {
        float iv = edD[k].v;
        acc.x = __fadd_rn(acc.x, __fmul_rn(uy.x, iv));
        acc.y = __fadd_rn(acc.y, __fmul_rn(uy.y, iv));
    }
    k0 = srcOff[i]; k1 = srcOff[i + 1];
    #pragma unroll 4
    for (int k = k0; k < k1; ++k) {
        Ed e = edS[k];
        float2 yd = y2[e.n * 4 + c];
        float t0 = __fmul_rn(yd.x, e.v); acc.x = __fadd_rn(acc.x, -t0);
        float t1 = __fmul_rn(yd.y, e.v); acc.y = __fadd_rn(acc.y, -t1);
    }
    float dt = dt_eff_of(dtp);
    float2 bs = ((const float2*)base)[idx];
    float2 ov;
    ov.x = __fadd_rn(bs.x, __fmul_rn(dt, acc.x));
    ov.y = __fadd_rn(bs.y, __fmul_rn(dt, acc.y));
    ((float2*)out)[idx] = ov;
    ((float2*)rInit)[idx] = ov;
    ((float2*)xInit)[idx] = make_float2(0.f, 0.f);
}

// Loop kernel 1: D1(p) -> w = p + dt*(u*acc), y = u*w, AND the dst-side of
// next D1_T: dacc = sum_k y[i]*invD[k] (y row in registers; same add chain).
__global__ void k_d1w_f(const Ed* __restrict__ edD, const int* __restrict__ dstOff,
                        const float* __restrict__ pv, const float* __restrict__ u,
                        float* __restrict__ w, float* __restrict__ y,
                        float* __restrict__ dacc,
                        const float* __restrict__ dtp, int NP) {
    int idx = blockIdx.x * blockDim.x + threadIdx.x;
    if (idx >= NP) return;
    int i = idx >> 2, c = idx & 3;
    const float2* pv2 = (const float2*)pv;
    float2 pi = pv2[idx];
    float2 acc = make_float2(0.f, 0.f);
    int k0 = dstOff[i], k1 = dstOff[i + 1];
    #pragma unroll 4
    for (int k = k0; k < k1; ++k) {
        Ed e = edD[k];
        float2 ps = pv2[e.n * 4 + c];
        acc.x = __fadd_rn(acc.x, __fmul_rn(__fsub_rn(pi.x, ps.x), e.v));
        acc.y = __fadd_rn(acc.y, __fmul_rn(__fsub_rn(pi.y, ps.y), e.v));
    }
    float dt = dt_eff_of(dtp);
    float2 uv = ((const float2*)u)[idx];
    float2 wv;
    wv.x = __fadd_rn(pi.x, __fmul_rn(dt, __fmul_rn(uv.x, acc.x)));
    wv.y = __fadd_rn(pi.y, __fmul_rn(dt, __fmul_rn(uv.y, acc.y)));
    ((float2*)w)[idx] = wv;
    float2 yv;
    yv.x = __fmul_rn(uv.x, wv.x);
    yv.y = __fmul_rn(uv.y, wv.y);
    ((float2*)y)[idx] = yv;
    // dst-side accumulation of D1_T with yv in registers (L2-hot re-stream)
    float2 da = make_float2(0.f, 0.f);
    #pragma unroll 4
    for (int k = k0; k < k1; ++k) {
        float iv = edD[k].v;
        da.x = __fadd_rn(da.x, __fmul_rn(yv.x, iv));
        da.y = __fadd_rn(da.y, __fmul_rn(yv.y, iv));
    }
    ((float2*)dacc)[idx] = da;
}

// Loop kernel 2: src-side of D1_T continuing from dacc; t = w + dt*acc.
__global__ void k_d1tzs(const Ed* __restrict__ edS, const int* __restrict__ srcOff,
                        const float* __restrict__ y, const float* __restrict__ dacc,
                        const float* __restrict__ base, float* __restrict__ out,
                        const float* __restrict__ dtp, int NP) {
    int idx = blockIdx.x * blockDim.x + threadIdx.x;
    if (idx >= NP) return;
    int i = idx >> 2, c = idx & 3;
    const float2* y2 = (const float2*)y;
    float2 acc = ((const float2*)dacc)[idx];
    int k0 = srcOff[i], k1 = srcOff[i + 1];
    #pragma unroll 4
    for (int k = k0; k < k1; ++k) {
        Ed e = edS[k];
        float2 yd = y2[e.n * 4 + c];
        float t0 = __fmul_rn(yd.x, e.v); acc.x = __fadd_rn(acc.x, -t0);
        float t1 = __fmul_rn(yd.y, e.v); acc.y = __fadd_rn(acc.y, -t1);
    }
    float dt = dt_eff_of(dtp);
    float2 bs = ((const float2*)base)[idx];
    float2 ov;
    ov.x = __fadd_rn(bs.x, __fmul_rn(dt, acc.x));
    ov.y = __fadd_rn(bs.y, __fmul_rn(dt, acc.y));
    ((float2*)out)[idx] = ov;
}

extern "C" void kernel_launch(void* const* d_in, const int* in_sizes, int n_in,
                              void* d_out, int out_size, void* d_ws, size_t ws_size,
                              hipStream_t stream) {
    const float* u   = (const float*)d_in[0];
    const int*   ei  = (const int*)d_in[1];
    const float* ea  = (const float*)d_in[2];
    const float* dtp = (const float*)d_in[3];
    const float* gp  = (const float*)d_in[4];

    const int NF = in_sizes[0];        // 1,600,000
    const int N  = NF / F;             // 200,000
    const int E  = in_sizes[2] / 2;    // 3,200,000
    const int* srcp = ei;
    const int* dstp = ei + E;

    // host-side pairwise-tree schedule (deterministic fn of NF; static so the
    // graph-replayed hipMemcpyAsync source stays valid)
    static Sched h_sched;
    build_sched_host(NF - 1, &h_sched);
    const int NL = h_sched.NL;

    char* wp = (char*)d_ws;
    float* scal    = (float*)wp; wp += 128 * 4;   // RS[it]@8+it, DONE[it]@64+it
    float* r       = (float*)wp; wp += (size_t)NF * 4;
    float* p       = (float*)wp; wp += (size_t)NF * 4;
    float* t       = (float*)wp; wp += (size_t)NF * 4;   // z
    float* w       = (float*)wp; wp += (size_t)NF * 4;
    float* y       = (float*)wp; wp += (size_t)NF * 4;   // u*w / u*b
    float* dacc    = (float*)wp; wp += (size_t)NF * 4;   // dst-side D1_T partial
    Rec*   recD    = (Rec*)wp;   wp += (size_t)E * 16;   // fill records, dst-CSR
    Rec*   recS    = (Rec*)wp;   wp += (size_t)E * 16;   // fill records, src-CSR
    Ed*    edD     = (Ed*)wp;    wp += (size_t)E * 8;    // {src,inv} dst-CSR
    Ed*    edS     = (Ed*)wp;    wp += (size_t)E * 8;    // {dst,inv} src-CSR
    float* slopeD  = (float*)wp; wp += (size_t)E * 4;
    int*   dstOff  = (int*)wp;   wp += (size_t)(N + 1) * 4;
    int*   srcOff  = (int*)wp;   wp += (size_t)(N + 1) * 4;
    int*   dstCnt  = (int*)wp;   wp += (size_t)N * 4;
    int*   srcCnt  = (int*)wp;   wp += (size_t)N * 4;
    int*   cursD   = (int*)wp;   wp += (size_t)N * 4;
    int*   cursS   = (int*)wp;   wp += (size_t)N * 4;
    int*   bsD     = (int*)wp;   wp += 512 * 4;
    int*   bsS     = (int*)wp;   wp += 512 * 4;
    float* partial1 = (float*)wp; wp += 2048 * 4;
    float* partial2 = (float*)wp; wp += 2048 * 4;
    wp = (char*)(((uintptr_t)wp + 255) & ~(uintptr_t)255);
    Sched* d_sched = (Sched*)wp; wp += (sizeof(Sched) + 255) & ~(size_t)255;
    float* x = (float*)d_out;

    hipMemcpyAsync(d_sched, &h_sched, sizeof(Sched), hipMemcpyHostToDevice,
                   stream);
    hipMemsetAsync(scal, 0, 128 * 4, stream);
    hipMemsetAsync(dstCnt, 0, (size_t)N * 4, stream);
    hipMemsetAsync(srcCnt, 0, (size_t)N * 4, stream);
    hipMemsetAsync(cursD, 0, (size_t)N * 4, stream);
    hipMemsetAsync(cursS, 0, (size_t)N * 4, stream);

    const int bn = 256;
    const int gN  = (N + bn - 1) / bn;
    const int gE  = (E + bn - 1) / bn;
    const int nb  = (N + 511) / 512;
    const int n4  = NF / 4;
    const int g4  = (n4 + bn - 1) / bn;
    const int NP  = NF / 2;            // (node, feature-pair) threads
    const int gP  = (NP + bn - 1) / bn;

    // ---- CSR build (stable by edge id) ----
    k_edge_pre<<<gE, bn, 0, stream>>>(dstp, srcp, dstCnt, srcCnt, E);
    k_scan1<<<nb, 512, 0, stream>>>(dstCnt, dstOff, bsD, N);
    k_scan2<<<1, 512, 0, stream>>>(bsD, nb);
    k_scan3<<<nb, 512, 0, stream>>>(dstOff, bsD, dstCnt, N, E);
    k_scan1<<<nb, 512, 0, stream>>>(srcCnt, srcOff, bsS, N);
    k_scan2<<<1, 512, 0, stream>>>(bsS, nb);
    k_scan3<<<nb, 512, 0, stream>>>(srcOff, bsS, srcCnt, N, E);
    k_fill<<<gE, bn, 0, stream>>>(dstp, srcp, ea, dstOff, srcOff, cursD, cursS,
                                  recD, recS, E);
    k_sort<<<gN, bn, 0, stream>>>(dstOff, srcOff, recD, recS, N);
    k_compact<<<gE, bn, 0, stream>>>(recD, recS, edD, slopeD, edS, E);

    // ---- setup: b->r, y=u*b ; p = b + dt*D1T(y) ; r=p, x=0 ; RS[0] = p.p ----
    k_slope_b<<<gN, bn, 0, stream>>>(u, slopeD, dstOff, r, y, dtp, gp, N);
    k_d1tz_full<<<gP, bn, 0, stream>>>(edD, dstOff, edS, srcOff,
                                       y, r, p, dtp, r, x, NP);
    k_dot_leaf<<<NL, 256, 0, stream>>>(p, p, d_sched, partial1);
    k_dot_rs0<<<1, 256, 0, stream>>>(p, partial1, d_sched, scal);

    // ---- CG loop (5 dispatches/iter) ----
    for (int it = 0; it < CG_ITERS; ++it) {
        k_d1w_f<<<gP, bn, 0, stream>>>(edD, dstOff, p, u, w, y, dacc, dtp, NP);
        k_d1tzs<<<gP, bn, 0, stream>>>(edS, srcOff, y, dacc, w, t, dtp, NP);
        k_dot_leaf<<<NL, 256, 0, stream>>>(p, t, d_sched, partial1);
        k_xr_dot<<<NL, 256, 0, stream>>>(x, r, p, t, scal, d_sched,
                                         partial1, partial2, it);
        k_p_fin<<<g4, bn, 0, stream>>>((float4*)p, (const float4*)r, r, scal,
                                       d_sched, partial2, it, n4);
    }
}

// Round 9
// 4568.041 us; speedup vs baseline: 1.9652x; 1.0206x over previous
//
#include <hip/hip_runtime.h>
#include <math.h>
#include <stdint.h>
#include <string.h>

// PhysicsLSGStep: bitwise-faithful f32 replication of the numpy reference.
// R20 (on top of R19):
//  - k_sort (global-memory insertion sort of 16B records, O(d^2) scattered
//    moves ~400MB) and k_compact (350MB pass) FUSED into k_sortc: per-node
//    keys (e<<6|m) sorted in per-thread LDS scratch, records emitted directly
//    into edD/slopeD/edS in sorted order. Keys are distinct => identical
//    permutation; integer-only => bit-exact. Degree>64 -> selection fallback.
//  - scan kernels merged (dst+src in one dispatch each); one memset covers
//    the four adjacent cnt/cursor buffers. -5 dispatches.
// Scatter sums stay in sorted-edge-id (CSR) order; dots replay the exact
// numpy pairwise tree (level-parallel, pairings unchanged). f32 __f*_rn only.

#define F 8
#define CG_ITERS 30
#define LEAF_T 4096
#define LEAF_PAD (LEAF_T + LEAF_T / 128 + 8)
#define ENC_ADD 1024
#define MAX_LEAF 1024
#define MAX_CLS 32
#define MAXDEG 64

// scal slots: RS[it] = scal[8+it], DONE[it] = scal[64+it]

#define LV(A_, i_) A_[(i_) + ((i_) >> 7)]

struct __align__(8) Ed { int n; float v; };
struct __align__(16) Rec { int e; int n; float v; float s; };

struct Sched {
    int NL, uNT, uMaxD, nCls;
    int leafOff[MAX_LEAF], leafN[MAX_LEAF], cls[MAX_LEAF];
    int cNB[MAX_CLS], cMaxD[MAX_CLS];
    int cBOff[MAX_CLS][64], cBN[MAX_CLS][64];
    int cA[MAX_CLS][64], cB[MAX_CLS][64], cOrder[MAX_CLS][64];
    int cLevOff[MAX_CLS][32];
    int uA[MAX_LEAF], uB[MAX_LEAF], uOrder[MAX_LEAF], uLevOff[64];
};

// ---------------- host-side schedule build (exact integer replica) --------

static void host_build_tree(int n, int T, int* bOff, int* bN,
                            int* A, int* B, int* dep,
                            int* pNB, int* pNT, int* pMaxD) {
    int so[64], sn[64], st[64], sid[64], sdp[64];
    int sp = 0, coff = 0, cn = n, c2 = 0, t = 0, rootd = 0;
    for (;;) {
        if (cn <= T) {
            if (bOff) { bOff[c2] = coff; bN[c2] = cn; }
            int id = c2, dp = 0; c2++;
            bool fin = false;
            for (;;) {
                if (sp == 0) { rootd = dp; fin = true; break; }
                if (st[sp - 1] == 0) {
                    st[sp - 1] = 1; sid[sp - 1] = id; sdp[sp - 1] = dp;
                    int n2 = sn[sp - 1] / 2; n2 -= (n2 & 7);
                    coff = so[sp - 1] + n2; cn = sn[sp - 1] - n2;
                    break;
                } else {
                    A[t] = sid[sp - 1]; B[t] = id;
                    int dA = sdp[sp - 1];
                    dp = ((dA > dp) ? dA : dp) + 1;
                    dep[t] = dp;
                    id = ENC_ADD + t; t++;
                    sp--;
                }
            }
            if (fin) break;
        } else {
            so[sp] = coff; sn[sp] = cn; st[sp] = 0; sp++;
            int n2 = cn / 2; n2 -= (n2 & 7);
            cn = n2;
        }
    }
    *pNB = c2; *pNT = t; *pMaxD = rootd;
}

static void host_bucketize(const int* dep, int NT, int maxD,
                           int* order, int* levOff) {
    int cnt[64];
    for (int d = 0; d <= maxD; ++d) cnt[d] = 0;
    for (int t = 0; t < NT; ++t) cnt[dep[t]]++;
    int run = 0;
    levOff[0] = 0;
    for (int d = 1; d <= maxD; ++d) { run += cnt[d]; levOff[d] = run; }
    int cur[64];
    for (int d = 1; d <= maxD; ++d) cur[d] = levOff[d - 1];
    for (int t = 0; t < NT; ++t) { int d = dep[t]; order[cur[d]++] = t; }
}

static void build_sched_host(int n, Sched* s) {
    static int uDep[MAX_LEAF];
    host_build_tree(n, LEAF_T, s->leafOff, s->leafN, s->uA, s->uB, uDep,
                    &s->NL, &s->uNT, &s->uMaxD);
    host_bucketize(uDep, s->uNT, s->uMaxD, s->uOrder, s->uLevOff);
    s->nCls = 0;
    int clsN[MAX_CLS];
    int dep[64];
    for (int j = 0; j < s->NL; ++j) {
        int c = -1;
        for (int k = 0; k < s->nCls; ++k)
            if (clsN[k] == s->leafN[j]) { c = k; break; }
        if (c < 0 && s->nCls < MAX_CLS) {
            c = s->nCls++;
            clsN[c] = s->leafN[j];
            int NB, NT, maxD;
            host_build_tree(s->leafN[j], 128, s->cBOff[c], s->cBN[c],
                            s->cA[c], s->cB[c], dep, &NB, &NT, &maxD);
            s->cNB[c] = NB; s->cMaxD[c] = maxD;
            host_bucketize(dep, NT, maxD, s->cOrder[c], s->cLevOff[c]);
        }
        s->cls[j] = c;
    }
}

// ---------------- device ----------------

__device__ __forceinline__ float dt_eff_of(const float* dtp) {
    return fminf(fmaxf(dtp[0], 0.02f), 2.0f);
}

__device__ __forceinline__ int slotOf(int e, int NB) {
    return (e < ENC_ADD) ? e : (NB + (e - ENC_ADD));
}

__device__ __forceinline__ float combine_upper(const float* __restrict__ partial,
                                               const Sched* __restrict__ sc,
                                               float* sU, int lane) {
    int NL = sc->NL, NT = sc->uNT, maxD = sc->uMaxD;
    for (int k = lane; k < NL; k += 256) sU[k] = partial[k];
    __syncthreads();
    for (int d = 1; d <= maxD; ++d) {
        int s0 = sc->uLevOff[d - 1], s1 = sc->uLevOff[d];
        for (int s = s0 + lane; s < s1; s += 256) {
            int tt = sc->uOrder[s];
            sU[NL + tt] = __fadd_rn(sU[slotOf(sc->uA[tt], NL)],
                                    sU[slotOf(sc->uB[tt], NL)]);
        }
        __syncthreads();
    }
    return (NT > 0) ? sU[NL + NT - 1] : sU[0];
}

__device__ __forceinline__ void dot_eval(const float* sA, const float* sB,
                                         float* sChain, float* sVal,
                                         int lane, int NB,
                                         const int* __restrict__ bOff,
                                         const int* __restrict__ bN,
                                         const int* __restrict__ A,
                                         const int* __restrict__ Bb,
                                         const int* __restrict__ order,
                                         const int* __restrict__ levOff,
                                         int maxD,
                                         float* __restrict__ partial, int j) {
    int bb = lane >> 3, jj = lane & 7;
    if (bb < NB) {
        int off = bOff[bb], n = bN[bb];
        if (n >= 8) {
            int lim = n - (n & 7);
            float rr = __fmul_rn(LV(sA, off + jj), LV(sB, off + jj));
            for (int e = jj + 8; e < lim; e += 8)
                rr = __fadd_rn(rr, __fmul_rn(LV(sA, off + e), LV(sB, off + e)));
            sChain[bb * 8 + jj] = rr;
        }
    }
    __syncthreads();
    if (lane < NB) {
        int off = bOff[lane], n = bN[lane];
        float res;
        if (n < 8) {
            res = 0.f;
            for (int e = 0; e < n; ++e)
                res = __fadd_rn(res, __fmul_rn(LV(sA, off + e), LV(sB, off + e)));
        } else {
            int lim = n - (n & 7);
            const float* c = sChain + lane * 8;
            res = __fadd_rn(__fadd_rn(__fadd_rn(c[0], c[1]), __fadd_rn(c[2], c[3])),
                            __fadd_rn(__fadd_rn(c[4], c[5]), __fadd_rn(c[6], c[7])));
            for (int e = lim; e < n; ++e)
                res = __fadd_rn(res, __fmul_rn(LV(sA, off + e), LV(sB, off + e)));
        }
        sVal[lane] = res;
    }
    __syncthreads();
    for (int d = 1; d <= maxD; ++d) {
        int s0 = levOff[d - 1], s1 = levOff[d];
        for (int s = s0 + lane; s < s1; s += 256) {
            int tt = order[s];
            sVal[NB + tt] = __fadd_rn(sVal[slotOf(A[tt], NB)],
                                      sVal[slotOf(Bb[tt], NB)]);
        }
        __syncthreads();
    }
    if (lane == 0) partial[j] = (NB > 1) ? sVal[NB + NB - 2] : sVal[0];
}

__global__ void k_dot_leaf(const float* __restrict__ a, const float* __restrict__ b,
                           const Sched* __restrict__ sc, float* __restrict__ partial) {
    __shared__ float sA[LEAF_PAD], sB[LEAF_PAD];
    __shared__ float sChain[512];
    __shared__ float sVal[160];
    int j = blockIdx.x, lane = threadIdx.x;
    int P = sc->leafOff[j] + 1, nn = sc->leafN[j];
    for (int g = lane; g < nn; g += 256) {
        float av = a[P + g], bv = b[P + g];
        int m = g + (g >> 7);
        sA[m] = av; sB[m] = bv;
    }
    __syncthreads();
    int c = sc->cls[j];
    dot_eval(sA, sB, sChain, sVal, lane, sc->cNB[c], sc->cBOff[c], sc->cBN[c],
             sc->cA[c], sc->cB[c], sc->cOrder[c], sc->cLevOff[c], sc->cMaxD[c],
             partial, j);
}

__global__ void k_dot_rs0(const float* __restrict__ a,
                          const float* __restrict__ partial,
                          const Sched* __restrict__ sc, float* __restrict__ scal) {
    __shared__ float sU[2048];
    int lane = threadIdx.x;
    float res = combine_upper(partial, sc, sU, lane);
    if (lane == 0)
        scal[8 + 0] = __fadd_rn(__fmul_rn(a[0], a[0]), res);
}

__global__ void k_xr_dot(float* __restrict__ x, float* __restrict__ r,
                         const float* __restrict__ p, const float* __restrict__ z,
                         const float* __restrict__ scal,
                         const Sched* __restrict__ sc,
                         const float* __restrict__ partial1,
                         float* __restrict__ partial2, int it) {
    __shared__ float sA[LEAF_PAD];
    __shared__ float sU[2048];
    __shared__ float sChain[512];
    __shared__ float sVal[160];
    __shared__ float sAl;
    __shared__ int   sAct;
    int j = blockIdx.x, lane = threadIdx.x;
    float res = combine_upper(partial1, sc, sU, lane);
    if (lane == 0) {
        float pt = __fadd_rn(__fmul_rn(p[0], z[0]), res);
        sAl = __fdiv_rn(scal[8 + it], __fadd_rn(pt, (float)1e-12));
        sAct = (scal[64 + it] == 0.f) ? 1 : 0;
    }
    __syncthreads();
    int active = sAct;
    float al = sAl;
    int P = sc->leafOff[j] + 1, nn = sc->leafN[j];
    if (j == 0 && lane == 0 && active) {
        x[0] = __fadd_rn(x[0], __fmul_rn(al, p[0]));
        r[0] = __fsub_rn(r[0], __fmul_rn(al, z[0]));
    }
    for (int g = lane; g < nn; g += 256) {
        int q = P + g;
        float rv = r[q];
        if (active) {
            float xv = x[q], pv = p[q], zv = z[q];
            x[q] = __fadd_rn(xv, __fmul_rn(al, pv));
            rv = __fsub_rn(rv, __fmul_rn(al, zv));
            r[q] = rv;
        }
        sA[g + (g >> 7)] = rv;
    }
    __syncthreads();
    int c = sc->cls[j];
    dot_eval(sA, sA, sChain, sVal, lane, sc->cNB[c], sc->cBOff[c], sc->cBN[c],
             sc->cA[c], sc->cB[c], sc->cOrder[c], sc->cLevOff[c], sc->cMaxD[c],
             partial2, j);
}

__global__ void k_p_fin(float4* __restrict__ p4, const float4* __restrict__ r4,
                        const float* __restrict__ rfull,
                        float* __restrict__ scal,
                        const Sched* __restrict__ sc,
                        const float* __restrict__ partial2, int it, int n4) {
    __shared__ float sU[2048];
    __shared__ float sBe;
    __shared__ int   sAct;
    int lane = threadIdx.x;
    float res = combine_upper(partial2, sc, sU, lane);
    if (lane == 0) {
        float rs1 = __fadd_rn(__fmul_rn(rfull[0], rfull[0]), res);
        float RS = scal[8 + it];
        float dn = scal[64 + it];
        sBe = __fdiv_rn(rs1, __fadd_rn(RS, (float)1e-12));
        sAct = (dn == 0.f) ? 1 : 0;
        if (blockIdx.x == 0) {
            scal[8 + it + 1]  = (dn == 0.f) ? rs1 : RS;
            scal[64 + it + 1] = (dn != 0.f || __fsqrt_rn(rs1) <= (float)1e-4)
                                ? 1.f : 0.f;
        }
    }
    __syncthreads();
    if (!sAct) return;
    float be = sBe;
    int i = blockIdx.x * blockDim.x + lane;
    if (i >= n4) return;
    float4 pv = p4[i], rv = r4[i];
    pv.x = __fadd_rn(rv.x, __fmul_rn(be, pv.x));
    pv.y = __fadd_rn(rv.y, __fmul_rn(be, pv.y));
    pv.z = __fadd_rn(rv.z, __fmul_rn(be, pv.z));
    pv.w = __fadd_rn(rv.w, __fmul_rn(be, pv.w));
    p4[i] = pv;
}

// ---------- CSR build (stable in edge order) ----------

__global__ void k_edge_pre(const int* __restrict__ dst, const int* __restrict__ src,
                           int* __restrict__ dstCnt, int* __restrict__ srcCnt, int E) {
    int e = blockIdx.x * blockDim.x + threadIdx.x;
    if (e >= E) return;
    atomicAdd(&dstCnt[dst[e]], 1);
    atomicAdd(&srcCnt[src[e]], 1);
}

// merged scans: dst handled by blocks [0,nb), src by [nb,2nb)
__global__ void k_scan1m(const int* __restrict__ cntD, const int* __restrict__ cntS,
                         int* __restrict__ inclD, int* __restrict__ inclS,
                         int* __restrict__ bsD, int* __restrict__ bsS,
                         int N, int nb) {
    __shared__ int sm[512];
    int bb = blockIdx.x;
    int isS = (bb >= nb) ? 1 : 0;
    int blk = bb - (isS ? nb : 0);
    const int* cnt = isS ? cntS : cntD;
    int* incl = isS ? inclS : inclD;
    int* bsums = isS ? bsS : bsD;
    int i = blk * 512 + threadIdx.x;
    sm[threadIdx.x] = (i < N) ? cnt[i] : 0;
    __syncthreads();
    for (int off = 1; off < 512; off <<= 1) {
        int t = (threadIdx.x >= off) ? sm[threadIdx.x - off] : 0;
        __syncthreads();
        sm[threadIdx.x] += t;
        __syncthreads();
    }
    if (i < N) incl[i] = sm[threadIdx.x];
    if (threadIdx.x == 511) bsums[blk] = sm[511];
}

__global__ void k_scan2m(int* __restrict__ bsD, int* __restrict__ bsS, int nb) {
    __shared__ int sm[512];
    for (int pass = 0; pass < 2; ++pass) {
        int* bsums = pass ? bsS : bsD;
        sm[threadIdx.x] = (threadIdx.x < nb) ? bsums[threadIdx.x] : 0;
        __syncthreads();
        for (int off = 1; off < 512; off <<= 1) {
            int t = (threadIdx.x >= off) ? sm[threadIdx.x - off] : 0;
            __syncthreads();
            sm[threadIdx.x] += t;
            __syncthreads();
        }
        if (threadIdx.x < nb) bsums[threadIdx.x] = sm[threadIdx.x];
        __syncthreads();
    }
}

__global__ void k_scan3m(int* __restrict__ offD, int* __restrict__ offS,
                         const int* __restrict__ bsD, const int* __restrict__ bsS,
                         const int* __restrict__ cntD, const int* __restrict__ cntS,
                         int N, int E, int nb) {
    int bb = blockIdx.x;
    int isS = (bb >= nb) ? 1 : 0;
    int blk = bb - (isS ? nb : 0);
    int* off = isS ? offS : offD;
    const int* bsums = isS ? bsS : bsD;
    const int* cnt = isS ? cntS : cntD;
    int i = blk * 512 + threadIdx.x;
    if (i < N) {
        int add = (blk > 0) ? bsums[blk - 1] : 0;
        off[i] = off[i] + add - cnt[i];
    }
    if (i == 0) off[N] = E;
}

// fill: scatter 16B records built from COALESCED edge-order reads.
__global__ void k_fill(const int* __restrict__ dst, const int* __restrict__ src,
                       const float* __restrict__ ea,
                       const int* __restrict__ dstOff, const int* __restrict__ srcOff,
                       int* __restrict__ cursD, int* __restrict__ cursS,
                       Rec* __restrict__ recD, Rec* __restrict__ recS, int E) {
    int e = blockIdx.x * blockDim.x + threadIdx.x;
    if (e >= E) return;
    int d = dst[e];
    int s0 = src[e];
    float2 exy = ((const float2*)ea)[e];
    float dx = fmaxf(exy.x, 1e-6f);
    float iv = __fdiv_rn(1.f, dx);
    float sl = __fdiv_rn(exy.y, dx);
    Rec rd; rd.e = e; rd.n = s0; rd.v = iv; rd.s = sl;
    Rec rs; rs.e = e; rs.n = d;  rs.v = iv; rs.s = 0.f;
    recD[dstOff[d] + atomicAdd(&cursD[d], 1)] = rd;
    recS[srcOff[s0] + atomicAdd(&cursS[s0], 1)] = rs;
}

// fused sort+compact: per-node keys (e<<6|m) sorted in per-thread LDS scratch;
// records emitted directly in sorted order. Keys distinct => identical
// permutation to insertion sort; integer-only => bit-exact output streams.
__global__ void k_sortc(const int* __restrict__ dstOff, const int* __restrict__ srcOff,
                        const Rec* __restrict__ recD, const Rec* __restrict__ recS,
                        Ed* __restrict__ edD, float* __restrict__ slopeD,
                        Ed* __restrict__ edS, int N) {
    __shared__ unsigned keys[256 * MAXDEG];   // 64 KB
    int i = blockIdx.x * blockDim.x + threadIdx.x;
    if (i >= N) return;
    unsigned* k0 = keys + threadIdx.x * MAXDEG;
    // ---- dst side -> edD, slopeD ----
    {
        int lo = dstOff[i], hi = dstOff[i + 1], d = hi - lo;
        if (d <= MAXDEG) {
            for (int m = 0; m < d; ++m)
                k0[m] = ((unsigned)recD[lo + m].e << 6) | (unsigned)m;
            for (int a = 1; a < d; ++a) {
                unsigned kk = k0[a]; int b = a - 1;
                while (b >= 0 && k0[b] > kk) { k0[b + 1] = k0[b]; b--; }
                k0[b + 1] = kk;
            }
            for (int m = 0; m < d; ++m) {
                Rec rr = recD[lo + (int)(k0[m] & 63u)];
                Ed ed; ed.n = rr.n; ed.v = rr.v;
                edD[lo + m] = ed; slopeD[lo + m] = rr.s;
            }
        } else {   // selection fallback (distinct keys => same output)
            int prev = -1;
            for (int m = 0; m < d; ++m) {
                int best = 0x7fffffff, bj = -1;
                for (int jx = 0; jx < d; ++jx) {
                    int ev = recD[lo + jx].e;
                    if (ev > prev && ev < best) { best = ev; bj = jx; }
                }
                Rec rr = recD[lo + bj];
                Ed ed; ed.n = rr.n; ed.v = rr.v;
                edD[lo + m] = ed; slopeD[lo + m] = rr.s;
                prev = best;
            }
        }
    }
    // ---- src side -> edS ----
    {
        int lo = srcOff[i], hi = srcOff[i + 1], d = hi - lo;
        if (d <= MAXDEG) {
            for (int m = 0; m < d; ++m)
                k0[m] = ((unsigned)recS[lo + m].e << 6) | (unsigned)m;
            for (int a = 1; a < d; ++a) {
                unsigned kk = k0[a]; int b = a - 1;
                while (b >= 0 && k0[b] > kk) { k0[b + 1] = k0[b]; b--; }
                k0[b + 1] = kk;
            }
            for (int m = 0; m < d; ++m) {
                Rec rr = recS[lo + (int)(k0[m] & 63u)];
                Ed ed; ed.n = rr.n; ed.v = rr.v;
                edS[lo + m] = ed;
            }
        } else {
            int prev = -1;
            for (int m = 0; m < d; ++m) {
                int best = 0x7fffffff, bj = -1;
                for (int jx = 0; jx < d; ++jx) {
                    int ev = recS[lo + jx].e;
                    if (ev > prev && ev < best) { best = ev; bj = jx; }
                }
                Rec rr = recS[lo + bj];
                Ed ed; ed.n = rr.n; ed.v = rr.v;
                edS[lo + m] = ed;
                prev = best;
            }
        }
    }
}

// ---------- physics kernels (exact np op order, f32 sequential) ----------

__global__ void k_slope_b(const float* __restrict__ u, const float* __restrict__ slopeD,
                          const int* __restrict__ dstOff,
                          float* __restrict__ r, float* __restrict__ y,
                          const float* __restrict__ dtp, const float* __restrict__ gp,
                          int N) {
    int i = blockIdx.x * blockDim.x + threadIdx.x;
    if (i >= N) return;
    float dtg = __fmul_rn(dt_eff_of(dtp), gp[0]);
    float sn = 0.f;
    int k0 = dstOff[i], k1 = dstOff[i + 1];
    for (int k = k0; k < k1; ++k) sn = __fadd_rn(sn, slopeD[k]);
    float ms = __fmul_rn(dtg, sn);
    const float4* u4 = (const float4*)u;
    float4* r4 = (float4*)r;
    float4* y4 = (float4*)y;
    #pragma unroll
    for (int hh = 0; hh < 2; ++hh) {
        float4 uv = u4[i * 2 + hh];
        float4 bv;
        bv.x = __fsub_rn(uv.x, ms);
        bv.y = __fsub_rn(uv.y, ms);
        bv.z = __fsub_rn(uv.z, ms);
        bv.w = __fsub_rn(uv.w, ms);
        r4[i * 2 + hh] = bv;
        float4 yv;
        yv.x = __fmul_rn(uv.x, bv.x);
        yv.y = __fmul_rn(uv.y, bv.y);
        yv.z = __fmul_rn(uv.z, bv.z);
        yv.w = __fmul_rn(uv.w, bv.w);
        y4[i * 2 + hh] = yv;
    }
}

__global__ void k_d1tz_full(const Ed* __restrict__ edD, const int* __restrict__ dstOff,
                            const Ed* __restrict__ edS, const int* __restrict__ srcOff,
                            const float* __restrict__ y,
                            const float* __restrict__ base, float* __restrict__ out,
                            const float* __restrict__ dtp,
                            float* __restrict__ rInit, float* __restrict__ xInit,
                            int NP) {
    int idx = blockIdx.x * blockDim.x + threadIdx.x;
    if (idx >= NP) return;
    int i = idx >> 2, c = idx & 3;
    const float2* y2 = (const float2*)y;
    float2 uy = y2[idx];
    float2 acc = make_float2(0.f, 0.f);
    int k0 = dstOff[i], k1 = dstOff[i + 1];
    #pragma unroll 4
    for (int k = k0; k < k1; ++k) {
        float iv = edD[k].v;
        acc.x = __fadd_rn(acc.x, __fmul_rn(uy.x, iv));
        acc.y = __fadd_rn(acc.y, __fmul_rn(uy.y, iv));
    }
    k0 = srcOff[i]; k1 = srcOff[i + 1];
    #pragma unroll 4
    for (int k = k0; k < k1; ++k) {
        Ed e = edS[k];
        float2 yd = y2[e.n * 4 + c];
        float t0 = __fmul_rn(yd.x, e.v); acc.x = __fadd_rn(acc.x, -t0);
        float t1 = __fmul_rn(yd.y, e.v); acc.y = __fadd_rn(acc.y, -t1);
    }
    float dt = dt_eff_of(dtp);
    float2 bs = ((const float2*)base)[idx];
    float2 ov;
    ov.x = __fadd_rn(bs.x, __fmul_rn(dt, acc.x));
    ov.y = __fadd_rn(bs.y, __fmul_rn(dt, acc.y));
    ((float2*)out)[idx] = ov;
    ((float2*)rInit)[idx] = ov;
    ((float2*)xInit)[idx] = make_float2(0.f, 0.f);
}

__global__ void k_d1w_f(const Ed* __restrict__ edD, const int* __restrict__ dstOff,
                        const float* __restrict__ pv, const float* __restrict__ u,
                        float* __restrict__ w, float* __restrict__ y,
                        float* __restrict__ dacc,
                        const float* __restrict__ dtp, int NP) {
    int idx = blockIdx.x * blockDim.x + threadIdx.x;
    if (idx >= NP) return;
    int i = idx >> 2, c = idx & 3;
    const float2* pv2 = (const float2*)pv;
    float2 pi = pv2[idx];
    float2 acc = make_float2(0.f, 0.f);
    int k0 = dstOff[i], k1 = dstOff[i + 1];
    #pragma unroll 4
    for (int k = k0; k < k1; ++k) {
        Ed e = edD[k];
        float2 ps = pv2[e.n * 4 + c];
        acc.x = __fadd_rn(acc.x, __fmul_rn(__fsub_rn(pi.x, ps.x), e.v));
        acc.y = __fadd_rn(acc.y, __fmul_rn(__fsub_rn(pi.y, ps.y), e.v));
    }
    float dt = dt_eff_of(dtp);
    float2 uv = ((const float2*)u)[idx];
    float2 wv;
    wv.x = __fadd_rn(pi.x, __fmul_rn(dt, __fmul_rn(uv.x, acc.x)));
    wv.y = __fadd_rn(pi.y, __fmul_rn(dt, __fmul_rn(uv.y, acc.y)));
    ((float2*)w)[idx] = wv;
    float2 yv;
    yv.x = __fmul_rn(uv.x, wv.x);
    yv.y = __fmul_rn(uv.y, wv.y);
    ((float2*)y)[idx] = yv;
    float2 da = make_float2(0.f, 0.f);
    #pragma unroll 4
    for (int k = k0; k < k1; ++k) {
        float iv = edD[k].v;
        da.x = __fadd_rn(da.x, __fmul_rn(yv.x, iv));
        da.y = __fadd_rn(da.y, __fmul_rn(yv.y, iv));
    }
    ((float2*)dacc)[idx] = da;
}

__global__ void k_d1tzs(const Ed* __restrict__ edS, const int* __restrict__ srcOff,
                        const float* __restrict__ y, const float* __restrict__ dacc,
                        const float* __restrict__ base, float* __restrict__ out,
                        const float* __restrict__ dtp, int NP) {
    int idx = blockIdx.x * blockDim.x + threadIdx.x;
    if (idx >= NP) return;
    int i = idx >> 2, c = idx & 3;
    const float2* y2 = (const float2*)y;
    float2 acc = ((const float2*)dacc)[idx];
    int k0 = srcOff[i], k1 = srcOff[i + 1];
    #pragma unroll 4
    for (int k = k0; k < k1; ++k) {
        Ed e = edS[k];
        float2 yd = y2[e.n * 4 + c];
        float t0 = __fmul_rn(yd.x, e.v); acc.x = __fadd_rn(acc.x, -t0);
        float t1 = __fmul_rn(yd.y, e.v); acc.y = __fadd_rn(acc.y, -t1);
    }
    float dt = dt_eff_of(dtp);
    float2 bs = ((const float2*)base)[idx];
    float2 ov;
    ov.x = __fadd_rn(bs.x, __fmul_rn(dt, acc.x));
    ov.y = __fadd_rn(bs.y, __fmul_rn(dt, acc.y));
    ((float2*)out)[idx] = ov;
}

extern "C" void kernel_launch(void* const* d_in, const int* in_sizes, int n_in,
                              void* d_out, int out_size, void* d_ws, size_t ws_size,
                              hipStream_t stream) {
    const float* u   = (const float*)d_in[0];
    const int*   ei  = (const int*)d_in[1];
    const float* ea  = (const float*)d_in[2];
    const float* dtp = (const float*)d_in[3];
    const float* gp  = (const float*)d_in[4];

    const int NF = in_sizes[0];        // 1,600,000
    const int N  = NF / F;             // 200,000
    const int E  = in_sizes[2] / 2;    // 3,200,000
    const int* srcp = ei;
    const int* dstp = ei + E;

    static Sched h_sched;
    build_sched_host(NF - 1, &h_sched);
    const int NL = h_sched.NL;

    char* wp = (char*)d_ws;
    float* scal    = (float*)wp; wp += 128 * 4;
    float* r       = (float*)wp; wp += (size_t)NF * 4;
    float* p       = (float*)wp; wp += (size_t)NF * 4;
    float* t       = (float*)wp; wp += (size_t)NF * 4;
    float* w       = (float*)wp; wp += (size_t)NF * 4;
    float* y       = (float*)wp; wp += (size_t)NF * 4;
    float* dacc    = (float*)wp; wp += (size_t)NF * 4;
    Rec*   recD    = (Rec*)wp;   wp += (size_t)E * 16;
    Rec*   recS    = (Rec*)wp;   wp += (size_t)E * 16;
    Ed*    edD     = (Ed*)wp;    wp += (size_t)E * 8;
    Ed*    edS     = (Ed*)wp;    wp += (size_t)E * 8;
    float* slopeD  = (float*)wp; wp += (size_t)E * 4;
    int*   dstOff  = (int*)wp;   wp += (size_t)(N + 1) * 4;
    int*   srcOff  = (int*)wp;   wp += (size_t)(N + 1) * 4;
    int*   dstCnt  = (int*)wp;   wp += (size_t)N * 4;   // 4 adjacent zeroed bufs
    int*   srcCnt  = (int*)wp;   wp += (size_t)N * 4;
    int*   cursD   = (int*)wp;   wp += (size_t)N * 4;
    int*   cursS   = (int*)wp;   wp += (size_t)N * 4;
    int*   bsD     = (int*)wp;   wp += 512 * 4;
    int*   bsS     = (int*)wp;   wp += 512 * 4;
    float* partial1 = (float*)wp; wp += 2048 * 4;
    float* partial2 = (float*)wp; wp += 2048 * 4;
    wp = (char*)(((uintptr_t)wp + 255) & ~(uintptr_t)255);
    Sched* d_sched = (Sched*)wp; wp += (sizeof(Sched) + 255) & ~(size_t)255;
    float* x = (float*)d_out;

    hipMemcpyAsync(d_sched, &h_sched, sizeof(Sched), hipMemcpyHostToDevice,
                   stream);
    hipMemsetAsync(scal, 0, 128 * 4, stream);
    hipMemsetAsync(dstCnt, 0, (size_t)N * 4 * 4, stream);  // cnt+curs, adjacent

    const int bn = 256;
    const int gN  = (N + bn - 1) / bn;
    const int gE  = (E + bn - 1) / bn;
    const int nb  = (N + 511) / 512;
    const int n4  = NF / 4;
    const int g4  = (n4 + bn - 1) / bn;
    const int NP  = NF / 2;
    const int gP  = (NP + bn - 1) / bn;

    // ---- CSR build (stable by edge id) ----
    k_edge_pre<<<gE, bn, 0, stream>>>(dstp, srcp, dstCnt, srcCnt, E);
    k_scan1m<<<2 * nb, 512, 0, stream>>>(dstCnt, srcCnt, dstOff, srcOff,
                                         bsD, bsS, N, nb);
    k_scan2m<<<1, 512, 0, stream>>>(bsD, bsS, nb);
    k_scan3m<<<2 * nb, 512, 0, stream>>>(dstOff, srcOff, bsD, bsS,
                                         dstCnt, srcCnt, N, E, nb);
    k_fill<<<gE, bn, 0, stream>>>(dstp, srcp, ea, dstOff, srcOff, cursD, cursS,
                                  recD, recS, E);
    k_sortc<<<gN, bn, 0, stream>>>(dstOff, srcOff, recD, recS,
                                   edD, slopeD, edS, N);

    // ---- setup ----
    k_slope_b<<<gN, bn, 0, stream>>>(u, slopeD, dstOff, r, y, dtp, gp, N);
    k_d1tz_full<<<gP, bn, 0, stream>>>(edD, dstOff, edS, srcOff,
                                       y, r, p, dtp, r, x, NP);
    k_dot_leaf<<<NL, 256, 0, stream>>>(p, p, d_sched, partial1);
    k_dot_rs0<<<1, 256, 0, stream>>>(p, partial1, d_sched, scal);

    // ---- CG loop (5 dispatches/iter) ----
    for (int it = 0; it < CG_ITERS; ++it) {
        k_d1w_f<<<gP, bn, 0, stream>>>(edD, dstOff, p, u, w, y, dacc, dtp, NP);
        k_d1tzs<<<gP, bn, 0, stream>>>(edS, srcOff, y, dacc, w, t, dtp, NP);
        k_dot_leaf<<<NL, 256, 0, stream>>>(p, t, d_sched, partial1);
        k_xr_dot<<<NL, 256, 0, stream>>>(x, r, p, t, scal, d_sched,
                                         partial1, partial2, it);
        k_p_fin<<<g4, bn, 0, stream>>>((float4*)p, (const float4*)r, r, scal,
                                       d_sched, partial2, it, n4);
    }
}

// Round 10
// 4416.035 us; speedup vs baseline: 2.0328x; 1.0344x over previous
//
#include <hip/hip_runtime.h>
#include <math.h>
#include <stdint.h>
#include <string.h>

// PhysicsLSGStep: bitwise-faithful f32 replication of the numpy reference.
// R21 (on top of R20), consolidation round:
//  - k_sortc split 2-way: dst side and src side of a node handled by
//    DIFFERENT threads (grid 2N) => serial sort path halved.
//  - slope sum fused into k_sortc's dst emit loop (identical ascending-order
//    __fadd_rn chain as k_slope_b's segment loop => bit-exact); slopeD array
//    and its 12.8MB round-trip deleted; k_slope_b reads snode[i].
//  - DONE[it] early-exit guards on d1w_f/d1tzs/dot_leaf/xr_dot: when CG has
//    converged their outputs are dead (x,r frozen; stale partials reproduce
//    frozen values; RS/DONE chain short-circuits) => bit-exact, free if the
//    solver never converges, big if it does.
//  - gather loops unroll 4 -> 8 (order-preserving).
// Scatter sums stay in sorted-edge-id (CSR) order; dots replay the exact
// numpy pairwise tree (level-parallel, pairings unchanged). f32 __f*_rn only.

#define F 8
#define CG_ITERS 30
#define LEAF_T 4096
#define LEAF_PAD (LEAF_T + LEAF_T / 128 + 8)
#define ENC_ADD 1024
#define MAX_LEAF 1024
#define MAX_CLS 32
#define MAXDEG 64

// scal slots: RS[it] = scal[8+it], DONE[it] = scal[64+it]

#define LV(A_, i_) A_[(i_) + ((i_) >> 7)]

struct __align__(8) Ed { int n; float v; };
struct __align__(16) Rec { int e; int n; float v; float s; };

struct Sched {
    int NL, uNT, uMaxD, nCls;
    int leafOff[MAX_LEAF], leafN[MAX_LEAF], cls[MAX_LEAF];
    int cNB[MAX_CLS], cMaxD[MAX_CLS];
    int cBOff[MAX_CLS][64], cBN[MAX_CLS][64];
    int cA[MAX_CLS][64], cB[MAX_CLS][64], cOrder[MAX_CLS][64];
    int cLevOff[MAX_CLS][32];
    int uA[MAX_LEAF], uB[MAX_LEAF], uOrder[MAX_LEAF], uLevOff[64];
};

// ---------------- host-side schedule build (exact integer replica) --------

static void host_build_tree(int n, int T, int* bOff, int* bN,
                            int* A, int* B, int* dep,
                            int* pNB, int* pNT, int* pMaxD) {
    int so[64], sn[64], st[64], sid[64], sdp[64];
    int sp = 0, coff = 0, cn = n, c2 = 0, t = 0, rootd = 0;
    for (;;) {
        if (cn <= T) {
            if (bOff) { bOff[c2] = coff; bN[c2] = cn; }
            int id = c2, dp = 0; c2++;
            bool fin = false;
            for (;;) {
                if (sp == 0) { rootd = dp; fin = true; break; }
                if (st[sp - 1] == 0) {
                    st[sp - 1] = 1; sid[sp - 1] = id; sdp[sp - 1] = dp;
                    int n2 = sn[sp - 1] / 2; n2 -= (n2 & 7);
                    coff = so[sp - 1] + n2; cn = sn[sp - 1] - n2;
                    break;
                } else {
                    A[t] = sid[sp - 1]; B[t] = id;
                    int dA = sdp[sp - 1];
                    dp = ((dA > dp) ? dA : dp) + 1;
                    dep[t] = dp;
                    id = ENC_ADD + t; t++;
                    sp--;
                }
            }
            if (fin) break;
        } else {
            so[sp] = coff; sn[sp] = cn; st[sp] = 0; sp++;
            int n2 = cn / 2; n2 -= (n2 & 7);
            cn = n2;
        }
    }
    *pNB = c2; *pNT = t; *pMaxD = rootd;
}

static void host_bucketize(const int* dep, int NT, int maxD,
                           int* order, int* levOff) {
    int cnt[64];
    for (int d = 0; d <= maxD; ++d) cnt[d] = 0;
    for (int t = 0; t < NT; ++t) cnt[dep[t]]++;
    int run = 0;
    levOff[0] = 0;
    for (int d = 1; d <= maxD; ++d) { run += cnt[d]; levOff[d] = run; }
    int cur[64];
    for (int d = 1; d <= maxD; ++d) cur[d] = levOff[d - 1];
    for (int t = 0; t < NT; ++t) { int d = dep[t]; order[cur[d]++] = t; }
}

static void build_sched_host(int n, Sched* s) {
    static int uDep[MAX_LEAF];
    host_build_tree(n, LEAF_T, s->leafOff, s->leafN, s->uA, s->uB, uDep,
                    &s->NL, &s->uNT, &s->uMaxD);
    host_bucketize(uDep, s->uNT, s->uMaxD, s->uOrder, s->uLevOff);
    s->nCls = 0;
    int clsN[MAX_CLS];
    int dep[64];
    for (int j = 0; j < s->NL; ++j) {
        int c = -1;
        for (int k = 0; k < s->nCls; ++k)
            if (clsN[k] == s->leafN[j]) { c = k; break; }
        if (c < 0 && s->nCls < MAX_CLS) {
            c = s->nCls++;
            clsN[c] = s->leafN[j];
            int NB, NT, maxD;
            host_build_tree(s->leafN[j], 128, s->cBOff[c], s->cBN[c],
                            s->cA[c], s->cB[c], dep, &NB, &NT, &maxD);
            s->cNB[c] = NB; s->cMaxD[c] = maxD;
            host_bucketize(dep, NT, maxD, s->cOrder[c], s->cLevOff[c]);
        }
        s->cls[j] = c;
    }
}

// ---------------- device ----------------

__device__ __forceinline__ float dt_eff_of(const float* dtp) {
    return fminf(fmaxf(dtp[0], 0.02f), 2.0f);
}

__device__ __forceinline__ int slotOf(int e, int NB) {
    return (e < ENC_ADD) ? e : (NB + (e - ENC_ADD));
}

__device__ __forceinline__ float combine_upper(const float* __restrict__ partial,
                                               const Sched* __restrict__ sc,
                                               float* sU, int lane) {
    int NL = sc->NL, NT = sc->uNT, maxD = sc->uMaxD;
    for (int k = lane; k < NL; k += 256) sU[k] = partial[k];
    __syncthreads();
    for (int d = 1; d <= maxD; ++d) {
        int s0 = sc->uLevOff[d - 1], s1 = sc->uLevOff[d];
        for (int s = s0 + lane; s < s1; s += 256) {
            int tt = sc->uOrder[s];
            sU[NL + tt] = __fadd_rn(sU[slotOf(sc->uA[tt], NL)],
                                    sU[slotOf(sc->uB[tt], NL)]);
        }
        __syncthreads();
    }
    return (NT > 0) ? sU[NL + NT - 1] : sU[0];
}

__device__ __forceinline__ void dot_eval(const float* sA, const float* sB,
                                         float* sChain, float* sVal,
                                         int lane, int NB,
                                         const int* __restrict__ bOff,
                                         const int* __restrict__ bN,
                                         const int* __restrict__ A,
                                         const int* __restrict__ Bb,
                                         const int* __restrict__ order,
                                         const int* __restrict__ levOff,
                                         int maxD,
                                         float* __restrict__ partial, int j) {
    int bb = lane >> 3, jj = lane & 7;
    if (bb < NB) {
        int off = bOff[bb], n = bN[bb];
        if (n >= 8) {
            int lim = n - (n & 7);
            float rr = __fmul_rn(LV(sA, off + jj), LV(sB, off + jj));
            for (int e = jj + 8; e < lim; e += 8)
                rr = __fadd_rn(rr, __fmul_rn(LV(sA, off + e), LV(sB, off + e)));
            sChain[bb * 8 + jj] = rr;
        }
    }
    __syncthreads();
    if (lane < NB) {
        int off = bOff[lane], n = bN[lane];
        float res;
        if (n < 8) {
            res = 0.f;
            for (int e = 0; e < n; ++e)
                res = __fadd_rn(res, __fmul_rn(LV(sA, off + e), LV(sB, off + e)));
        } else {
            int lim = n - (n & 7);
            const float* c = sChain + lane * 8;
            res = __fadd_rn(__fadd_rn(__fadd_rn(c[0], c[1]), __fadd_rn(c[2], c[3])),
                            __fadd_rn(__fadd_rn(c[4], c[5]), __fadd_rn(c[6], c[7])));
            for (int e = lim; e < n; ++e)
                res = __fadd_rn(res, __fmul_rn(LV(sA, off + e), LV(sB, off + e)));
        }
        sVal[lane] = res;
    }
    __syncthreads();
    for (int d = 1; d <= maxD; ++d) {
        int s0 = levOff[d - 1], s1 = levOff[d];
        for (int s = s0 + lane; s < s1; s += 256) {
            int tt = order[s];
            sVal[NB + tt] = __fadd_rn(sVal[slotOf(A[tt], NB)],
                                      sVal[slotOf(Bb[tt], NB)]);
        }
        __syncthreads();
    }
    if (lane == 0) partial[j] = (NB > 1) ? sVal[NB + NB - 2] : sVal[0];
}

// per-leaf dot partial (a.b). grid = NL blocks, 256 threads.
// guarded: skipped when DONE[it] (outputs dead once converged).
__global__ void k_dot_leaf(const float* __restrict__ a, const float* __restrict__ b,
                           const Sched* __restrict__ sc, float* __restrict__ partial,
                           const float* __restrict__ scal, int it) {
    if (scal[64 + it] != 0.f) return;
    __shared__ float sA[LEAF_PAD], sB[LEAF_PAD];
    __shared__ float sChain[512];
    __shared__ float sVal[160];
    int j = blockIdx.x, lane = threadIdx.x;
    int P = sc->leafOff[j] + 1, nn = sc->leafN[j];
    for (int g = lane; g < nn; g += 256) {
        float av = a[P + g], bv = b[P + g];
        int m = g + (g >> 7);
        sA[m] = av; sB[m] = bv;
    }
    __syncthreads();
    int c = sc->cls[j];
    dot_eval(sA, sB, sChain, sVal, lane, sc->cNB[c], sc->cBOff[c], sc->cBN[c],
             sc->cA[c], sc->cB[c], sc->cOrder[c], sc->cLevOff[c], sc->cMaxD[c],
             partial, j);
}

__global__ void k_dot_rs0(const float* __restrict__ a,
                          const float* __restrict__ partial,
                          const Sched* __restrict__ sc, float* __restrict__ scal) {
    __shared__ float sU[2048];
    int lane = threadIdx.x;
    float res = combine_upper(partial, sc, sU, lane);
    if (lane == 0)
        scal[8 + 0] = __fadd_rn(__fmul_rn(a[0], a[0]), res);
}

// guarded: when DONE[it], r is frozen so partial2 (stale) already holds r.r.
__global__ void k_xr_dot(float* __restrict__ x, float* __restrict__ r,
                         const float* __restrict__ p, const float* __restrict__ z,
                         const float* __restrict__ scal,
                         const Sched* __restrict__ sc,
                         const float* __restrict__ partial1,
                         float* __restrict__ partial2, int it) {
    if (scal[64 + it] != 0.f) return;
    __shared__ float sA[LEAF_PAD];
    __shared__ float sU[2048];
    __shared__ float sChain[512];
    __shared__ float sVal[160];
    __shared__ float sAl;
    int j = blockIdx.x, lane = threadIdx.x;
    float res = combine_upper(partial1, sc, sU, lane);
    if (lane == 0) {
        float pt = __fadd_rn(__fmul_rn(p[0], z[0]), res);
        sAl = __fdiv_rn(scal[8 + it], __fadd_rn(pt, (float)1e-12));
    }
    __syncthreads();
    float al = sAl;
    int P = sc->leafOff[j] + 1, nn = sc->leafN[j];
    if (j == 0 && lane == 0) {
        x[0] = __fadd_rn(x[0], __fmul_rn(al, p[0]));
        r[0] = __fsub_rn(r[0], __fmul_rn(al, z[0]));
    }
    for (int g = lane; g < nn; g += 256) {
        int q = P + g;
        float xv = x[q], pv = p[q], zv = z[q], rv = r[q];
        x[q] = __fadd_rn(xv, __fmul_rn(al, pv));
        rv = __fsub_rn(rv, __fmul_rn(al, zv));
        r[q] = rv;
        sA[g + (g >> 7)] = rv;
    }
    __syncthreads();
    int c = sc->cls[j];
    dot_eval(sA, sA, sChain, sVal, lane, sc->cNB[c], sc->cBOff[c], sc->cBN[c],
             sc->cA[c], sc->cB[c], sc->cOrder[c], sc->cLevOff[c], sc->cMaxD[c],
             partial2, j);
}

__global__ void k_p_fin(float4* __restrict__ p4, const float4* __restrict__ r4,
                        const float* __restrict__ rfull,
                        float* __restrict__ scal,
                        const Sched* __restrict__ sc,
                        const float* __restrict__ partial2, int it, int n4) {
    __shared__ float sU[2048];
    __shared__ float sBe;
    __shared__ int   sAct;
    int lane = threadIdx.x;
    float res = combine_upper(partial2, sc, sU, lane);
    if (lane == 0) {
        float rs1 = __fadd_rn(__fmul_rn(rfull[0], rfull[0]), res);
        float RS = scal[8 + it];
        float dn = scal[64 + it];
        sBe = __fdiv_rn(rs1, __fadd_rn(RS, (float)1e-12));
        sAct = (dn == 0.f) ? 1 : 0;
        if (blockIdx.x == 0) {
            scal[8 + it + 1]  = (dn == 0.f) ? rs1 : RS;
            scal[64 + it + 1] = (dn != 0.f || __fsqrt_rn(rs1) <= (float)1e-4)
                                ? 1.f : 0.f;
        }
    }
    __syncthreads();
    if (!sAct) return;
    float be = sBe;
    int i = blockIdx.x * blockDim.x + lane;
    if (i >= n4) return;
    float4 pv = p4[i], rv = r4[i];
    pv.x = __fadd_rn(rv.x, __fmul_rn(be, pv.x));
    pv.y = __fadd_rn(rv.y, __fmul_rn(be, pv.y));
    pv.z = __fadd_rn(rv.z, __fmul_rn(be, pv.z));
    pv.w = __fadd_rn(rv.w, __fmul_rn(be, pv.w));
    p4[i] = pv;
}

// ---------- CSR build (stable in edge order) ----------

__global__ void k_edge_pre(const int* __restrict__ dst, const int* __restrict__ src,
                           int* __restrict__ dstCnt, int* __restrict__ srcCnt, int E) {
    int e = blockIdx.x * blockDim.x + threadIdx.x;
    if (e >= E) return;
    atomicAdd(&dstCnt[dst[e]], 1);
    atomicAdd(&srcCnt[src[e]], 1);
}

__global__ void k_scan1m(const int* __restrict__ cntD, const int* __restrict__ cntS,
                         int* __restrict__ inclD, int* __restrict__ inclS,
                         int* __restrict__ bsD, int* __restrict__ bsS,
                         int N, int nb) {
    __shared__ int sm[512];
    int bb = blockIdx.x;
    int isS = (bb >= nb) ? 1 : 0;
    int blk = bb - (isS ? nb : 0);
    const int* cnt = isS ? cntS : cntD;
    int* incl = isS ? inclS : inclD;
    int* bsums = isS ? bsS : bsD;
    int i = blk * 512 + threadIdx.x;
    sm[threadIdx.x] = (i < N) ? cnt[i] : 0;
    __syncthreads();
    for (int off = 1; off < 512; off <<= 1) {
        int t = (threadIdx.x >= off) ? sm[threadIdx.x - off] : 0;
        __syncthreads();
        sm[threadIdx.x] += t;
        __syncthreads();
    }
    if (i < N) incl[i] = sm[threadIdx.x];
    if (threadIdx.x == 511) bsums[blk] = sm[511];
}

__global__ void k_scan2m(int* __restrict__ bsD, int* __restrict__ bsS, int nb) {
    __shared__ int sm[512];
    for (int pass = 0; pass < 2; ++pass) {
        int* bsums = pass ? bsS : bsD;
        sm[threadIdx.x] = (threadIdx.x < nb) ? bsums[threadIdx.x] : 0;
        __syncthreads();
        for (int off = 1; off < 512; off <<= 1) {
            int t = (threadIdx.x >= off) ? sm[threadIdx.x - off] : 0;
            __syncthreads();
            sm[threadIdx.x] += t;
            __syncthreads();
        }
        if (threadIdx.x < nb) bsums[threadIdx.x] = sm[threadIdx.x];
        __syncthreads();
    }
}

__global__ void k_scan3m(int* __restrict__ offD, int* __restrict__ offS,
                         const int* __restrict__ bsD, const int* __restrict__ bsS,
                         const int* __restrict__ cntD, const int* __restrict__ cntS,
                         int N, int E, int nb) {
    int bb = blockIdx.x;
    int isS = (bb >= nb) ? 1 : 0;
    int blk = bb - (isS ? nb : 0);
    int* off = isS ? offS : offD;
    const int* bsums = isS ? bsS : bsD;
    const int* cnt = isS ? cntS : cntD;
    int i = blk * 512 + threadIdx.x;
    if (i < N) {
        int add = (blk > 0) ? bsums[blk - 1] : 0;
        off[i] = off[i] + add - cnt[i];
    }
    if (i == 0) off[N] = E;
}

__global__ void k_fill(const int* __restrict__ dst, const int* __restrict__ src,
                       const float* __restrict__ ea,
                       const int* __restrict__ dstOff, const int* __restrict__ srcOff,
                       int* __restrict__ cursD, int* __restrict__ cursS,
                       Rec* __restrict__ recD, Rec* __restrict__ recS, int E) {
    int e = blockIdx.x * blockDim.x + threadIdx.x;
    if (e >= E) return;
    int d = dst[e];
    int s0 = src[e];
    float2 exy = ((const float2*)ea)[e];
    float dx = fmaxf(exy.x, 1e-6f);
    float iv = __fdiv_rn(1.f, dx);
    float sl = __fdiv_rn(exy.y, dx);
    Rec rd; rd.e = e; rd.n = s0; rd.v = iv; rd.s = sl;
    Rec rs; rs.e = e; rs.n = d;  rs.v = iv; rs.s = 0.f;
    recD[dstOff[d] + atomicAdd(&cursD[d], 1)] = rd;
    recS[srcOff[s0] + atomicAdd(&cursS[s0], 1)] = rs;
}

// fused sort+compact, 2-way split: threads [0,N) do dst side (also
// accumulating the node slope sum in sorted order — identical __fadd_rn
// chain as the old k_slope_b loop), threads [N,2N) do src side.
__global__ void k_sortc(const int* __restrict__ dstOff, const int* __restrict__ srcOff,
                        const Rec* __restrict__ recD, const Rec* __restrict__ recS,
                        Ed* __restrict__ edD, float* __restrict__ snode,
                        Ed* __restrict__ edS, int N) {
    __shared__ unsigned keys[256 * MAXDEG];   // 64 KB
    int tid = blockIdx.x * blockDim.x + threadIdx.x;
    if (tid >= 2 * N) return;
    unsigned* k0 = keys + threadIdx.x * MAXDEG;
    if (tid < N) {
        int i = tid;
        int lo = dstOff[i], hi = dstOff[i + 1], d = hi - lo;
        float sn = 0.f;
        if (d <= MAXDEG) {
            for (int m = 0; m < d; ++m)
                k0[m] = ((unsigned)recD[lo + m].e << 6) | (unsigned)m;
            for (int a = 1; a < d; ++a) {
                unsigned kk = k0[a]; int b = a - 1;
                while (b >= 0 && k0[b] > kk) { k0[b + 1] = k0[b]; b--; }
                k0[b + 1] = kk;
            }
            for (int m = 0; m < d; ++m) {
                Rec rr = recD[lo + (int)(k0[m] & 63u)];
                Ed ed; ed.n = rr.n; ed.v = rr.v;
                edD[lo + m] = ed;
                sn = __fadd_rn(sn, rr.s);
            }
        } else {   // selection fallback (distinct keys => same output)
            int prev = -1;
            for (int m = 0; m < d; ++m) {
                int best = 0x7fffffff, bj = -1;
                for (int jx = 0; jx < d; ++jx) {
                    int ev = recD[lo + jx].e;
                    if (ev > prev && ev < best) { best = ev; bj = jx; }
                }
                Rec rr = recD[lo + bj];
                Ed ed; ed.n = rr.n; ed.v = rr.v;
                edD[lo + m] = ed;
                sn = __fadd_rn(sn, rr.s);
                prev = best;
            }
        }
        snode[i] = sn;
    } else {
        int i = tid - N;
        int lo = srcOff[i], hi = srcOff[i + 1], d = hi - lo;
        if (d <= MAXDEG) {
            for (int m = 0; m < d; ++m)
                k0[m] = ((unsigned)recS[lo + m].e << 6) | (unsigned)m;
            for (int a = 1; a < d; ++a) {
                unsigned kk = k0[a]; int b = a - 1;
                while (b >= 0 && k0[b] > kk) { k0[b + 1] = k0[b]; b--; }
                k0[b + 1] = kk;
            }
            for (int m = 0; m < d; ++m) {
                Rec rr = recS[lo + (int)(k0[m] & 63u)];
                Ed ed; ed.n = rr.n; ed.v = rr.v;
                edS[lo + m] = ed;
            }
        } else {
            int prev = -1;
            for (int m = 0; m < d; ++m) {
                int best = 0x7fffffff, bj = -1;
                for (int jx = 0; jx < d; ++jx) {
                    int ev = recS[lo + jx].e;
                    if (ev > prev && ev < best) { best = ev; bj = jx; }
                }
                Rec rr = recS[lo + bj];
                Ed ed; ed.n = rr.n; ed.v = rr.v;
                edS[lo + m] = ed;
                prev = best;
            }
        }
    }
}

// ---------- physics kernels (exact np op order, f32 sequential) ----------

__global__ void k_slope_b(const float* __restrict__ u, const float* __restrict__ snode,
                          float* __restrict__ r, float* __restrict__ y,
                          const float* __restrict__ dtp, const float* __restrict__ gp,
                          int N) {
    int i = blockIdx.x * blockDim.x + threadIdx.x;
    if (i >= N) return;
    float dtg = __fmul_rn(dt_eff_of(dtp), gp[0]);
    float sn = snode[i];
    float ms = __fmul_rn(dtg, sn);
    const float4* u4 = (const float4*)u;
    float4* r4 = (float4*)r;
    float4* y4 = (float4*)y;
    #pragma unroll
    for (int hh = 0; hh < 2; ++hh) {
        float4 uv = u4[i * 2 + hh];
        float4 bv;
        bv.x = __fsub_rn(uv.x, ms);
        bv.y = __fsub_rn(uv.y, ms);
        bv.z = __fsub_rn(uv.z, ms);
        bv.w = __fsub_rn(uv.w, ms);
        r4[i * 2 + hh] = bv;
        float4 yv;
        yv.x = __fmul_rn(uv.x, bv.x);
        yv.y = __fmul_rn(uv.y, bv.y);
        yv.z = __fmul_rn(uv.z, bv.z);
        yv.w = __fmul_rn(uv.w, bv.w);
        y4[i * 2 + hh] = yv;
    }
}

__global__ void k_d1tz_full(const Ed* __restrict__ edD, const int* __restrict__ dstOff,
                            const Ed* __restrict__ edS, const int* __restrict__ srcOff,
                            const float* __restrict__ y,
                            const float* __restrict__ base, float* __restrict__ out,
                            const float* __restrict__ dtp,
                            float* __restrict__ rInit, float* __restrict__ xInit,
                            int NP) {
    int idx = blockIdx.x * blockDim.x + threadIdx.x;
    if (idx >= NP) return;
    int i = idx >> 2, c = idx & 3;
    const float2* y2 = (const float2*)y;
    float2 uy = y2[idx];
    float2 acc = make_float2(0.f, 0.f);
    int k0 = dstOff[i], k1 = dstOff[i + 1];
    #pragma unroll 4
    for (int k = k0; k < k1; ++k) {
        float iv = edD[k].v;
        acc.x = __fadd_rn(acc.x, __fmul_rn(uy.x, iv));
        acc.y = __fadd_rn(acc.y, __fmul_rn(uy.y, iv));
    }
    k0 = srcOff[i]; k1 = srcOff[i + 1];
    #pragma unroll 4
    for (int k = k0; k < k1; ++k) {
        Ed e = edS[k];
        float2 yd = y2[e.n * 4 + c];
        float t0 = __fmul_rn(yd.x, e.v); acc.x = __fadd_rn(acc.x, -t0);
        float t1 = __fmul_rn(yd.y, e.v); acc.y = __fadd_rn(acc.y, -t1);
    }
    float dt = dt_eff_of(dtp);
    float2 bs = ((const float2*)base)[idx];
    float2 ov;
    ov.x = __fadd_rn(bs.x, __fmul_rn(dt, acc.x));
    ov.y = __fadd_rn(bs.y, __fmul_rn(dt, acc.y));
    ((float2*)out)[idx] = ov;
    ((float2*)rInit)[idx] = ov;
    ((float2*)xInit)[idx] = make_float2(0.f, 0.f);
}

// guarded loop kernel 1.
__global__ void k_d1w_f(const Ed* __restrict__ edD, const int* __restrict__ dstOff,
                        const float* __restrict__ pv, const float* __restrict__ u,
                        float* __restrict__ w, float* __restrict__ y,
                        float* __restrict__ dacc,
                        const float* __restrict__ dtp,
                        const float* __restrict__ scal, int it, int NP) {
    if (scal[64 + it] != 0.f) return;
    int idx = blockIdx.x * blockDim.x + threadIdx.x;
    if (idx >= NP) return;
    int i = idx >> 2, c = idx & 3;
    const float2* pv2 = (const float2*)pv;
    float2 pi = pv2[idx];
    float2 acc = make_float2(0.f, 0.f);
    int k0 = dstOff[i], k1 = dstOff[i + 1];
    #pragma unroll 8
    for (int k = k0; k < k1; ++k) {
        Ed e = edD[k];
        float2 ps = pv2[e.n * 4 + c];
        acc.x = __fadd_rn(acc.x, __fmul_rn(__fsub_rn(pi.x, ps.x), e.v));
        acc.y = __fadd_rn(acc.y, __fmul_rn(__fsub_rn(pi.y, ps.y), e.v));
    }
    float dt = dt_eff_of(dtp);
    float2 uv = ((const float2*)u)[idx];
    float2 wv;
    wv.x = __fadd_rn(pi.x, __fmul_rn(dt, __fmul_rn(uv.x, acc.x)));
    wv.y = __fadd_rn(pi.y, __fmul_rn(dt, __fmul_rn(uv.y, acc.y)));
    ((float2*)w)[idx] = wv;
    float2 yv;
    yv.x = __fmul_rn(uv.x, wv.x);
    yv.y = __fmul_rn(uv.y, wv.y);
    ((float2*)y)[idx] = yv;
    float2 da = make_float2(0.f, 0.f);
    #pragma unroll 8
    for (int k = k0; k < k1; ++k) {
        float iv = edD[k].v;
        da.x = __fadd_rn(da.x, __fmul_rn(yv.x, iv));
        da.y = __fadd_rn(da.y, __fmul_rn(yv.y, iv));
    }
    ((float2*)dacc)[idx] = da;
}

// guarded loop kernel 2.
__global__ void k_d1tzs(const Ed* __restrict__ edS, const int* __restrict__ srcOff,
                        const float* __restrict__ y, const float* __restrict__ dacc,
                        const float* __restrict__ base, float* __restrict__ out,
                        const float* __restrict__ dtp,
                        const float* __restrict__ scal, int it, int NP) {
    if (scal[64 + it] != 0.f) return;
    int idx = blockIdx.x * blockDim.x + threadIdx.x;
    if (idx >= NP) return;
    int i = idx >> 2, c = idx & 3;
    const float2* y2 = (const float2*)y;
    float2 acc = ((const float2*)dacc)[idx];
    int k0 = srcOff[i], k1 = srcOff[i + 1];
    #pragma unroll 8
    for (int k = k0; k < k1; ++k) {
        Ed e = edS[k];
        float2 yd = y2[e.n * 4 + c];
        float t0 = __fmul_rn(yd.x, e.v); acc.x = __fadd_rn(acc.x, -t0);
        float t1 = __fmul_rn(yd.y, e.v); acc.y = __fadd_rn(acc.y, -t1);
    }
    float dt = dt_eff_of(dtp);
    float2 bs = ((const float2*)base)[idx];
    float2 ov;
    ov.x = __fadd_rn(bs.x, __fmul_rn(dt, acc.x));
    ov.y = __fadd_rn(bs.y, __fmul_rn(dt, acc.y));
    ((float2*)out)[idx] = ov;
}

extern "C" void kernel_launch(void* const* d_in, const int* in_sizes, int n_in,
                              void* d_out, int out_size, void* d_ws, size_t ws_size,
                              hipStream_t stream) {
    const float* u   = (const float*)d_in[0];
    const int*   ei  = (const int*)d_in[1];
    const float* ea  = (const float*)d_in[2];
    const float* dtp = (const float*)d_in[3];
    const float* gp  = (const float*)d_in[4];

    const int NF = in_sizes[0];        // 1,600,000
    const int N  = NF / F;             // 200,000
    const int E  = in_sizes[2] / 2;    // 3,200,000
    const int* srcp = ei;
    const int* dstp = ei + E;

    static Sched h_sched;
    build_sched_host(NF - 1, &h_sched);
    const int NL = h_sched.NL;

    char* wp = (char*)d_ws;
    float* scal    = (float*)wp; wp += 128 * 4;
    float* r       = (float*)wp; wp += (size_t)NF * 4;
    float* p       = (float*)wp; wp += (size_t)NF * 4;
    float* t       = (float*)wp; wp += (size_t)NF * 4;
    float* w       = (float*)wp; wp += (size_t)NF * 4;
    float* y       = (float*)wp; wp += (size_t)NF * 4;
    float* dacc    = (float*)wp; wp += (size_t)NF * 4;
    Rec*   recD    = (Rec*)wp;   wp += (size_t)E * 16;
    Rec*   recS    = (Rec*)wp;   wp += (size_t)E * 16;
    Ed*    edD     = (Ed*)wp;    wp += (size_t)E * 8;
    Ed*    edS     = (Ed*)wp;    wp += (size_t)E * 8;
    float* snode   = (float*)wp; wp += (size_t)N * 4;
    int*   dstOff  = (int*)wp;   wp += (size_t)(N + 1) * 4;
    int*   srcOff  = (int*)wp;   wp += (size_t)(N + 1) * 4;
    int*   dstCnt  = (int*)wp;   wp += (size_t)N * 4;   // 4 adjacent zeroed bufs
    int*   srcCnt  = (int*)wp;   wp += (size_t)N * 4;
    int*   cursD   = (int*)wp;   wp += (size_t)N * 4;
    int*   cursS   = (int*)wp;   wp += (size_t)N * 4;
    int*   bsD     = (int*)wp;   wp += 512 * 4;
    int*   bsS     = (int*)wp;   wp += 512 * 4;
    float* partial1 = (float*)wp; wp += 2048 * 4;
    float* partial2 = (float*)wp; wp += 2048 * 4;
    wp = (char*)(((uintptr_t)wp + 255) & ~(uintptr_t)255);
    Sched* d_sched = (Sched*)wp; wp += (sizeof(Sched) + 255) & ~(size_t)255;
    float* x = (float*)d_out;

    hipMemcpyAsync(d_sched, &h_sched, sizeof(Sched), hipMemcpyHostToDevice,
                   stream);
    hipMemsetAsync(scal, 0, 128 * 4, stream);
    hipMemsetAsync(dstCnt, 0, (size_t)N * 4 * 4, stream);

    const int bn = 256;
    const int gN  = (N + bn - 1) / bn;
    const int gN2 = (2 * N + bn - 1) / bn;
    const int gE  = (E + bn - 1) / bn;
    const int nb  = (N + 511) / 512;
    const int n4  = NF / 4;
    const int g4  = (n4 + bn - 1) / bn;
    const int NP  = NF / 2;
    const int gP  = (NP + bn - 1) / bn;

    // ---- CSR build (stable by edge id) ----
    k_edge_pre<<<gE, bn, 0, stream>>>(dstp, srcp, dstCnt, srcCnt, E);
    k_scan1m<<<2 * nb, 512, 0, stream>>>(dstCnt, srcCnt, dstOff, srcOff,
                                         bsD, bsS, N, nb);
    k_scan2m<<<1, 512, 0, stream>>>(bsD, bsS, nb);
    k_scan3m<<<2 * nb, 512, 0, stream>>>(dstOff, srcOff, bsD, bsS,
                                         dstCnt, srcCnt, N, E, nb);
    k_fill<<<gE, bn, 0, stream>>>(dstp, srcp, ea, dstOff, srcOff, cursD, cursS,
                                  recD, recS, E);
    k_sortc<<<gN2, bn, 0, stream>>>(dstOff, srcOff, recD, recS,
                                    edD, snode, edS, N);

    // ---- setup ----
    k_slope_b<<<gN, bn, 0, stream>>>(u, snode, r, y, dtp, gp, N);
    k_d1tz_full<<<gP, bn, 0, stream>>>(edD, dstOff, edS, srcOff,
                                       y, r, p, dtp, r, x, NP);
    k_dot_leaf<<<NL, 256, 0, stream>>>(p, p, d_sched, partial1, scal, 0);
    k_dot_rs0<<<1, 256, 0, stream>>>(p, partial1, d_sched, scal);

    // ---- CG loop (5 dispatches/iter) ----
    for (int it = 0; it < CG_ITERS; ++it) {
        k_d1w_f<<<gP, bn, 0, stream>>>(edD, dstOff, p, u, w, y, dacc, dtp,
                                       scal, it, NP);
        k_d1tzs<<<gP, bn, 0, stream>>>(edS, srcOff, y, dacc, w, t, dtp,
                                       scal, it, NP);
        k_dot_leaf<<<NL, 256, 0, stream>>>(p, t, d_sched, partial1, scal, it);
        k_xr_dot<<<NL, 256, 0, stream>>>(x, r, p, t, scal, d_sched,
                                         partial1, partial2, it);
        k_p_fin<<<g4, bn, 0, stream>>>((float4*)p, (const float4*)r, r, scal,
                                       d_sched, partial2, it, n4);
    }
}